// Round 9
// baseline (708.564 us; speedup 1.0000x reference)
//
#include <hip/hip_runtime.h>

#define Nn 16384
#define Dm 256
#define Ff 1024

typedef __attribute__((ext_vector_type(8))) short bf16x8;
typedef __attribute__((ext_vector_type(4))) float f32x4;

typedef const __attribute__((address_space(1))) unsigned int glb_u32;
typedef __attribute__((address_space(3))) unsigned int lds_u32;

__device__ __forceinline__ void async_copy16(const void* g, void* l) {
  __builtin_amdgcn_global_load_lds((glb_u32*)g, (lds_u32*)l, 16, 0, 0);
}

__device__ __forceinline__ unsigned short f2bf(float f) {
  union { float f; unsigned u; } v; v.f = f;
  return (unsigned short)((v.u + 0x7FFFu + ((v.u >> 16) & 1u)) >> 16);
}

__device__ __forceinline__ float bf2f(unsigned short u) {
  union { unsigned u; float f; } v; v.u = ((unsigned)u) << 16;
  return v.f;
}

__device__ __forceinline__ float sel4(float4 v, int h) {
  float r = v.x;
  r = (h == 1) ? v.y : r;
  r = (h == 2) ? v.z : r;
  r = (h == 3) ? v.w : r;
  return r;
}

__device__ __forceinline__ float4 lrelu4(float4 a, float4 b) {
  float4 r;
  float e;
  e = a.x + b.x; r.x = e > 0.f ? e : 0.2f * e;
  e = a.y + b.y; r.y = e > 0.f ? e : 0.2f * e;
  e = a.z + b.z; r.z = e > 0.f ? e : 0.2f * e;
  e = a.w + b.w; r.w = e > 0.f ? e : 0.2f * e;
  return r;
}

// ---------------- tiled weight convert+transpose: wt[b][j][k] = bf16(w[b][k][j]) ----------------
__global__ __launch_bounds__(256) void wconvt_kernel(const float* __restrict__ w,
                                                     unsigned short* __restrict__ wt,
                                                     int K, int J) {
  __shared__ unsigned short t[64][65];
  int b = blockIdx.z;
  int j0 = blockIdx.x * 64, k0 = blockIdx.y * 64;
  int tj = threadIdx.x & 63, q = threadIdx.x >> 6;  // 4 rows per pass
  const float* wb = w + (size_t)b * K * J;
#pragma unroll
  for (int r = 0; r < 16; ++r) {
    int k = r * 4 + q;
    t[k][tj] = f2bf(wb[(size_t)(k0 + k) * J + j0 + tj]);
  }
  __syncthreads();
  unsigned short* wtb = wt + (size_t)b * K * J;
#pragma unroll
  for (int r = 0; r < 16; ++r) {
    int j = r * 4 + q;
    wtb[(size_t)(j0 + j) * K + k0 + tj] = t[tj][j];
  }
}

// ---------------- CSR build ----------------
__global__ void count_kernel(const int* __restrict__ dst, int E, int* __restrict__ cnt) {
  for (int e = blockIdx.x * blockDim.x + threadIdx.x; e < E; e += gridDim.x * blockDim.x)
    atomicAdd(&cnt[dst[e]], 1);
}

__global__ __launch_bounds__(256) void scan1_kernel(const int* __restrict__ cnt,
                                                    int* __restrict__ part,
                                                    int* __restrict__ bsum) {
  __shared__ int sd[256];
  int b = blockIdx.x, tid = threadIdx.x;
  int v = cnt[b * 256 + tid];
  sd[tid] = v;
  __syncthreads();
  for (int offt = 1; offt < 256; offt <<= 1) {
    int t = (tid >= offt) ? sd[tid - offt] : 0;
    __syncthreads();
    sd[tid] += t;
    __syncthreads();
  }
  part[b * 256 + tid] = sd[tid] - v;  // exclusive
  if (tid == 255) bsum[b] = sd[255];
}

__global__ __launch_bounds__(64) void scan2_kernel(const int* __restrict__ bsum,
                                                   int* __restrict__ bbase,
                                                   int* __restrict__ rowptr) {
  __shared__ int sd[64];
  int tid = threadIdx.x;
  int v = bsum[tid];
  sd[tid] = v;
  __syncthreads();
  for (int offt = 1; offt < 64; offt <<= 1) {
    int t = (tid >= offt) ? sd[tid - offt] : 0;
    __syncthreads();
    sd[tid] += t;
    __syncthreads();
  }
  bbase[tid] = sd[tid] - v;
  if (tid == 63) rowptr[Nn] = sd[63];
}

__global__ __launch_bounds__(256) void scan3_kernel(const int* __restrict__ part,
                                                    const int* __restrict__ bbase,
                                                    int* __restrict__ rowptr,
                                                    int* __restrict__ cursor) {
  int b = blockIdx.x, tid = threadIdx.x;
  int v = part[b * 256 + tid] + bbase[b];
  rowptr[b * 256 + tid] = v;
  cursor[b * 256 + tid] = v;
}

__global__ void fill_kernel(const int* __restrict__ src, const int* __restrict__ dst, int E,
                            int* __restrict__ cursor, int* __restrict__ csrc) {
  for (int e = blockIdx.x * blockDim.x + threadIdx.x; e < E; e += gridDim.x * blockDim.x) {
    int pos = atomicAdd(&cursor[dst[e]], 1);
    csrc[pos] = src[e];
  }
}

// ---------------- initial input prep (layer 0): x01b[0]=bf16(hf+hs), x01b[1]=bf16(hs) ----------------
__global__ void prep_kernel(const float* __restrict__ hf, const float* __restrict__ hs,
                            unsigned short* __restrict__ x01b, int total) {
  const size_t ZS = (size_t)Nn * Dm;
  for (int i = blockIdx.x * blockDim.x + threadIdx.x; i < total; i += gridDim.x * blockDim.x) {
    float a = hf[i], b = hs[i];
    x01b[i] = f2bf(a + b);
    x01b[ZS + i] = f2bf(b);
  }
}

// ---------------- proj GEMM (both streams, z) + fused attention scores, BK=64 ----------------
// Outputs INTERLEAVED: hbI[n][z][256], a_sI[n][z][4], a_dI[n][z][4].
__global__ __launch_bounds__(256, 2) void proj_kernel(
    const unsigned short* __restrict__ xib, const unsigned short* __restrict__ Wgt_l,
    unsigned short* __restrict__ hbI, const float* __restrict__ asr_l,
    const float* __restrict__ ads_l, float* __restrict__ a_sI, float* __restrict__ a_dI) {
  __shared__ __align__(16) unsigned short sA[128 * 64];
  __shared__ __align__(16) unsigned short sB[64 * 64];
  const int K = 256;
  const size_t ZS = (size_t)Nn * Dm;
  int tid = threadIdx.x;
  int wave = tid >> 6, lane = tid & 63;
  int l16 = lane & 15, lhi = lane >> 4;
  int brow = blockIdx.x, bcol = blockIdx.y, z = blockIdx.z;
  int wm = wave >> 1, wn = wave & 1;  // wave tile 64x32

  const unsigned short* Ab = xib + z * ZS + (size_t)brow * 128 * K;
  const unsigned short* Bb = Wgt_l + (size_t)z * 4 * 65536 + (size_t)bcol * 64 * K;
  int lrow = lane >> 3, lk = (lane & 7) * 8;

  f32x4 acc[4][2] = {};

  for (int k0 = 0; k0 < K; k0 += 64) {
#pragma unroll
    for (int r = 0; r < 4; ++r) {
      int rb = r * 32 + wave * 8;
      async_copy16(Ab + (size_t)(rb + lrow) * K + k0 + lk, &sA[rb * 64]);
      if (r < 2)
        async_copy16(Bb + (size_t)(rb + lrow) * K + k0 + lk, &sB[rb * 64]);
    }
    __syncthreads();
#pragma unroll
    for (int kk = 0; kk < 2; ++kk) {
      bf16x8 af[4], bfr[2];
#pragma unroll
      for (int mi = 0; mi < 4; ++mi)
        af[mi] = *(const bf16x8*)&sA[(wm * 64 + mi * 16 + l16) * 64 + kk * 32 + lhi * 8];
#pragma unroll
      for (int ni = 0; ni < 2; ++ni)
        bfr[ni] = *(const bf16x8*)&sB[(wn * 32 + ni * 16 + l16) * 64 + kk * 32 + lhi * 8];
#pragma unroll
      for (int mi = 0; mi < 4; ++mi)
#pragma unroll
        for (int ni = 0; ni < 2; ++ni)
          acc[mi][ni] = __builtin_amdgcn_mfma_f32_16x16x32_bf16(af[mi], bfr[ni], acc[mi][ni], 0, 0, 0);
    }
    __syncthreads();
  }

  // ---- epilogue: interleaved C store (bf16) + per-row attention-score partials ----
  const float* asr_p = asr_l + z * 1024 + bcol * 64;
  const float* ads_p = ads_l + z * 1024 + bcol * 64;
  float as0 = asr_p[wn * 32 + l16],      ad0 = ads_p[wn * 32 + l16];
  float as1 = asr_p[wn * 32 + 16 + l16], ad1 = ads_p[wn * 32 + 16 + l16];
  float* sredS = (float*)sA;        // [wm][wn][64] = 256 floats
  float* sredD = (float*)sA + 256;  // (sA dead after K loop)

#pragma unroll
  for (int mi = 0; mi < 4; ++mi) {
#pragma unroll
    for (int j = 0; j < 4; ++j) {
      int r = brow * 128 + wm * 64 + mi * 16 + lhi * 4 + j;
      float v0 = acc[mi][0][j], v1 = acc[mi][1][j];
      size_t rb = (size_t)r * 512 + z * 256 + bcol * 64 + wn * 32;
      hbI[rb + l16] = f2bf(v0);
      hbI[rb + 16 + l16] = f2bf(v1);
      float ps = v0 * as0 + v1 * as1;
      float pd = v0 * ad0 + v1 * ad1;
#pragma unroll
      for (int off = 1; off < 16; off <<= 1) {
        ps += __shfl_xor(ps, off);
        pd += __shfl_xor(pd, off);
      }
      if (l16 == 0) {
        int rl = mi * 16 + lhi * 4 + j;  // row within wave tile [0,64)
        sredS[wm * 128 + wn * 64 + rl] = ps;
        sredD[wm * 128 + wn * 64 + rl] = pd;
      }
    }
  }
  __syncthreads();
  if (tid < 128) {
    int w = tid >> 6, rl = tid & 63;
    float s = sredS[w * 128 + rl] + sredS[w * 128 + 64 + rl];
    float d = sredD[w * 128 + rl] + sredD[w * 128 + 64 + rl];
    int row = brow * 128 + tid;
    a_sI[(size_t)row * 8 + z * 4 + bcol] = s;
    a_dI[(size_t)row * 8 + z * 4 + bcol] = d;
  }
}

// ---------------- FFN1: f = relu(x1 @ W1 + b1), BK=64, BM=BN=128, z=stream ----------------
__global__ __launch_bounds__(256, 2) void ffn1_kernel(
    const unsigned short* __restrict__ A2, const unsigned short* __restrict__ Bt_l,
    unsigned short* __restrict__ out2, const float* __restrict__ b1_l) {
  const int K = 256, Ncol = Ff;
  const size_t ZS = (size_t)Nn * Dm;
  __shared__ __align__(16) unsigned short sA[128 * 64];
  __shared__ __align__(16) unsigned short sB[128 * 64];
  int tid = threadIdx.x, wave = tid >> 6, lane = tid & 63;
  int l16 = lane & 15, lhi = lane >> 4;
  int brow = blockIdx.x, bcol = blockIdx.y, z = blockIdx.z;
  int wm = wave >> 1, wn = wave & 1;  // wave tile 64x64

  const unsigned short* Ab = A2 + z * ZS + (size_t)brow * 128 * K;
  const unsigned short* Bb = Bt_l + (size_t)z * 4 * Ff * 256 + (size_t)bcol * 128 * K;
  int lrow = lane >> 3, lk = (lane & 7) * 8;

  f32x4 acc[4][4] = {};

  for (int k0 = 0; k0 < K; k0 += 64) {
#pragma unroll
    for (int r = 0; r < 4; ++r) {
      int rb = r * 32 + wave * 8;
      async_copy16(Ab + (size_t)(rb + lrow) * K + k0 + lk, &sA[rb * 64]);
      async_copy16(Bb + (size_t)(rb + lrow) * K + k0 + lk, &sB[rb * 64]);
    }
    __syncthreads();
#pragma unroll
    for (int kk = 0; kk < 2; ++kk) {
      bf16x8 af[4], bfr[4];
#pragma unroll
      for (int mi = 0; mi < 4; ++mi)
        af[mi] = *(const bf16x8*)&sA[(wm * 64 + mi * 16 + l16) * 64 + kk * 32 + lhi * 8];
#pragma unroll
      for (int ni = 0; ni < 4; ++ni)
        bfr[ni] = *(const bf16x8*)&sB[(wn * 64 + ni * 16 + l16) * 64 + kk * 32 + lhi * 8];
#pragma unroll
      for (int mi = 0; mi < 4; ++mi)
#pragma unroll
        for (int ni = 0; ni < 4; ++ni)
          acc[mi][ni] = __builtin_amdgcn_mfma_f32_16x16x32_bf16(af[mi], bfr[ni], acc[mi][ni], 0, 0, 0);
    }
    __syncthreads();
  }

  unsigned short* outB = out2 + (size_t)z * Nn * Ff;
  const float* bias = b1_l + z * 4096;
#pragma unroll
  for (int mi = 0; mi < 4; ++mi) {
#pragma unroll
    for (int ni = 0; ni < 4; ++ni) {
#pragma unroll
      for (int j = 0; j < 4; ++j) {
        int r = brow * 128 + wm * 64 + mi * 16 + lhi * 4 + j;
        int c = bcol * 128 + wn * 64 + ni * 16 + l16;
        float v = acc[mi][ni][j] + bias[c];
        v = v > 0.f ? v : 0.f;
        outB[(size_t)r * Ncol + c] = f2bf(v);
      }
    }
  }
}

// ---------------- FFN2: t = f @ W2 + b2 + x1 (bf16 resid), bf16 out, BK=64, BN=64 ----------------
__global__ __launch_bounds__(256, 2) void ffn2_kernel(
    const unsigned short* __restrict__ A2, const unsigned short* __restrict__ Bt_l,
    unsigned short* __restrict__ out2, const float* __restrict__ b2_l,
    const unsigned short* __restrict__ resid2) {
  const int K = Ff, Ncol = 256;
  const size_t ZS = (size_t)Nn * Dm;
  __shared__ __align__(16) unsigned short sA[128 * 64];
  __shared__ __align__(16) unsigned short sB[64 * 64];
  int tid = threadIdx.x, wave = tid >> 6, lane = tid & 63;
  int l16 = lane & 15, lhi = lane >> 4;
  int brow = blockIdx.x, bcol = blockIdx.y, z = blockIdx.z;
  int wm = wave >> 1, wn = wave & 1;  // wave tile 64x32

  const unsigned short* Ab = A2 + (size_t)z * Nn * Ff + (size_t)brow * 128 * K;
  const unsigned short* Bb = Bt_l + (size_t)z * 4 * Ff * 256 + (size_t)bcol * 64 * K;
  int lrow = lane >> 3, lk = (lane & 7) * 8;

  f32x4 acc[4][2] = {};

  for (int k0 = 0; k0 < K; k0 += 64) {
#pragma unroll
    for (int r = 0; r < 4; ++r) {
      int rb = r * 32 + wave * 8;
      async_copy16(Ab + (size_t)(rb + lrow) * K + k0 + lk, &sA[rb * 64]);
      if (r < 2)
        async_copy16(Bb + (size_t)(rb + lrow) * K + k0 + lk, &sB[rb * 64]);
    }
    __syncthreads();
#pragma unroll
    for (int kk = 0; kk < 2; ++kk) {
      bf16x8 af[4], bfr[2];
#pragma unroll
      for (int mi = 0; mi < 4; ++mi)
        af[mi] = *(const bf16x8*)&sA[(wm * 64 + mi * 16 + l16) * 64 + kk * 32 + lhi * 8];
#pragma unroll
      for (int ni = 0; ni < 2; ++ni)
        bfr[ni] = *(const bf16x8*)&sB[(wn * 32 + ni * 16 + l16) * 64 + kk * 32 + lhi * 8];
#pragma unroll
      for (int mi = 0; mi < 4; ++mi)
#pragma unroll
        for (int ni = 0; ni < 2; ++ni)
          acc[mi][ni] = __builtin_amdgcn_mfma_f32_16x16x32_bf16(af[mi], bfr[ni], acc[mi][ni], 0, 0, 0);
    }
    __syncthreads();
  }

  unsigned short* outB = out2 + z * ZS;
  const float* bias = b2_l + z * 1024;
  const unsigned short* resid = resid2 + z * ZS;
#pragma unroll
  for (int mi = 0; mi < 4; ++mi) {
#pragma unroll
    for (int ni = 0; ni < 2; ++ni) {
#pragma unroll
      for (int j = 0; j < 4; ++j) {
        int r = brow * 128 + wm * 64 + mi * 16 + lhi * 4 + j;
        int c = bcol * 64 + wn * 32 + ni * 16 + l16;
        float v = acc[mi][ni][j] + bias[c] + bf2f(resid[(size_t)r * Ncol + c]);
        outB[(size_t)r * Ncol + c] = f2bf(v);
      }
    }
  }
}

// ---------------- wave-per-node DUAL-STREAM fused softmax + agg + bias + resid + LN1 ----------------
// One wave handles node n for BOTH streams: per edge, two adjacent 512B rows (1KB granule).
// 4 waves/block. Barrier-free. Fast path for deg <= 64.
__global__ __launch_bounds__(256) void agg_kernel(
    const unsigned short* __restrict__ hbI, const float* __restrict__ a_sI,
    const float* __restrict__ a_dI,
    const int* __restrict__ rowptr, const int* __restrict__ csrc,
    const float* __restrict__ bias_l, const unsigned short* __restrict__ x01b,
    const float* __restrict__ g1_l, const float* __restrict__ bt1_l,
    unsigned short* __restrict__ x1b2) {
  __shared__ float sw[4][576];  // [wave][slot*9 + z*4 + head]  (stride 9: conflict-free)
  __shared__ int ssrc[4][64];
  const size_t ZS = (size_t)Nn * Dm;

  int wave = threadIdx.x >> 6, lane = threadIdx.x & 63;
  int n = blockIdx.x * 4 + wave;
  int l32 = lane & 31;
  int par = lane >> 5;         // edge parity
  int hch = l32 >> 3;          // head of my channel block
  int c0 = l32 * 8;            // my 8 channels
  int beg = rowptr[n], end = rowptr[n + 1];
  float4 adv0 = *(const float4*)&a_dI[n * 8];
  float4 adv1 = *(const float4*)&a_dI[n * 8 + 4];
  const float NI = -__builtin_inff();
  float acc0[8] = {}, acc1[8] = {};
  float den0 = 0.f, den1 = 0.f;

  if (end - beg <= 64) {
    // ---- fast path: single chunk, no online rescale ----
    int cnt = end - beg;
    float4 ev0 = {NI, NI, NI, NI}, ev1 = {NI, NI, NI, NI};
    if (lane < cnt) {
      int s = csrc[beg + lane];
      ssrc[wave][lane] = s;
      ev0 = lrelu4(*(const float4*)&a_sI[s * 8], adv0);
      ev1 = lrelu4(*(const float4*)&a_sI[s * 8 + 4], adv1);
    }
    float4 mv0 = ev0, mv1 = ev1;
#pragma unroll
    for (int off = 32; off; off >>= 1) {
      mv0.x = fmaxf(mv0.x, __shfl_xor(mv0.x, off));
      mv0.y = fmaxf(mv0.y, __shfl_xor(mv0.y, off));
      mv0.z = fmaxf(mv0.z, __shfl_xor(mv0.z, off));
      mv0.w = fmaxf(mv0.w, __shfl_xor(mv0.w, off));
      mv1.x = fmaxf(mv1.x, __shfl_xor(mv1.x, off));
      mv1.y = fmaxf(mv1.y, __shfl_xor(mv1.y, off));
      mv1.z = fmaxf(mv1.z, __shfl_xor(mv1.z, off));
      mv1.w = fmaxf(mv1.w, __shfl_xor(mv1.w, off));
    }
    if (lane < cnt) {
      float* swl = &sw[wave][lane * 9];
      swl[0] = __expf(ev0.x - mv0.x); swl[1] = __expf(ev0.y - mv0.y);
      swl[2] = __expf(ev0.z - mv0.z); swl[3] = __expf(ev0.w - mv0.w);
      swl[4] = __expf(ev1.x - mv1.x); swl[5] = __expf(ev1.y - mv1.y);
      swl[6] = __expf(ev1.z - mv1.z); swl[7] = __expf(ev1.w - mv1.w);
    }
    __builtin_amdgcn_wave_barrier();
    for (int i = par; i < cnt; i += 2) {
      int s_i = ssrc[wave][i];
      float w0 = sw[wave][i * 9 + hch];
      float w1 = sw[wave][i * 9 + 4 + hch];
      const unsigned short* rowp = hbI + (size_t)s_i * 512 + c0;
      bf16x8 h0 = *(const bf16x8*)rowp;
      bf16x8 h1 = *(const bf16x8*)(rowp + 256);
#pragma unroll
      for (int j = 0; j < 8; ++j)
        acc0[j] = fmaf(bf2f((unsigned short)h0[j]), w0, acc0[j]);
#pragma unroll
      for (int j = 0; j < 8; ++j)
        acc1[j] = fmaf(bf2f((unsigned short)h1[j]), w1, acc1[j]);
      den0 += w0;
      den1 += w1;
    }
  } else {
    // ---- general path: online softmax over 64-edge chunks ----
    float4 m40 = {NI, NI, NI, NI}, m41 = {NI, NI, NI, NI};
    for (int base = beg; base < end; base += 64) {
      int cnt = min(64, end - base);
      float4 ev0 = {NI, NI, NI, NI}, ev1 = {NI, NI, NI, NI};
      if (lane < cnt) {
        int s = csrc[base + lane];
        ssrc[wave][lane] = s;
        ev0 = lrelu4(*(const float4*)&a_sI[s * 8], adv0);
        ev1 = lrelu4(*(const float4*)&a_sI[s * 8 + 4], adv1);
      }
      float4 mv0 = ev0, mv1 = ev1;
#pragma unroll
      for (int off = 32; off; off >>= 1) {
        mv0.x = fmaxf(mv0.x, __shfl_xor(mv0.x, off));
        mv0.y = fmaxf(mv0.y, __shfl_xor(mv0.y, off));
        mv0.z = fmaxf(mv0.z, __shfl_xor(mv0.z, off));
        mv0.w = fmaxf(mv0.w, __shfl_xor(mv0.w, off));
        mv1.x = fmaxf(mv1.x, __shfl_xor(mv1.x, off));
        mv1.y = fmaxf(mv1.y, __shfl_xor(mv1.y, off));
        mv1.z = fmaxf(mv1.z, __shfl_xor(mv1.z, off));
        mv1.w = fmaxf(mv1.w, __shfl_xor(mv1.w, off));
      }
      float4 m40n, m41n;
      m40n.x = fmaxf(m40.x, mv0.x); m40n.y = fmaxf(m40.y, mv0.y);
      m40n.z = fmaxf(m40.z, mv0.z); m40n.w = fmaxf(m40.w, mv0.w);
      m41n.x = fmaxf(m41.x, mv1.x); m41n.y = fmaxf(m41.y, mv1.y);
      m41n.z = fmaxf(m41.z, mv1.z); m41n.w = fmaxf(m41.w, mv1.w);
      float rm0 = __expf(sel4(m40, hch) - sel4(m40n, hch));
      float rm1 = __expf(sel4(m41, hch) - sel4(m41n, hch));
#pragma unroll
      for (int j = 0; j < 8; ++j) { acc0[j] *= rm0; acc1[j] *= rm1; }
      den0 *= rm0;
      den1 *= rm1;
      if (lane < cnt) {
        float* swl = &sw[wave][lane * 9];
        swl[0] = __expf(ev0.x - m40n.x); swl[1] = __expf(ev0.y - m40n.y);
        swl[2] = __expf(ev0.z - m40n.z); swl[3] = __expf(ev0.w - m40n.w);
        swl[4] = __expf(ev1.x - m41n.x); swl[5] = __expf(ev1.y - m41n.y);
        swl[6] = __expf(ev1.z - m41n.z); swl[7] = __expf(ev1.w - m41n.w);
      }
      m40 = m40n;
      m41 = m41n;
      __builtin_amdgcn_wave_barrier();
      for (int i = par; i < cnt; i += 2) {
        int s_i = ssrc[wave][i];
        float w0 = sw[wave][i * 9 + hch];
        float w1 = sw[wave][i * 9 + 4 + hch];
        const unsigned short* rowp = hbI + (size_t)s_i * 512 + c0;
        bf16x8 h0 = *(const bf16x8*)rowp;
        bf16x8 h1 = *(const bf16x8*)(rowp + 256);
#pragma unroll
        for (int j = 0; j < 8; ++j)
          acc0[j] = fmaf(bf2f((unsigned short)h0[j]), w0, acc0[j]);
#pragma unroll
        for (int j = 0; j < 8; ++j)
          acc1[j] = fmaf(bf2f((unsigned short)h1[j]), w1, acc1[j]);
        den0 += w0;
        den1 += w1;
      }
      __builtin_amdgcn_wave_barrier();
    }
  }

  // combine edge parities (lane ^ 32 holds same channels, other parity)
#pragma unroll
  for (int j = 0; j < 8; ++j) {
    acc0[j] += __shfl_xor(acc0[j], 32);
    acc1[j] += __shfl_xor(acc1[j], 32);
  }
  den0 += __shfl_xor(den0, 32);
  den1 += __shfl_xor(den1, 32);

  float invden0 = 1.f / fmaxf(den0, 1e-16f);
  float invden1 = 1.f / fmaxf(den1, 1e-16f);
  bf16x8 rv0 = *(const bf16x8*)(x01b + (size_t)n * 256 + c0);
  bf16x8 rv1 = *(const bf16x8*)(x01b + ZS + (size_t)n * 256 + c0);
  float outv0[8], outv1[8];
  float s10 = 0.f, s20 = 0.f, s11 = 0.f, s21 = 0.f;
#pragma unroll
  for (int j = 0; j < 8; ++j) {
    float v0 = acc0[j] * invden0 + bias_l[c0 + j] + bf2f((unsigned short)rv0[j]);
    float v1 = acc1[j] * invden1 + bias_l[1024 + c0 + j] + bf2f((unsigned short)rv1[j]);
    outv0[j] = v0; outv1[j] = v1;
    s10 += v0; s20 += v0 * v0;
    s11 += v1; s21 += v1 * v1;
  }
  // LN reduce over the 32-lane half (halves hold identical data)
#pragma unroll
  for (int off = 16; off; off >>= 1) {
    s10 += __shfl_xor(s10, off);
    s20 += __shfl_xor(s20, off);
    s11 += __shfl_xor(s11, off);
    s21 += __shfl_xor(s21, off);
  }
  float mean0 = s10 * (1.f / 256.f);
  float var0 = s20 * (1.f / 256.f) - mean0 * mean0;
  float rst0 = rsqrtf(var0 + 1e-5f);
  float mean1 = s11 * (1.f / 256.f);
  float var1 = s21 * (1.f / 256.f) - mean1 * mean1;
  float rst1 = rsqrtf(var1 + 1e-5f);
  if (par == 0) {
    unsigned short yb0[8], yb1[8];
#pragma unroll
    for (int j = 0; j < 8; ++j) {
      yb0[j] = f2bf((outv0[j] - mean0) * rst0 * g1_l[c0 + j] + bt1_l[c0 + j]);
      yb1[j] = f2bf((outv1[j] - mean1) * rst1 * g1_l[1024 + c0 + j] + bt1_l[1024 + c0 + j]);
    }
    *(bf16x8*)&x1b2[(size_t)n * 256 + c0] = *(bf16x8*)yb0;
    *(bf16x8*)&x1b2[ZS + (size_t)n * 256 + c0] = *(bf16x8*)yb1;
  }
}

// ---------------- dual LN2 (wave per node) + optional next-layer prep ----------------
template <int PREP>
__global__ __launch_bounds__(256) void ln2_kernel(const unsigned short* __restrict__ tb2,
                                                  const float* __restrict__ g2_l,
                                                  const float* __restrict__ bt2_l,
                                                  float* __restrict__ out_hf,
                                                  float* __restrict__ out_hs,
                                                  unsigned short* __restrict__ x01b) {
  const size_t ZS = (size_t)Nn * Dm;
  int wave = threadIdx.x >> 6, lane = threadIdx.x & 63;
  int n = blockIdx.x * 4 + wave;
  int c0 = lane * 4;
  size_t idx = (size_t)n * 256 + c0;
  ushort4 u0 = *(const ushort4*)&tb2[idx];
  ushort4 u1 = *(const ushort4*)&tb2[ZS + idx];
  float v0[4] = {bf2f(u0.x), bf2f(u0.y), bf2f(u0.z), bf2f(u0.w)};
  float v1[4] = {bf2f(u1.x), bf2f(u1.y), bf2f(u1.z), bf2f(u1.w)};
  float a0 = 0.f, b0 = 0.f, a1 = 0.f, b1 = 0.f;
#pragma unroll
  for (int j = 0; j < 4; ++j) {
    a0 += v0[j]; b0 += v0[j] * v0[j];
    a1 += v1[j]; b1 += v1[j] * v1[j];
  }
#pragma unroll
  for (int off = 32; off; off >>= 1) {
    a0 += __shfl_xor(a0, off);
    b0 += __shfl_xor(b0, off);
    a1 += __shfl_xor(a1, off);
    b1 += __shfl_xor(b1, off);
  }
  float m0 = a0 * (1.f / 256.f), m1 = a1 * (1.f / 256.f);
  float r0 = rsqrtf(b0 * (1.f / 256.f) - m0 * m0 + 1e-5f);
  float r1 = rsqrtf(b1 * (1.f / 256.f) - m1 * m1 + 1e-5f);
  float4 y0, y1;
  unsigned short p0[4], p1[4];
#pragma unroll
  for (int j = 0; j < 4; ++j) {
    float yf = (v0[j] - m0) * r0 * g2_l[c0 + j] + bt2_l[c0 + j];
    float ys = (v1[j] - m1) * r1 * g2_l[1024 + c0 + j] + bt2_l[1024 + c0 + j];
    ((float*)&y0)[j] = yf;
    ((float*)&y1)[j] = ys;
    if (PREP) { p0[j] = f2bf(yf + ys); p1[j] = f2bf(ys); }
  }
  *(float4*)&out_hf[idx] = y0;
  *(float4*)&out_hs[idx] = y1;
  if (PREP) {
    *(ushort4*)&x01b[idx] = *(ushort4*)p0;
    *(ushort4*)&x01b[ZS + idx] = *(ushort4*)p1;
  }
}

extern "C" void kernel_launch(void* const* d_in, const int* in_sizes, int n_in,
                              void* d_out, int out_size, void* d_ws, size_t ws_size,
                              hipStream_t stream) {
  const float* hf_in = (const float*)d_in[0];
  const float* hs_in = (const float*)d_in[1];
  const int* ei = (const int*)d_in[2];
  const int E = in_sizes[2] / 2;
  const float* Wgat = (const float*)d_in[3];
  const float* att_src = (const float*)d_in[4];
  const float* att_dst = (const float*)d_in[5];
  const float* bias_gat = (const float*)d_in[6];
  const float* W1 = (const float*)d_in[7];
  const float* b1 = (const float*)d_in[8];
  const float* W2 = (const float*)d_in[9];
  const float* b2 = (const float*)d_in[10];
  const float* g1 = (const float*)d_in[11];
  const float* bt1 = (const float*)d_in[12];
  const float* g2 = (const float*)d_in[13];
  const float* bt2 = (const float*)d_in[14];
  const int* src = ei;
  const int* dst = ei + E;
  const size_t ZS = (size_t)Nn * Dm;

  // ---- carve workspace ----
  char* wsp = (char*)d_ws;
  size_t off = 0;
  auto carve = [&](size_t bytes) -> void* {
    void* p = wsp + off;
    off += (bytes + 255) & ~(size_t)255;
    return p;
  };
  unsigned short* Wgt  = (unsigned short*)carve((size_t)8 * 256 * 256 * 2);
  unsigned short* W1t  = (unsigned short*)carve((size_t)8 * 256 * 1024 * 2);
  unsigned short* W2t  = (unsigned short*)carve((size_t)8 * 1024 * 256 * 2);
  int* cnt      = (int*)carve((size_t)Nn * 4);
  int* rowptr   = (int*)carve((size_t)(Nn + 1) * 4);
  int* cursor   = (int*)carve((size_t)Nn * 4);
  int* part     = (int*)carve((size_t)Nn * 4);
  int* bsum     = (int*)carve((size_t)64 * 4);
  int* bbase    = (int*)carve((size_t)64 * 4);
  int* csrc     = (int*)carve((size_t)E * 4);
  unsigned short* x01b = (unsigned short*)carve(2 * ZS * 2);  // [z]: layer input bf16
  unsigned short* hbI  = (unsigned short*)carve(2 * ZS * 2);  // [n][z][256] interleaved
  float* a_sI   = (float*)carve((size_t)Nn * 8 * 4);          // [n][z][4]
  float* a_dI   = (float*)carve((size_t)Nn * 8 * 4);
  unsigned short* x1b2 = (unsigned short*)carve(2 * ZS * 2);  // [z]: LN1 out bf16
  unsigned short* tb2  = (unsigned short*)carve(2 * ZS * 2);  // [z]: FFN2 out (pre-LN2) bf16
  unsigned short* f_b2 = (unsigned short*)carve((size_t)2 * Nn * Ff * 2);  // [z]: FFN1 out
  if (off > ws_size) return;  // workspace too small — fail visibly

  // ---- once per call: weights (tiled transpose) + CSR ----
  wconvt_kernel<<<dim3(4, 4, 8), 256, 0, stream>>>(Wgat, Wgt, 256, 256);
  wconvt_kernel<<<dim3(16, 4, 8), 256, 0, stream>>>(W1, W1t, 256, 1024);
  wconvt_kernel<<<dim3(4, 16, 8), 256, 0, stream>>>(W2, W2t, 1024, 256);
  hipMemsetAsync(cnt, 0, (size_t)Nn * 4, stream);
  count_kernel<<<1024, 256, 0, stream>>>(dst, E, cnt);
  scan1_kernel<<<64, 256, 0, stream>>>(cnt, part, bsum);
  scan2_kernel<<<1, 64, 0, stream>>>(bsum, bbase, rowptr);
  scan3_kernel<<<64, 256, 0, stream>>>(part, bbase, rowptr, cursor);
  fill_kernel<<<1024, 256, 0, stream>>>(src, dst, E, cursor, csrc);

  float* out_hf = (float*)d_out;
  float* out_hs = out_hf + ZS;

  prep_kernel<<<2048, 256, 0, stream>>>(hf_in, hs_in, x01b, Nn * Dm);

  for (int l = 0; l < 4; ++l) {
    // proj (both streams) + fused scores -> interleaved h, a_s, a_d
    proj_kernel<<<dim3(128, 4, 2), 256, 0, stream>>>(
        x01b, Wgt + (size_t)l * 65536, hbI,
        att_src + l * 256, att_dst + l * 256, a_sI, a_dI);
    // dual-stream segment softmax + aggregate + bias + residual + LN1
    agg_kernel<<<Nn / 4, 256, 0, stream>>>(
        hbI, a_sI, a_dI, rowptr, csrc,
        bias_gat + l * 256, x01b, g1 + l * 256, bt1 + l * 256, x1b2);
    // FFN (both streams per dispatch)
    ffn1_kernel<<<dim3(128, 8, 2), 256, 0, stream>>>(
        x1b2, W1t + (size_t)l * 256 * 1024, f_b2, b1 + l * 1024);
    ffn2_kernel<<<dim3(128, 4, 2), 256, 0, stream>>>(
        f_b2, W2t + (size_t)l * 1024 * 256, tb2, b2 + l * 256, x1b2);
    // dual LN2 -> states (+ next-layer prep for l<3)
    if (l < 3) {
      ln2_kernel<1><<<Nn / 4, 256, 0, stream>>>(tb2, g2 + l * 256, bt2 + l * 256,
                                                out_hf, out_hs, x01b);
    } else {
      ln2_kernel<0><<<Nn / 4, 256, 0, stream>>>(tb2, g2 + l * 256, bt2 + l * 256,
                                                out_hf, out_hs, x01b);
    }
  }
}

// Round 10
// 701.734 us; speedup vs baseline: 1.0097x; 1.0097x over previous
//
#include <hip/hip_runtime.h>

#define Nn 16384
#define Dm 256
#define Ff 1024

typedef __attribute__((ext_vector_type(8))) short bf16x8;
typedef __attribute__((ext_vector_type(4))) float f32x4;

typedef const __attribute__((address_space(1))) unsigned int glb_u32;
typedef __attribute__((address_space(3))) unsigned int lds_u32;

__device__ __forceinline__ void async_copy16(const void* g, void* l) {
  __builtin_amdgcn_global_load_lds((glb_u32*)g, (lds_u32*)l, 16, 0, 0);
}

__device__ __forceinline__ unsigned short f2bf(float f) {
  union { float f; unsigned u; } v; v.f = f;
  return (unsigned short)((v.u + 0x7FFFu + ((v.u >> 16) & 1u)) >> 16);
}

__device__ __forceinline__ float bf2f(unsigned short u) {
  union { unsigned u; float f; } v; v.u = ((unsigned)u) << 16;
  return v.f;
}

__device__ __forceinline__ float sel4(float4 v, int h) {
  float r = v.x;
  r = (h == 1) ? v.y : r;
  r = (h == 2) ? v.z : r;
  r = (h == 3) ? v.w : r;
  return r;
}

// ---------------- tiled weight convert+transpose: wt[b][j][k] = bf16(w[b][k][j]) ----------------
__global__ __launch_bounds__(256) void wconvt_kernel(const float* __restrict__ w,
                                                     unsigned short* __restrict__ wt,
                                                     int K, int J) {
  __shared__ unsigned short t[64][65];
  int b = blockIdx.z;
  int j0 = blockIdx.x * 64, k0 = blockIdx.y * 64;
  int tj = threadIdx.x & 63, q = threadIdx.x >> 6;  // 4 rows per pass
  const float* wb = w + (size_t)b * K * J;
#pragma unroll
  for (int r = 0; r < 16; ++r) {
    int k = r * 4 + q;
    t[k][tj] = f2bf(wb[(size_t)(k0 + k) * J + j0 + tj]);
  }
  __syncthreads();
  unsigned short* wtb = wt + (size_t)b * K * J;
#pragma unroll
  for (int r = 0; r < 16; ++r) {
    int j = r * 4 + q;
    wtb[(size_t)(j0 + j) * K + k0 + tj] = t[tj][j];
  }
}

// ---------------- CSR build ----------------
__global__ void count_kernel(const int* __restrict__ dst, int E, int* __restrict__ cnt) {
  for (int e = blockIdx.x * blockDim.x + threadIdx.x; e < E; e += gridDim.x * blockDim.x)
    atomicAdd(&cnt[dst[e]], 1);
}

__global__ __launch_bounds__(256) void scan1_kernel(const int* __restrict__ cnt,
                                                    int* __restrict__ part,
                                                    int* __restrict__ bsum) {
  __shared__ int sd[256];
  int b = blockIdx.x, tid = threadIdx.x;
  int v = cnt[b * 256 + tid];
  sd[tid] = v;
  __syncthreads();
  for (int offt = 1; offt < 256; offt <<= 1) {
    int t = (tid >= offt) ? sd[tid - offt] : 0;
    __syncthreads();
    sd[tid] += t;
    __syncthreads();
  }
  part[b * 256 + tid] = sd[tid] - v;  // exclusive
  if (tid == 255) bsum[b] = sd[255];
}

__global__ __launch_bounds__(64) void scan2_kernel(const int* __restrict__ bsum,
                                                   int* __restrict__ bbase,
                                                   int* __restrict__ rowptr) {
  __shared__ int sd[64];
  int tid = threadIdx.x;
  int v = bsum[tid];
  sd[tid] = v;
  __syncthreads();
  for (int offt = 1; offt < 64; offt <<= 1) {
    int t = (tid >= offt) ? sd[tid - offt] : 0;
    __syncthreads();
    sd[tid] += t;
    __syncthreads();
  }
  bbase[tid] = sd[tid] - v;
  if (tid == 63) rowptr[Nn] = sd[63];
}

__global__ __launch_bounds__(256) void scan3_kernel(const int* __restrict__ part,
                                                    const int* __restrict__ bbase,
                                                    int* __restrict__ rowptr,
                                                    int* __restrict__ cursor) {
  int b = blockIdx.x, tid = threadIdx.x;
  int v = part[b * 256 + tid] + bbase[b];
  rowptr[b * 256 + tid] = v;
  cursor[b * 256 + tid] = v;
}

__global__ void fill_kernel(const int* __restrict__ src, const int* __restrict__ dst, int E,
                            int* __restrict__ cursor, int* __restrict__ csrc) {
  for (int e = blockIdx.x * blockDim.x + threadIdx.x; e < E; e += gridDim.x * blockDim.x) {
    int pos = atomicAdd(&cursor[dst[e]], 1);
    csrc[pos] = src[e];
  }
}

// ---------------- initial input prep (layer 0): x01b[0]=bf16(hf+hs), x01b[1]=bf16(hs) ----------------
__global__ void prep_kernel(const float* __restrict__ hf, const float* __restrict__ hs,
                            unsigned short* __restrict__ x01b, int total) {
  const size_t ZS = (size_t)Nn * Dm;
  for (int i = blockIdx.x * blockDim.x + threadIdx.x; i < total; i += gridDim.x * blockDim.x) {
    float a = hf[i], b = hs[i];
    x01b[i] = f2bf(a + b);
    x01b[ZS + i] = f2bf(b);
  }
}

// ---------------- proj GEMM (both streams, z) + fused scores, BK=64, double-buffered ----------------
__global__ __launch_bounds__(256, 2) void proj_kernel(
    const unsigned short* __restrict__ xib, const unsigned short* __restrict__ Wgt_l,
    unsigned short* __restrict__ hbuf2, const float* __restrict__ asr_l,
    const float* __restrict__ ads_l, float* __restrict__ a_s2, float* __restrict__ a_d2) {
  __shared__ __align__(16) unsigned short sA[2][128 * 64];
  __shared__ __align__(16) unsigned short sB[2][64 * 64];
  const int K = 256;
  const size_t ZS = (size_t)Nn * Dm;
  int tid = threadIdx.x;
  int wave = tid >> 6, lane = tid & 63;
  int l16 = lane & 15, lhi = lane >> 4;
  int brow = blockIdx.x, bcol = blockIdx.y, z = blockIdx.z;
  int wm = wave >> 1, wn = wave & 1;  // wave tile 64x32

  const unsigned short* Ab = xib + z * ZS + (size_t)brow * 128 * K;
  const unsigned short* Bb = Wgt_l + (size_t)z * 4 * 65536 + (size_t)bcol * 64 * K;
  int lrow = lane >> 3, lk = (lane & 7) * 8;

  f32x4 acc[4][2] = {};

  auto stage = [&](int buf, int k0) {
#pragma unroll
    for (int r = 0; r < 4; ++r) {
      int rb = r * 32 + wave * 8;
      async_copy16(Ab + (size_t)(rb + lrow) * K + k0 + lk, &sA[buf][rb * 64]);
      if (r < 2)
        async_copy16(Bb + (size_t)(rb + lrow) * K + k0 + lk, &sB[buf][rb * 64]);
    }
  };

  stage(0, 0);
  __syncthreads();
  int cur = 0;
#pragma unroll
  for (int t = 0; t < 4; ++t) {
    if (t < 3) stage(cur ^ 1, (t + 1) * 64);
#pragma unroll
    for (int kk = 0; kk < 2; ++kk) {
      bf16x8 af[4], bfr[2];
#pragma unroll
      for (int mi = 0; mi < 4; ++mi)
        af[mi] = *(const bf16x8*)&sA[cur][(wm * 64 + mi * 16 + l16) * 64 + kk * 32 + lhi * 8];
#pragma unroll
      for (int ni = 0; ni < 2; ++ni)
        bfr[ni] = *(const bf16x8*)&sB[cur][(wn * 32 + ni * 16 + l16) * 64 + kk * 32 + lhi * 8];
#pragma unroll
      for (int mi = 0; mi < 4; ++mi)
#pragma unroll
        for (int ni = 0; ni < 2; ++ni)
          acc[mi][ni] = __builtin_amdgcn_mfma_f32_16x16x32_bf16(af[mi], bfr[ni], acc[mi][ni], 0, 0, 0);
    }
    __syncthreads();
    cur ^= 1;
  }

  // ---- epilogue: C store (bf16) + per-row attention-score partials ----
  unsigned short* hb = hbuf2 + z * ZS;
  const float* asr_p = asr_l + z * 1024 + bcol * 64;
  const float* ads_p = ads_l + z * 1024 + bcol * 64;
  float as0 = asr_p[wn * 32 + l16],      ad0 = ads_p[wn * 32 + l16];
  float as1 = asr_p[wn * 32 + 16 + l16], ad1 = ads_p[wn * 32 + 16 + l16];
  float* sredS = (float*)sA;        // scratch (sA dead after K loop; last iter ended in barrier)
  float* sredD = (float*)sA + 256;

#pragma unroll
  for (int mi = 0; mi < 4; ++mi) {
#pragma unroll
    for (int j = 0; j < 4; ++j) {
      int r = brow * 128 + wm * 64 + mi * 16 + lhi * 4 + j;
      float v0 = acc[mi][0][j], v1 = acc[mi][1][j];
      hb[(size_t)r * 256 + bcol * 64 + wn * 32 + l16] = f2bf(v0);
      hb[(size_t)r * 256 + bcol * 64 + wn * 32 + 16 + l16] = f2bf(v1);
      float ps = v0 * as0 + v1 * as1;
      float pd = v0 * ad0 + v1 * ad1;
#pragma unroll
      for (int off = 1; off < 16; off <<= 1) {
        ps += __shfl_xor(ps, off);
        pd += __shfl_xor(pd, off);
      }
      if (l16 == 0) {
        int rl = mi * 16 + lhi * 4 + j;  // row within wave tile [0,64)
        sredS[wm * 128 + wn * 64 + rl] = ps;
        sredD[wm * 128 + wn * 64 + rl] = pd;
      }
    }
  }
  __syncthreads();
  if (tid < 128) {
    int w = tid >> 6, rl = tid & 63;
    float s = sredS[w * 128 + rl] + sredS[w * 128 + 64 + rl];
    float d = sredD[w * 128 + rl] + sredD[w * 128 + 64 + rl];
    int row = brow * 128 + tid;
    a_s2[(size_t)z * Nn * 4 + row * 4 + bcol] = s;
    a_d2[(size_t)z * Nn * 4 + row * 4 + bcol] = d;
  }
}

// ---------------- 128x128 GEMM, BK=64, double-buffered, z=stream ----------------
// EPI 1 (FFN1): +bias, relu, bf16 out. EPI 2 (FFN2): +bias +bf16 resid, bf16 out.
template <int EPI>
__global__ __launch_bounds__(256, 2) void gemm128_kernel(
    const unsigned short* __restrict__ A2, size_t aZ,
    const unsigned short* __restrict__ Bt_l,
    unsigned short* __restrict__ out2, size_t oZ,
    const float* __restrict__ bias_l, int biasZ,
    const unsigned short* __restrict__ resid2,
    int K, int Ncol) {
  __shared__ __align__(16) unsigned short sA[2][128 * 64];
  __shared__ __align__(16) unsigned short sB[2][128 * 64];
  int tid = threadIdx.x, wave = tid >> 6, lane = tid & 63;
  int l16 = lane & 15, lhi = lane >> 4;
  int brow = blockIdx.x, bcol = blockIdx.y, z = blockIdx.z;
  int wm = wave >> 1, wn = wave & 1;  // wave tile 64x64

  const unsigned short* Ab = A2 + z * aZ + (size_t)brow * 128 * K;
  const unsigned short* Bb = Bt_l + (size_t)z * 4 * Ff * 256 + (size_t)bcol * 128 * K;
  int lrow = lane >> 3, lk = (lane & 7) * 8;

  f32x4 acc[4][4] = {};

  auto stage = [&](int buf, int k0) {
#pragma unroll
    for (int r = 0; r < 4; ++r) {
      int rb = r * 32 + wave * 8;
      async_copy16(Ab + (size_t)(rb + lrow) * K + k0 + lk, &sA[buf][rb * 64]);
      async_copy16(Bb + (size_t)(rb + lrow) * K + k0 + lk, &sB[buf][rb * 64]);
    }
  };

  int NT = K >> 6;
  stage(0, 0);
  __syncthreads();
  int cur = 0;
  for (int t = 0; t < NT; ++t) {
    if (t + 1 < NT) stage(cur ^ 1, (t + 1) * 64);
#pragma unroll
    for (int kk = 0; kk < 2; ++kk) {
      bf16x8 af[4], bfr[4];
#pragma unroll
      for (int mi = 0; mi < 4; ++mi)
        af[mi] = *(const bf16x8*)&sA[cur][(wm * 64 + mi * 16 + l16) * 64 + kk * 32 + lhi * 8];
#pragma unroll
      for (int ni = 0; ni < 4; ++ni)
        bfr[ni] = *(const bf16x8*)&sB[cur][(wn * 64 + ni * 16 + l16) * 64 + kk * 32 + lhi * 8];
#pragma unroll
      for (int mi = 0; mi < 4; ++mi)
#pragma unroll
        for (int ni = 0; ni < 4; ++ni)
          acc[mi][ni] = __builtin_amdgcn_mfma_f32_16x16x32_bf16(af[mi], bfr[ni], acc[mi][ni], 0, 0, 0);
    }
    __syncthreads();
    cur ^= 1;
  }

  unsigned short* outB = out2 + z * oZ;
  const float* bias = bias_l + z * biasZ;
  const unsigned short* resid = (EPI == 2) ? resid2 + z * oZ : nullptr;
#pragma unroll
  for (int mi = 0; mi < 4; ++mi) {
#pragma unroll
    for (int ni = 0; ni < 4; ++ni) {
#pragma unroll
      for (int j = 0; j < 4; ++j) {
        int r = brow * 128 + wm * 64 + mi * 16 + lhi * 4 + j;
        int c = bcol * 128 + wn * 64 + ni * 16 + l16;
        float v = acc[mi][ni][j] + bias[c];
        if (EPI == 1) {
          v = v > 0.f ? v : 0.f;
        } else {
          v += bf2f(resid[(size_t)r * Ncol + c]);
        }
        outB[(size_t)r * Ncol + c] = f2bf(v);
      }
    }
  }
}

// ---------------- wave-per-node fused softmax + aggregation + bias + residual + LN1 ----------------
// grid (Nn/4, 2): y = stream. 4 waves/block. Barrier-free. Fast path for deg <= 64.
__global__ __launch_bounds__(256) void agg_kernel(
    const unsigned short* __restrict__ hbuf2, const float* __restrict__ a_s2,
    const float* __restrict__ a_d2,
    const int* __restrict__ rowptr, const int* __restrict__ csrc,
    const float* __restrict__ bias_l, const unsigned short* __restrict__ x01b,
    const float* __restrict__ g1_l, const float* __restrict__ bt1_l,
    unsigned short* __restrict__ x1b2) {
  __shared__ float sw[4][320];  // [wave][slot*5 + head]  (stride 5: conflict-free)
  __shared__ int ssrc[4][64];
  const size_t ZS = (size_t)Nn * Dm;
  int z = blockIdx.y;
  const unsigned short* hb = hbuf2 + z * ZS;
  const float* a_s = a_s2 + (size_t)z * Nn * 4;
  const float* a_d = a_d2 + (size_t)z * Nn * 4;
  const float* bias = bias_l + z * 1024;
  const unsigned short* xres = x01b + z * ZS;
  const float* g1 = g1_l + z * 1024;
  const float* bt1 = bt1_l + z * 1024;
  unsigned short* x1b = x1b2 + z * ZS;

  int wave = threadIdx.x >> 6, lane = threadIdx.x & 63;
  int n = blockIdx.x * 4 + wave;
  int l32 = lane & 31;
  int par = lane >> 5;         // edge parity
  int hch = l32 >> 3;          // head of my channel block
  int c0 = l32 * 8;            // my 8 channels
  int beg = rowptr[n], end = rowptr[n + 1];
  float4 adv = *(const float4*)&a_d[n * 4];
  const float NI = -__builtin_inff();
  float acc[8] = {};
  float den = 0.f;

  if (end - beg <= 64) {
    // ---- fast path: single chunk, no online rescale ----
    int cnt = end - beg;
    float4 ev = {NI, NI, NI, NI};
    if (lane < cnt) {
      int s = csrc[beg + lane];
      ssrc[wave][lane] = s;
      float4 as = *(const float4*)&a_s[s * 4];
      float e0 = as.x + adv.x; ev.x = e0 > 0.f ? e0 : 0.2f * e0;
      float e1 = as.y + adv.y; ev.y = e1 > 0.f ? e1 : 0.2f * e1;
      float e2 = as.z + adv.z; ev.z = e2 > 0.f ? e2 : 0.2f * e2;
      float e3 = as.w + adv.w; ev.w = e3 > 0.f ? e3 : 0.2f * e3;
    }
    float4 mv = ev;
#pragma unroll
    for (int off = 32; off; off >>= 1) {
      mv.x = fmaxf(mv.x, __shfl_xor(mv.x, off));
      mv.y = fmaxf(mv.y, __shfl_xor(mv.y, off));
      mv.z = fmaxf(mv.z, __shfl_xor(mv.z, off));
      mv.w = fmaxf(mv.w, __shfl_xor(mv.w, off));
    }
    if (lane < cnt) {
      float* swl = &sw[wave][lane * 5];
      swl[0] = __expf(ev.x - mv.x);
      swl[1] = __expf(ev.y - mv.y);
      swl[2] = __expf(ev.z - mv.z);
      swl[3] = __expf(ev.w - mv.w);
    }
    __builtin_amdgcn_wave_barrier();
    for (int i = par; i < cnt; i += 2) {
      float w = sw[wave][i * 5 + hch];
      int s_i = ssrc[wave][i];
      bf16x8 hv = *(const bf16x8*)(hb + (size_t)s_i * 256 + c0);
#pragma unroll
      for (int j = 0; j < 8; ++j)
        acc[j] = fmaf(bf2f((unsigned short)hv[j]), w, acc[j]);
      den += w;
    }
  } else {
    // ---- general path: online softmax over 64-edge chunks ----
    float4 m4 = {NI, NI, NI, NI};
    for (int base = beg; base < end; base += 64) {
      int cnt = min(64, end - base);
      float4 ev = {NI, NI, NI, NI};
      if (lane < cnt) {
        int s = csrc[base + lane];
        ssrc[wave][lane] = s;
        float4 as = *(const float4*)&a_s[s * 4];
        float e0 = as.x + adv.x; ev.x = e0 > 0.f ? e0 : 0.2f * e0;
        float e1 = as.y + adv.y; ev.y = e1 > 0.f ? e1 : 0.2f * e1;
        float e2 = as.z + adv.z; ev.z = e2 > 0.f ? e2 : 0.2f * e2;
        float e3 = as.w + adv.w; ev.w = e3 > 0.f ? e3 : 0.2f * e3;
      }
      float4 mv = ev;
#pragma unroll
      for (int off = 32; off; off >>= 1) {
        mv.x = fmaxf(mv.x, __shfl_xor(mv.x, off));
        mv.y = fmaxf(mv.y, __shfl_xor(mv.y, off));
        mv.z = fmaxf(mv.z, __shfl_xor(mv.z, off));
        mv.w = fmaxf(mv.w, __shfl_xor(mv.w, off));
      }
      float4 m4n;
      m4n.x = fmaxf(m4.x, mv.x); m4n.y = fmaxf(m4.y, mv.y);
      m4n.z = fmaxf(m4.z, mv.z); m4n.w = fmaxf(m4.w, mv.w);
      float rm = __expf(sel4(m4, hch) - sel4(m4n, hch));
#pragma unroll
      for (int j = 0; j < 8; ++j) acc[j] *= rm;
      den *= rm;
      if (lane < cnt) {
        float* swl = &sw[wave][lane * 5];
        swl[0] = __expf(ev.x - m4n.x);
        swl[1] = __expf(ev.y - m4n.y);
        swl[2] = __expf(ev.z - m4n.z);
        swl[3] = __expf(ev.w - m4n.w);
      }
      m4 = m4n;
      __builtin_amdgcn_wave_barrier();
      for (int i = par; i < cnt; i += 2) {
        float w = sw[wave][i * 5 + hch];
        int s_i = ssrc[wave][i];
        bf16x8 hv = *(const bf16x8*)(hb + (size_t)s_i * 256 + c0);
#pragma unroll
        for (int j = 0; j < 8; ++j)
          acc[j] = fmaf(bf2f((unsigned short)hv[j]), w, acc[j]);
        den += w;
      }
      __builtin_amdgcn_wave_barrier();
    }
  }

  // combine edge parities (lane ^ 32 holds same channels, other parity)
#pragma unroll
  for (int j = 0; j < 8; ++j) acc[j] += __shfl_xor(acc[j], 32);
  den += __shfl_xor(den, 32);

  float invden = 1.f / fmaxf(den, 1e-16f);
  bf16x8 rv = *(const bf16x8*)(xres + (size_t)n * 256 + c0);
  float outv[8];
  float s1 = 0.f, s2 = 0.f;
#pragma unroll
  for (int j = 0; j < 8; ++j) {
    float v = acc[j] * invden + bias[c0 + j] + bf2f((unsigned short)rv[j]);
    outv[j] = v;
    s1 += v;
    s2 += v * v;
  }
  // LN reduce over the 32-lane half (halves hold identical data)
#pragma unroll
  for (int off = 16; off; off >>= 1) {
    s1 += __shfl_xor(s1, off);
    s2 += __shfl_xor(s2, off);
  }
  float mean = s1 * (1.f / 256.f);
  float var = s2 * (1.f / 256.f) - mean * mean;
  float rst = rsqrtf(var + 1e-5f);
  if (par == 0) {
    unsigned short yb[8];
#pragma unroll
    for (int j = 0; j < 8; ++j)
      yb[j] = f2bf((outv[j] - mean) * rst * g1[c0 + j] + bt1[c0 + j]);
    *(bf16x8*)&x1b[(size_t)n * 256 + c0] = *(bf16x8*)yb;
  }
}

// ---------------- dual LN2 (wave per node) + optional next-layer prep ----------------
template <int PREP>
__global__ __launch_bounds__(256) void ln2_kernel(const unsigned short* __restrict__ tb2,
                                                  const float* __restrict__ g2_l,
                                                  const float* __restrict__ bt2_l,
                                                  float* __restrict__ out_hf,
                                                  float* __restrict__ out_hs,
                                                  unsigned short* __restrict__ x01b) {
  const size_t ZS = (size_t)Nn * Dm;
  int wave = threadIdx.x >> 6, lane = threadIdx.x & 63;
  int n = blockIdx.x * 4 + wave;
  int c0 = lane * 4;
  size_t idx = (size_t)n * 256 + c0;
  ushort4 u0 = *(const ushort4*)&tb2[idx];
  ushort4 u1 = *(const ushort4*)&tb2[ZS + idx];
  float v0[4] = {bf2f(u0.x), bf2f(u0.y), bf2f(u0.z), bf2f(u0.w)};
  float v1[4] = {bf2f(u1.x), bf2f(u1.y), bf2f(u1.z), bf2f(u1.w)};
  float a0 = 0.f, b0 = 0.f, a1 = 0.f, b1 = 0.f;
#pragma unroll
  for (int j = 0; j < 4; ++j) {
    a0 += v0[j]; b0 += v0[j] * v0[j];
    a1 += v1[j]; b1 += v1[j] * v1[j];
  }
#pragma unroll
  for (int off = 32; off; off >>= 1) {
    a0 += __shfl_xor(a0, off);
    b0 += __shfl_xor(b0, off);
    a1 += __shfl_xor(a1, off);
    b1 += __shfl_xor(b1, off);
  }
  float m0 = a0 * (1.f / 256.f), m1 = a1 * (1.f / 256.f);
  float r0 = rsqrtf(b0 * (1.f / 256.f) - m0 * m0 + 1e-5f);
  float r1 = rsqrtf(b1 * (1.f / 256.f) - m1 * m1 + 1e-5f);
  float4 y0, y1;
  unsigned short p0[4], p1[4];
#pragma unroll
  for (int j = 0; j < 4; ++j) {
    float yf = (v0[j] - m0) * r0 * g2_l[c0 + j] + bt2_l[c0 + j];
    float ys = (v1[j] - m1) * r1 * g2_l[1024 + c0 + j] + bt2_l[1024 + c0 + j];
    ((float*)&y0)[j] = yf;
    ((float*)&y1)[j] = ys;
    if (PREP) { p0[j] = f2bf(yf + ys); p1[j] = f2bf(ys); }
  }
  *(float4*)&out_hf[idx] = y0;
  *(float4*)&out_hs[idx] = y1;
  if (PREP) {
    *(ushort4*)&x01b[idx] = *(ushort4*)p0;
    *(ushort4*)&x01b[ZS + idx] = *(ushort4*)p1;
  }
}

extern "C" void kernel_launch(void* const* d_in, const int* in_sizes, int n_in,
                              void* d_out, int out_size, void* d_ws, size_t ws_size,
                              hipStream_t stream) {
  const float* hf_in = (const float*)d_in[0];
  const float* hs_in = (const float*)d_in[1];
  const int* ei = (const int*)d_in[2];
  const int E = in_sizes[2] / 2;
  const float* Wgat = (const float*)d_in[3];
  const float* att_src = (const float*)d_in[4];
  const float* att_dst = (const float*)d_in[5];
  const float* bias_gat = (const float*)d_in[6];
  const float* W1 = (const float*)d_in[7];
  const float* b1 = (const float*)d_in[8];
  const float* W2 = (const float*)d_in[9];
  const float* b2 = (const float*)d_in[10];
  const float* g1 = (const float*)d_in[11];
  const float* bt1 = (const float*)d_in[12];
  const float* g2 = (const float*)d_in[13];
  const float* bt2 = (const float*)d_in[14];
  const int* src = ei;
  const int* dst = ei + E;
  const size_t ZS = (size_t)Nn * Dm;

  // ---- carve workspace ----
  char* wsp = (char*)d_ws;
  size_t off = 0;
  auto carve = [&](size_t bytes) -> void* {
    void* p = wsp + off;
    off += (bytes + 255) & ~(size_t)255;
    return p;
  };
  unsigned short* Wgt  = (unsigned short*)carve((size_t)8 * 256 * 256 * 2);
  unsigned short* W1t  = (unsigned short*)carve((size_t)8 * 256 * 1024 * 2);
  unsigned short* W2t  = (unsigned short*)carve((size_t)8 * 1024 * 256 * 2);
  int* cnt      = (int*)carve((size_t)Nn * 4);
  int* rowptr   = (int*)carve((size_t)(Nn + 1) * 4);
  int* cursor   = (int*)carve((size_t)Nn * 4);
  int* part     = (int*)carve((size_t)Nn * 4);
  int* bsum     = (int*)carve((size_t)64 * 4);
  int* bbase    = (int*)carve((size_t)64 * 4);
  int* csrc     = (int*)carve((size_t)E * 4);
  unsigned short* x01b = (unsigned short*)carve(2 * ZS * 2);  // [z]: layer input bf16
  unsigned short* hbuf2 = (unsigned short*)carve(2 * ZS * 2); // [z]: proj out bf16
  float* a_s2   = (float*)carve((size_t)2 * Nn * 4 * 4);
  float* a_d2   = (float*)carve((size_t)2 * Nn * 4 * 4);
  unsigned short* x1b2 = (unsigned short*)carve(2 * ZS * 2);  // [z]: LN1 out bf16
  unsigned short* tb2  = (unsigned short*)carve(2 * ZS * 2);  // [z]: FFN2 out (pre-LN2) bf16
  unsigned short* f_b2 = (unsigned short*)carve((size_t)2 * Nn * Ff * 2);  // [z]: FFN1 out
  if (off > ws_size) return;  // workspace too small — fail visibly

  // ---- once per call: weights (tiled transpose) + CSR ----
  wconvt_kernel<<<dim3(4, 4, 8), 256, 0, stream>>>(Wgat, Wgt, 256, 256);
  wconvt_kernel<<<dim3(16, 4, 8), 256, 0, stream>>>(W1, W1t, 256, 1024);
  wconvt_kernel<<<dim3(4, 16, 8), 256, 0, stream>>>(W2, W2t, 1024, 256);
  hipMemsetAsync(cnt, 0, (size_t)Nn * 4, stream);
  count_kernel<<<1024, 256, 0, stream>>>(dst, E, cnt);
  scan1_kernel<<<64, 256, 0, stream>>>(cnt, part, bsum);
  scan2_kernel<<<1, 64, 0, stream>>>(bsum, bbase, rowptr);
  scan3_kernel<<<64, 256, 0, stream>>>(part, bbase, rowptr, cursor);
  fill_kernel<<<1024, 256, 0, stream>>>(src, dst, E, cursor, csrc);

  float* out_hf = (float*)d_out;
  float* out_hs = out_hf + ZS;

  prep_kernel<<<2048, 256, 0, stream>>>(hf_in, hs_in, x01b, Nn * Dm);

  for (int l = 0; l < 4; ++l) {
    // proj (both streams) + fused scores
    proj_kernel<<<dim3(128, 4, 2), 256, 0, stream>>>(
        x01b, Wgt + (size_t)l * 65536, hbuf2,
        att_src + l * 256, att_dst + l * 256, a_s2, a_d2);
    // segment softmax + aggregate + bias + residual + LN1 (both streams)
    agg_kernel<<<dim3(Nn / 4, 2), 256, 0, stream>>>(
        hbuf2, a_s2, a_d2, rowptr, csrc,
        bias_gat + l * 256, x01b, g1 + l * 256, bt1 + l * 256, x1b2);
    // FFN1: f = relu(x1 @ W1 + b1) — 128x128, K=256
    gemm128_kernel<1><<<dim3(128, 8, 2), 256, 0, stream>>>(
        x1b2, ZS, W1t + (size_t)l * 256 * 1024,
        f_b2, (size_t)Nn * Ff, b1 + l * 1024, 4096, nullptr, 256, Ff);
    // FFN2: t = f @ W2 + b2 + x1 — 128x128, K=1024
    gemm128_kernel<2><<<dim3(128, 2, 2), 256, 0, stream>>>(
        f_b2, (size_t)Nn * Ff, W2t + (size_t)l * 1024 * 256,
        tb2, ZS, b2 + l * 256, 1024, x1b2, 1024, 256);
    // dual LN2 -> states (+ next-layer prep for l<3)
    if (l < 3) {
      ln2_kernel<1><<<Nn / 4, 256, 0, stream>>>(tb2, g2 + l * 256, bt2 + l * 256,
                                                out_hf, out_hs, x01b);
    } else {
      ln2_kernel<0><<<Nn / 4, 256, 0, stream>>>(tb2, g2 + l * 256, bt2 + l * 256,
                                                out_hf, out_hs, x01b);
    }
  }
}

// Round 11
// 645.278 us; speedup vs baseline: 1.0981x; 1.0875x over previous
//
#include <hip/hip_runtime.h>

#define Nn 16384
#define Dm 256
#define Ff 1024

typedef __attribute__((ext_vector_type(8))) short bf16x8;
typedef __attribute__((ext_vector_type(4))) float f32x4;

typedef const __attribute__((address_space(1))) unsigned int glb_u32;
typedef __attribute__((address_space(3))) unsigned int lds_u32;

__device__ __forceinline__ void async_copy16(const void* g, void* l) {
  __builtin_amdgcn_global_load_lds((glb_u32*)g, (lds_u32*)l, 16, 0, 0);
}

__device__ __forceinline__ unsigned short f2bf(float f) {
  union { float f; unsigned u; } v; v.f = f;
  return (unsigned short)((v.u + 0x7FFFu + ((v.u >> 16) & 1u)) >> 16);
}

__device__ __forceinline__ float bf2f(unsigned short u) {
  union { unsigned u; float f; } v; v.u = ((unsigned)u) << 16;
  return v.f;
}

__device__ __forceinline__ float sel4(float4 v, int h) {
  float r = v.x;
  r = (h == 1) ? v.y : r;
  r = (h == 2) ? v.z : r;
  r = (h == 3) ? v.w : r;
  return r;
}

// ---------------- tiled weight convert+transpose: wt[b][j][k] = bf16(w[b][k][j]) ----------------
__global__ __launch_bounds__(256) void wconvt_kernel(const float* __restrict__ w,
                                                     unsigned short* __restrict__ wt,
                                                     int K, int J) {
  __shared__ unsigned short t[64][65];
  int b = blockIdx.z;
  int j0 = blockIdx.x * 64, k0 = blockIdx.y * 64;
  int tj = threadIdx.x & 63, q = threadIdx.x >> 6;  // 4 rows per pass
  const float* wb = w + (size_t)b * K * J;
#pragma unroll
  for (int r = 0; r < 16; ++r) {
    int k = r * 4 + q;
    t[k][tj] = f2bf(wb[(size_t)(k0 + k) * J + j0 + tj]);
  }
  __syncthreads();
  unsigned short* wtb = wt + (size_t)b * K * J;
#pragma unroll
  for (int r = 0; r < 16; ++r) {
    int j = r * 4 + q;
    wtb[(size_t)(j0 + j) * K + k0 + tj] = t[tj][j];
  }
}

// ---------------- CSR build ----------------
__global__ void count_kernel(const int* __restrict__ dst, int E, int* __restrict__ cnt) {
  for (int e = blockIdx.x * blockDim.x + threadIdx.x; e < E; e += gridDim.x * blockDim.x)
    atomicAdd(&cnt[dst[e]], 1);
}

__global__ __launch_bounds__(256) void scan1_kernel(const int* __restrict__ cnt,
                                                    int* __restrict__ part,
                                                    int* __restrict__ bsum) {
  __shared__ int sd[256];
  int b = blockIdx.x, tid = threadIdx.x;
  int v = cnt[b * 256 + tid];
  sd[tid] = v;
  __syncthreads();
  for (int offt = 1; offt < 256; offt <<= 1) {
    int t = (tid >= offt) ? sd[tid - offt] : 0;
    __syncthreads();
    sd[tid] += t;
    __syncthreads();
  }
  part[b * 256 + tid] = sd[tid] - v;  // exclusive
  if (tid == 255) bsum[b] = sd[255];
}

__global__ __launch_bounds__(64) void scan2_kernel(const int* __restrict__ bsum,
                                                   int* __restrict__ bbase,
                                                   int* __restrict__ rowptr) {
  __shared__ int sd[64];
  int tid = threadIdx.x;
  int v = bsum[tid];
  sd[tid] = v;
  __syncthreads();
  for (int offt = 1; offt < 64; offt <<= 1) {
    int t = (tid >= offt) ? sd[tid - offt] : 0;
    __syncthreads();
    sd[tid] += t;
    __syncthreads();
  }
  bbase[tid] = sd[tid] - v;
  if (tid == 63) rowptr[Nn] = sd[63];
}

__global__ __launch_bounds__(256) void scan3_kernel(const int* __restrict__ part,
                                                    const int* __restrict__ bbase,
                                                    int* __restrict__ rowptr,
                                                    int* __restrict__ cursor) {
  int b = blockIdx.x, tid = threadIdx.x;
  int v = part[b * 256 + tid] + bbase[b];
  rowptr[b * 256 + tid] = v;
  cursor[b * 256 + tid] = v;
}

__global__ void fill_kernel(const int* __restrict__ src, const int* __restrict__ dst, int E,
                            int* __restrict__ cursor, int* __restrict__ csrc) {
  for (int e = blockIdx.x * blockDim.x + threadIdx.x; e < E; e += gridDim.x * blockDim.x) {
    int pos = atomicAdd(&cursor[dst[e]], 1);
    csrc[pos] = src[e];
  }
}

// ---------------- initial input prep (layer 0): x01b[0]=bf16(hf+hs), x01b[1]=bf16(hs) ----------------
__global__ void prep_kernel(const float* __restrict__ hf, const float* __restrict__ hs,
                            unsigned short* __restrict__ x01b, int total) {
  const size_t ZS = (size_t)Nn * Dm;
  for (int i = blockIdx.x * blockDim.x + threadIdx.x; i < total; i += gridDim.x * blockDim.x) {
    float a = hf[i], b = hs[i];
    x01b[i] = f2bf(a + b);
    x01b[ZS + i] = f2bf(b);
  }
}

// ---------------- proj GEMM (both streams, z) + fused attention scores, BK=64 ----------------
__global__ __launch_bounds__(256, 2) void proj_kernel(
    const unsigned short* __restrict__ xib, const unsigned short* __restrict__ Wgt_l,
    unsigned short* __restrict__ hbuf2, const float* __restrict__ asr_l,
    const float* __restrict__ ads_l, float* __restrict__ a_s2, float* __restrict__ a_d2) {
  __shared__ __align__(16) unsigned short sA[128 * 64];
  __shared__ __align__(16) unsigned short sB[64 * 64];
  const int K = 256;
  const size_t ZS = (size_t)Nn * Dm;
  int tid = threadIdx.x;
  int wave = tid >> 6, lane = tid & 63;
  int l16 = lane & 15, lhi = lane >> 4;
  int brow = blockIdx.x, bcol = blockIdx.y, z = blockIdx.z;
  int wm = wave >> 1, wn = wave & 1;  // wave tile 64x32

  const unsigned short* Ab = xib + z * ZS + (size_t)brow * 128 * K;
  const unsigned short* Bb = Wgt_l + (size_t)z * 4 * 65536 + (size_t)bcol * 64 * K;
  int lrow = lane >> 3, lk = (lane & 7) * 8;

  f32x4 acc[4][2] = {};

  for (int k0 = 0; k0 < K; k0 += 64) {
#pragma unroll
    for (int r = 0; r < 4; ++r) {
      int rb = r * 32 + wave * 8;
      async_copy16(Ab + (size_t)(rb + lrow) * K + k0 + lk, &sA[rb * 64]);
      if (r < 2)
        async_copy16(Bb + (size_t)(rb + lrow) * K + k0 + lk, &sB[rb * 64]);
    }
    __syncthreads();
#pragma unroll
    for (int kk = 0; kk < 2; ++kk) {
      bf16x8 af[4], bfr[2];
#pragma unroll
      for (int mi = 0; mi < 4; ++mi)
        af[mi] = *(const bf16x8*)&sA[(wm * 64 + mi * 16 + l16) * 64 + kk * 32 + lhi * 8];
#pragma unroll
      for (int ni = 0; ni < 2; ++ni)
        bfr[ni] = *(const bf16x8*)&sB[(wn * 32 + ni * 16 + l16) * 64 + kk * 32 + lhi * 8];
#pragma unroll
      for (int mi = 0; mi < 4; ++mi)
#pragma unroll
        for (int ni = 0; ni < 2; ++ni)
          acc[mi][ni] = __builtin_amdgcn_mfma_f32_16x16x32_bf16(af[mi], bfr[ni], acc[mi][ni], 0, 0, 0);
    }
    __syncthreads();
  }

  // ---- epilogue: C store (bf16) + per-row attention-score partials ----
  unsigned short* hb = hbuf2 + z * ZS;
  const float* asr_p = asr_l + z * 1024 + bcol * 64;
  const float* ads_p = ads_l + z * 1024 + bcol * 64;
  float as0 = asr_p[wn * 32 + l16],      ad0 = ads_p[wn * 32 + l16];
  float as1 = asr_p[wn * 32 + 16 + l16], ad1 = ads_p[wn * 32 + 16 + l16];
  float* sredS = (float*)sA;        // [wm][wn][64] = 256 floats
  float* sredD = (float*)sA + 256;  // (sA dead after K loop)

#pragma unroll
  for (int mi = 0; mi < 4; ++mi) {
#pragma unroll
    for (int j = 0; j < 4; ++j) {
      int r = brow * 128 + wm * 64 + mi * 16 + lhi * 4 + j;
      float v0 = acc[mi][0][j], v1 = acc[mi][1][j];
      hb[(size_t)r * 256 + bcol * 64 + wn * 32 + l16] = f2bf(v0);
      hb[(size_t)r * 256 + bcol * 64 + wn * 32 + 16 + l16] = f2bf(v1);
      float ps = v0 * as0 + v1 * as1;
      float pd = v0 * ad0 + v1 * ad1;
#pragma unroll
      for (int off = 1; off < 16; off <<= 1) {
        ps += __shfl_xor(ps, off);
        pd += __shfl_xor(pd, off);
      }
      if (l16 == 0) {
        int rl = mi * 16 + lhi * 4 + j;  // row within wave tile [0,64)
        sredS[wm * 128 + wn * 64 + rl] = ps;
        sredD[wm * 128 + wn * 64 + rl] = pd;
      }
    }
  }
  __syncthreads();
  if (tid < 128) {
    int w = tid >> 6, rl = tid & 63;
    float s = sredS[w * 128 + rl] + sredS[w * 128 + 64 + rl];
    float d = sredD[w * 128 + rl] + sredD[w * 128 + 64 + rl];
    int row = brow * 128 + tid;
    a_s2[(size_t)z * Nn * 4 + row * 4 + bcol] = s;
    a_d2[(size_t)z * Nn * 4 + row * 4 + bcol] = d;
  }
}

// ---------------- FFN1: f = relu(x1 @ W1 + b1), BK=64, BM=BN=128, z=stream ----------------
__global__ __launch_bounds__(256, 2) void ffn1_kernel(
    const unsigned short* __restrict__ A2, const unsigned short* __restrict__ Bt_l,
    unsigned short* __restrict__ out2, const float* __restrict__ b1_l) {
  const int K = 256, Ncol = Ff;
  const size_t ZS = (size_t)Nn * Dm;
  __shared__ __align__(16) unsigned short sA[128 * 64];
  __shared__ __align__(16) unsigned short sB[128 * 64];
  int tid = threadIdx.x, wave = tid >> 6, lane = tid & 63;
  int l16 = lane & 15, lhi = lane >> 4;
  int brow = blockIdx.x, bcol = blockIdx.y, z = blockIdx.z;
  int wm = wave >> 1, wn = wave & 1;  // wave tile 64x64

  const unsigned short* Ab = A2 + z * ZS + (size_t)brow * 128 * K;
  const unsigned short* Bb = Bt_l + (size_t)z * 4 * Ff * 256 + (size_t)bcol * 128 * K;
  int lrow = lane >> 3, lk = (lane & 7) * 8;

  f32x4 acc[4][4] = {};

  for (int k0 = 0; k0 < K; k0 += 64) {
#pragma unroll
    for (int r = 0; r < 4; ++r) {
      int rb = r * 32 + wave * 8;
      async_copy16(Ab + (size_t)(rb + lrow) * K + k0 + lk, &sA[rb * 64]);
      async_copy16(Bb + (size_t)(rb + lrow) * K + k0 + lk, &sB[rb * 64]);
    }
    __syncthreads();
#pragma unroll
    for (int kk = 0; kk < 2; ++kk) {
      bf16x8 af[4], bfr[4];
#pragma unroll
      for (int mi = 0; mi < 4; ++mi)
        af[mi] = *(const bf16x8*)&sA[(wm * 64 + mi * 16 + l16) * 64 + kk * 32 + lhi * 8];
#pragma unroll
      for (int ni = 0; ni < 4; ++ni)
        bfr[ni] = *(const bf16x8*)&sB[(wn * 64 + ni * 16 + l16) * 64 + kk * 32 + lhi * 8];
#pragma unroll
      for (int mi = 0; mi < 4; ++mi)
#pragma unroll
        for (int ni = 0; ni < 4; ++ni)
          acc[mi][ni] = __builtin_amdgcn_mfma_f32_16x16x32_bf16(af[mi], bfr[ni], acc[mi][ni], 0, 0, 0);
    }
    __syncthreads();
  }

  unsigned short* outB = out2 + (size_t)z * Nn * Ff;
  const float* bias = b1_l + z * 4096;
#pragma unroll
  for (int mi = 0; mi < 4; ++mi) {
#pragma unroll
    for (int ni = 0; ni < 4; ++ni) {
#pragma unroll
      for (int j = 0; j < 4; ++j) {
        int r = brow * 128 + wm * 64 + mi * 16 + lhi * 4 + j;
        int c = bcol * 128 + wn * 64 + ni * 16 + l16;
        float v = acc[mi][ni][j] + bias[c];
        v = v > 0.f ? v : 0.f;
        outB[(size_t)r * Ncol + c] = f2bf(v);
      }
    }
  }
}

// ---------------- FFN2: t = f @ W2 + b2 + x1 (bf16 resid), bf16 out, BK=64, BN=64 ----------------
__global__ __launch_bounds__(256, 2) void ffn2_kernel(
    const unsigned short* __restrict__ A2, const unsigned short* __restrict__ Bt_l,
    unsigned short* __restrict__ out2, const float* __restrict__ b2_l,
    const unsigned short* __restrict__ resid2) {
  const int K = Ff, Ncol = 256;
  const size_t ZS = (size_t)Nn * Dm;
  __shared__ __align__(16) unsigned short sA[128 * 64];
  __shared__ __align__(16) unsigned short sB[64 * 64];
  int tid = threadIdx.x, wave = tid >> 6, lane = tid & 63;
  int l16 = lane & 15, lhi = lane >> 4;
  int brow = blockIdx.x, bcol = blockIdx.y, z = blockIdx.z;
  int wm = wave >> 1, wn = wave & 1;  // wave tile 64x32

  const unsigned short* Ab = A2 + (size_t)z * Nn * Ff + (size_t)brow * 128 * K;
  const unsigned short* Bb = Bt_l + (size_t)z * 4 * Ff * 256 + (size_t)bcol * 64 * K;
  int lrow = lane >> 3, lk = (lane & 7) * 8;

  f32x4 acc[4][2] = {};

  for (int k0 = 0; k0 < K; k0 += 64) {
#pragma unroll
    for (int r = 0; r < 4; ++r) {
      int rb = r * 32 + wave * 8;
      async_copy16(Ab + (size_t)(rb + lrow) * K + k0 + lk, &sA[rb * 64]);
      if (r < 2)
        async_copy16(Bb + (size_t)(rb + lrow) * K + k0 + lk, &sB[rb * 64]);
    }
    __syncthreads();
#pragma unroll
    for (int kk = 0; kk < 2; ++kk) {
      bf16x8 af[4], bfr[2];
#pragma unroll
      for (int mi = 0; mi < 4; ++mi)
        af[mi] = *(const bf16x8*)&sA[(wm * 64 + mi * 16 + l16) * 64 + kk * 32 + lhi * 8];
#pragma unroll
      for (int ni = 0; ni < 2; ++ni)
        bfr[ni] = *(const bf16x8*)&sB[(wn * 32 + ni * 16 + l16) * 64 + kk * 32 + lhi * 8];
#pragma unroll
      for (int mi = 0; mi < 4; ++mi)
#pragma unroll
        for (int ni = 0; ni < 2; ++ni)
          acc[mi][ni] = __builtin_amdgcn_mfma_f32_16x16x32_bf16(af[mi], bfr[ni], acc[mi][ni], 0, 0, 0);
    }
    __syncthreads();
  }

  unsigned short* outB = out2 + z * ZS;
  const float* bias = b2_l + z * 1024;
  const unsigned short* resid = resid2 + z * ZS;
#pragma unroll
  for (int mi = 0; mi < 4; ++mi) {
#pragma unroll
    for (int ni = 0; ni < 2; ++ni) {
#pragma unroll
      for (int j = 0; j < 4; ++j) {
        int r = brow * 128 + wm * 64 + mi * 16 + lhi * 4 + j;
        int c = bcol * 64 + wn * 32 + ni * 16 + l16;
        float v = acc[mi][ni][j] + bias[c] + bf2f(resid[(size_t)r * Ncol + c]);
        outB[(size_t)r * Ncol + c] = f2bf(v);
      }
    }
  }
}

// ---------------- wave-per-node fused softmax + aggregation + bias + residual + LN1 ----------------
// grid (Nn/4, 2): y = stream. 4 waves/block. Barrier-free. Fast path for deg <= 64.
__global__ __launch_bounds__(256) void agg_kernel(
    const unsigned short* __restrict__ hbuf2, const float* __restrict__ a_s2,
    const float* __restrict__ a_d2,
    const int* __restrict__ rowptr, const int* __restrict__ csrc,
    const float* __restrict__ bias_l, const unsigned short* __restrict__ x01b,
    const float* __restrict__ g1_l, const float* __restrict__ bt1_l,
    unsigned short* __restrict__ x1b2) {
  __shared__ float sw[4][320];  // [wave][slot*5 + head]  (stride 5: conflict-free)
  __shared__ int ssrc[4][64];
  const size_t ZS = (size_t)Nn * Dm;
  int z = blockIdx.y;
  const unsigned short* hb = hbuf2 + z * ZS;
  const float* a_s = a_s2 + (size_t)z * Nn * 4;
  const float* a_d = a_d2 + (size_t)z * Nn * 4;
  const float* bias = bias_l + z * 1024;
  const unsigned short* xres = x01b + z * ZS;
  const float* g1 = g1_l + z * 1024;
  const float* bt1 = bt1_l + z * 1024;
  unsigned short* x1b = x1b2 + z * ZS;

  int wave = threadIdx.x >> 6, lane = threadIdx.x & 63;
  int n = blockIdx.x * 4 + wave;
  int l32 = lane & 31;
  int par = lane >> 5;         // edge parity
  int hch = l32 >> 3;          // head of my channel block
  int c0 = l32 * 8;            // my 8 channels
  int beg = rowptr[n], end = rowptr[n + 1];
  float4 adv = *(const float4*)&a_d[n * 4];
  const float NI = -__builtin_inff();
  float acc[8] = {};
  float den = 0.f;

  if (end - beg <= 64) {
    // ---- fast path: single chunk, no online rescale ----
    int cnt = end - beg;
    float4 ev = {NI, NI, NI, NI};
    if (lane < cnt) {
      int s = csrc[beg + lane];
      ssrc[wave][lane] = s;
      float4 as = *(const float4*)&a_s[s * 4];
      float e0 = as.x + adv.x; ev.x = e0 > 0.f ? e0 : 0.2f * e0;
      float e1 = as.y + adv.y; ev.y = e1 > 0.f ? e1 : 0.2f * e1;
      float e2 = as.z + adv.z; ev.z = e2 > 0.f ? e2 : 0.2f * e2;
      float e3 = as.w + adv.w; ev.w = e3 > 0.f ? e3 : 0.2f * e3;
    }
    float4 mv = ev;
#pragma unroll
    for (int off = 32; off; off >>= 1) {
      mv.x = fmaxf(mv.x, __shfl_xor(mv.x, off));
      mv.y = fmaxf(mv.y, __shfl_xor(mv.y, off));
      mv.z = fmaxf(mv.z, __shfl_xor(mv.z, off));
      mv.w = fmaxf(mv.w, __shfl_xor(mv.w, off));
    }
    if (lane < cnt) {
      float* swl = &sw[wave][lane * 5];
      swl[0] = __expf(ev.x - mv.x);
      swl[1] = __expf(ev.y - mv.y);
      swl[2] = __expf(ev.z - mv.z);
      swl[3] = __expf(ev.w - mv.w);
    }
    __builtin_amdgcn_wave_barrier();
    for (int i = par; i < cnt; i += 2) {
      float w = sw[wave][i * 5 + hch];
      int s_i = ssrc[wave][i];
      bf16x8 hv = *(const bf16x8*)(hb + (size_t)s_i * 256 + c0);
#pragma unroll
      for (int j = 0; j < 8; ++j)
        acc[j] = fmaf(bf2f((unsigned short)hv[j]), w, acc[j]);
      den += w;
    }
  } else {
    // ---- general path: online softmax over 64-edge chunks ----
    float4 m4 = {NI, NI, NI, NI};
    for (int base = beg; base < end; base += 64) {
      int cnt = min(64, end - base);
      float4 ev = {NI, NI, NI, NI};
      if (lane < cnt) {
        int s = csrc[base + lane];
        ssrc[wave][lane] = s;
        float4 as = *(const float4*)&a_s[s * 4];
        float e0 = as.x + adv.x; ev.x = e0 > 0.f ? e0 : 0.2f * e0;
        float e1 = as.y + adv.y; ev.y = e1 > 0.f ? e1 : 0.2f * e1;
        float e2 = as.z + adv.z; ev.z = e2 > 0.f ? e2 : 0.2f * e2;
        float e3 = as.w + adv.w; ev.w = e3 > 0.f ? e3 : 0.2f * e3;
      }
      float4 mv = ev;
#pragma unroll
      for (int off = 32; off; off >>= 1) {
        mv.x = fmaxf(mv.x, __shfl_xor(mv.x, off));
        mv.y = fmaxf(mv.y, __shfl_xor(mv.y, off));
        mv.z = fmaxf(mv.z, __shfl_xor(mv.z, off));
        mv.w = fmaxf(mv.w, __shfl_xor(mv.w, off));
      }
      float4 m4n;
      m4n.x = fmaxf(m4.x, mv.x); m4n.y = fmaxf(m4.y, mv.y);
      m4n.z = fmaxf(m4.z, mv.z); m4n.w = fmaxf(m4.w, mv.w);
      float rm = __expf(sel4(m4, hch) - sel4(m4n, hch));
#pragma unroll
      for (int j = 0; j < 8; ++j) acc[j] *= rm;
      den *= rm;
      if (lane < cnt) {
        float* swl = &sw[wave][lane * 5];
        swl[0] = __expf(ev.x - m4n.x);
        swl[1] = __expf(ev.y - m4n.y);
        swl[2] = __expf(ev.z - m4n.z);
        swl[3] = __expf(ev.w - m4n.w);
      }
      m4 = m4n;
      __builtin_amdgcn_wave_barrier();
      for (int i = par; i < cnt; i += 2) {
        float w = sw[wave][i * 5 + hch];
        int s_i = ssrc[wave][i];
        bf16x8 hv = *(const bf16x8*)(hb + (size_t)s_i * 256 + c0);
#pragma unroll
        for (int j = 0; j < 8; ++j)
          acc[j] = fmaf(bf2f((unsigned short)hv[j]), w, acc[j]);
        den += w;
      }
      __builtin_amdgcn_wave_barrier();
    }
  }

  // combine edge parities (lane ^ 32 holds same channels, other parity)
#pragma unroll
  for (int j = 0; j < 8; ++j) acc[j] += __shfl_xor(acc[j], 32);
  den += __shfl_xor(den, 32);

  float invden = 1.f / fmaxf(den, 1e-16f);
  bf16x8 rv = *(const bf16x8*)(xres + (size_t)n * 256 + c0);
  float outv[8];
  float s1 = 0.f, s2 = 0.f;
#pragma unroll
  for (int j = 0; j < 8; ++j) {
    float v = acc[j] * invden + bias[c0 + j] + bf2f((unsigned short)rv[j]);
    outv[j] = v;
    s1 += v;
    s2 += v * v;
  }
  // LN reduce over the 32-lane half (halves hold identical data)
#pragma unroll
  for (int off = 16; off; off >>= 1) {
    s1 += __shfl_xor(s1, off);
    s2 += __shfl_xor(s2, off);
  }
  float mean = s1 * (1.f / 256.f);
  float var = s2 * (1.f / 256.f) - mean * mean;
  float rst = rsqrtf(var + 1e-5f);
  if (par == 0) {
    unsigned short yb[8];
#pragma unroll
    for (int j = 0; j < 8; ++j)
      yb[j] = f2bf((outv[j] - mean) * rst * g1[c0 + j] + bt1[c0 + j]);
    *(bf16x8*)&x1b[(size_t)n * 256 + c0] = *(bf16x8*)yb;
  }
}

// ---------------- dual LN2 (wave per node) ----------------
// PREP=1 (layers 0-2): writes ONLY next-layer bf16 inputs (out states are dead until layer 3).
// PREP=0 (layer 3): writes ONLY the f32 output states.
template <int PREP>
__global__ __launch_bounds__(256) void ln2_kernel(const unsigned short* __restrict__ tb2,
                                                  const float* __restrict__ g2_l,
                                                  const float* __restrict__ bt2_l,
                                                  float* __restrict__ out_hf,
                                                  float* __restrict__ out_hs,
                                                  unsigned short* __restrict__ x01b) {
  const size_t ZS = (size_t)Nn * Dm;
  int wave = threadIdx.x >> 6, lane = threadIdx.x & 63;
  int n = blockIdx.x * 4 + wave;
  int c0 = lane * 4;
  size_t idx = (size_t)n * 256 + c0;
  ushort4 u0 = *(const ushort4*)&tb2[idx];
  ushort4 u1 = *(const ushort4*)&tb2[ZS + idx];
  float v0[4] = {bf2f(u0.x), bf2f(u0.y), bf2f(u0.z), bf2f(u0.w)};
  float v1[4] = {bf2f(u1.x), bf2f(u1.y), bf2f(u1.z), bf2f(u1.w)};
  float a0 = 0.f, b0 = 0.f, a1 = 0.f, b1 = 0.f;
#pragma unroll
  for (int j = 0; j < 4; ++j) {
    a0 += v0[j]; b0 += v0[j] * v0[j];
    a1 += v1[j]; b1 += v1[j] * v1[j];
  }
#pragma unroll
  for (int off = 32; off; off >>= 1) {
    a0 += __shfl_xor(a0, off);
    b0 += __shfl_xor(b0, off);
    a1 += __shfl_xor(a1, off);
    b1 += __shfl_xor(b1, off);
  }
  float m0 = a0 * (1.f / 256.f), m1 = a1 * (1.f / 256.f);
  float r0 = rsqrtf(b0 * (1.f / 256.f) - m0 * m0 + 1e-5f);
  float r1 = rsqrtf(b1 * (1.f / 256.f) - m1 * m1 + 1e-5f);
  float4 y0, y1;
  unsigned short p0[4], p1[4];
#pragma unroll
  for (int j = 0; j < 4; ++j) {
    float yf = (v0[j] - m0) * r0 * g2_l[c0 + j] + bt2_l[c0 + j];
    float ys = (v1[j] - m1) * r1 * g2_l[1024 + c0 + j] + bt2_l[1024 + c0 + j];
    ((float*)&y0)[j] = yf;
    ((float*)&y1)[j] = ys;
    if (PREP) { p0[j] = f2bf(yf + ys); p1[j] = f2bf(ys); }
  }
  if (PREP) {
    // out states are dead until the last layer — skip their 32 MB of f32 writes
    *(ushort4*)&x01b[idx] = *(ushort4*)p0;
    *(ushort4*)&x01b[ZS + idx] = *(ushort4*)p1;
  } else {
    *(float4*)&out_hf[idx] = y0;
    *(float4*)&out_hs[idx] = y1;
  }
}

extern "C" void kernel_launch(void* const* d_in, const int* in_sizes, int n_in,
                              void* d_out, int out_size, void* d_ws, size_t ws_size,
                              hipStream_t stream) {
  const float* hf_in = (const float*)d_in[0];
  const float* hs_in = (const float*)d_in[1];
  const int* ei = (const int*)d_in[2];
  const int E = in_sizes[2] / 2;
  const float* Wgat = (const float*)d_in[3];
  const float* att_src = (const float*)d_in[4];
  const float* att_dst = (const float*)d_in[5];
  const float* bias_gat = (const float*)d_in[6];
  const float* W1 = (const float*)d_in[7];
  const float* b1 = (const float*)d_in[8];
  const float* W2 = (const float*)d_in[9];
  const float* b2 = (const float*)d_in[10];
  const float* g1 = (const float*)d_in[11];
  const float* bt1 = (const float*)d_in[12];
  const float* g2 = (const float*)d_in[13];
  const float* bt2 = (const float*)d_in[14];
  const int* src = ei;
  const int* dst = ei + E;
  const size_t ZS = (size_t)Nn * Dm;

  // ---- carve workspace ----
  char* wsp = (char*)d_ws;
  size_t off = 0;
  auto carve = [&](size_t bytes) -> void* {
    void* p = wsp + off;
    off += (bytes + 255) & ~(size_t)255;
    return p;
  };
  unsigned short* Wgt  = (unsigned short*)carve((size_t)8 * 256 * 256 * 2);
  unsigned short* W1t  = (unsigned short*)carve((size_t)8 * 256 * 1024 * 2);
  unsigned short* W2t  = (unsigned short*)carve((size_t)8 * 1024 * 256 * 2);
  int* cnt      = (int*)carve((size_t)Nn * 4);
  int* rowptr   = (int*)carve((size_t)(Nn + 1) * 4);
  int* cursor   = (int*)carve((size_t)Nn * 4);
  int* part     = (int*)carve((size_t)Nn * 4);
  int* bsum     = (int*)carve((size_t)64 * 4);
  int* bbase    = (int*)carve((size_t)64 * 4);
  int* csrc     = (int*)carve((size_t)E * 4);
  unsigned short* x01b = (unsigned short*)carve(2 * ZS * 2);  // [z]: layer input bf16
  unsigned short* hbuf2 = (unsigned short*)carve(2 * ZS * 2); // [z]: proj out bf16
  float* a_s2   = (float*)carve((size_t)2 * Nn * 4 * 4);
  float* a_d2   = (float*)carve((size_t)2 * Nn * 4 * 4);
  unsigned short* x1b2 = (unsigned short*)carve(2 * ZS * 2);  // [z]: LN1 out bf16
  unsigned short* tb2  = (unsigned short*)carve(2 * ZS * 2);  // [z]: FFN2 out (pre-LN2) bf16
  unsigned short* f_b2 = (unsigned short*)carve((size_t)2 * Nn * Ff * 2);  // [z]: FFN1 out
  if (off > ws_size) return;  // workspace too small — fail visibly

  // ---- once per call: weights (tiled transpose) + CSR ----
  wconvt_kernel<<<dim3(4, 4, 8), 256, 0, stream>>>(Wgat, Wgt, 256, 256);
  wconvt_kernel<<<dim3(16, 4, 8), 256, 0, stream>>>(W1, W1t, 256, 1024);
  wconvt_kernel<<<dim3(4, 16, 8), 256, 0, stream>>>(W2, W2t, 1024, 256);
  hipMemsetAsync(cnt, 0, (size_t)Nn * 4, stream);
  count_kernel<<<1024, 256, 0, stream>>>(dst, E, cnt);
  scan1_kernel<<<64, 256, 0, stream>>>(cnt, part, bsum);
  scan2_kernel<<<1, 64, 0, stream>>>(bsum, bbase, rowptr);
  scan3_kernel<<<64, 256, 0, stream>>>(part, bbase, rowptr, cursor);
  fill_kernel<<<1024, 256, 0, stream>>>(src, dst, E, cursor, csrc);

  float* out_hf = (float*)d_out;
  float* out_hs = out_hf + ZS;

  prep_kernel<<<2048, 256, 0, stream>>>(hf_in, hs_in, x01b, Nn * Dm);

  for (int l = 0; l < 4; ++l) {
    // proj (both streams) + fused scores
    proj_kernel<<<dim3(128, 4, 2), 256, 0, stream>>>(
        x01b, Wgt + (size_t)l * 65536, hbuf2,
        att_src + l * 256, att_dst + l * 256, a_s2, a_d2);
    // segment softmax + aggregate + bias + residual + LN1 (both streams)
    agg_kernel<<<dim3(Nn / 4, 2), 256, 0, stream>>>(
        hbuf2, a_s2, a_d2, rowptr, csrc,
        bias_gat + l * 256, x01b, g1 + l * 256, bt1 + l * 256, x1b2);
    // FFN (both streams per dispatch)
    ffn1_kernel<<<dim3(128, 8, 2), 256, 0, stream>>>(
        x1b2, W1t + (size_t)l * 256 * 1024, f_b2, b1 + l * 1024);
    ffn2_kernel<<<dim3(128, 4, 2), 256, 0, stream>>>(
        f_b2, W2t + (size_t)l * 1024 * 256, tb2, b2 + l * 256, x1b2);
    // dual LN2 (+ next-layer prep for l<3; out states written only at l=3)
    if (l < 3) {
      ln2_kernel<1><<<Nn / 4, 256, 0, stream>>>(tb2, g2 + l * 256, bt2 + l * 256,
                                                out_hf, out_hs, x01b);
    } else {
      ln2_kernel<0><<<Nn / 4, 256, 0, stream>>>(tb2, g2 + l * 256, bt2 + l * 256,
                                                out_hf, out_hs, x01b);
    }
  }
}

// Round 12
// 644.955 us; speedup vs baseline: 1.0986x; 1.0005x over previous
//
#include <hip/hip_runtime.h>

#define Nn 16384
#define Dm 256
#define Ff 1024

typedef __attribute__((ext_vector_type(8))) short bf16x8;
typedef __attribute__((ext_vector_type(4))) float f32x4;

typedef const __attribute__((address_space(1))) unsigned int glb_u32;
typedef __attribute__((address_space(3))) unsigned int lds_u32;

__device__ __forceinline__ void async_copy16(const void* g, void* l) {
  __builtin_amdgcn_global_load_lds((glb_u32*)g, (lds_u32*)l, 16, 0, 0);
}

__device__ __forceinline__ unsigned short f2bf(float f) {
  union { float f; unsigned u; } v; v.f = f;
  return (unsigned short)((v.u + 0x7FFFu + ((v.u >> 16) & 1u)) >> 16);
}

__device__ __forceinline__ float bf2f(unsigned short u) {
  union { unsigned u; float f; } v; v.u = ((unsigned)u) << 16;
  return v.f;
}

__device__ __forceinline__ float sel4(float4 v, int h) {
  float r = v.x;
  r = (h == 1) ? v.y : r;
  r = (h == 2) ? v.z : r;
  r = (h == 3) ? v.w : r;
  return r;
}

// ---------------- tiled weight convert+transpose: wt[b][j][k] = bf16(w[b][k][j]) ----------------
__global__ __launch_bounds__(256) void wconvt_kernel(const float* __restrict__ w,
                                                     unsigned short* __restrict__ wt,
                                                     int K, int J) {
  __shared__ unsigned short t[64][65];
  int b = blockIdx.z;
  int j0 = blockIdx.x * 64, k0 = blockIdx.y * 64;
  int tj = threadIdx.x & 63, q = threadIdx.x >> 6;  // 4 rows per pass
  const float* wb = w + (size_t)b * K * J;
#pragma unroll
  for (int r = 0; r < 16; ++r) {
    int k = r * 4 + q;
    t[k][tj] = f2bf(wb[(size_t)(k0 + k) * J + j0 + tj]);
  }
  __syncthreads();
  unsigned short* wtb = wt + (size_t)b * K * J;
#pragma unroll
  for (int r = 0; r < 16; ++r) {
    int j = r * 4 + q;
    wtb[(size_t)(j0 + j) * K + k0 + tj] = t[tj][j];
  }
}

// ---------------- CSR build ----------------
__global__ void count_kernel(const int* __restrict__ dst, int E, int* __restrict__ cnt) {
  for (int e = blockIdx.x * blockDim.x + threadIdx.x; e < E; e += gridDim.x * blockDim.x)
    atomicAdd(&cnt[dst[e]], 1);
}

__global__ __launch_bounds__(256) void scan1_kernel(const int* __restrict__ cnt,
                                                    int* __restrict__ part,
                                                    int* __restrict__ bsum) {
  __shared__ int sd[256];
  int b = blockIdx.x, tid = threadIdx.x;
  int v = cnt[b * 256 + tid];
  sd[tid] = v;
  __syncthreads();
  for (int offt = 1; offt < 256; offt <<= 1) {
    int t = (tid >= offt) ? sd[tid - offt] : 0;
    __syncthreads();
    sd[tid] += t;
    __syncthreads();
  }
  part[b * 256 + tid] = sd[tid] - v;  // exclusive
  if (tid == 255) bsum[b] = sd[255];
}

__global__ __launch_bounds__(64) void scan2_kernel(const int* __restrict__ bsum,
                                                   int* __restrict__ bbase,
                                                   int* __restrict__ rowptr) {
  __shared__ int sd[64];
  int tid = threadIdx.x;
  int v = bsum[tid];
  sd[tid] = v;
  __syncthreads();
  for (int offt = 1; offt < 64; offt <<= 1) {
    int t = (tid >= offt) ? sd[tid - offt] : 0;
    __syncthreads();
    sd[tid] += t;
    __syncthreads();
  }
  bbase[tid] = sd[tid] - v;
  if (tid == 63) rowptr[Nn] = sd[63];
}

__global__ __launch_bounds__(256) void scan3_kernel(const int* __restrict__ part,
                                                    const int* __restrict__ bbase,
                                                    int* __restrict__ rowptr,
                                                    int* __restrict__ cursor) {
  int b = blockIdx.x, tid = threadIdx.x;
  int v = part[b * 256 + tid] + bbase[b];
  rowptr[b * 256 + tid] = v;
  cursor[b * 256 + tid] = v;
}

__global__ void fill_kernel(const int* __restrict__ src, const int* __restrict__ dst, int E,
                            int* __restrict__ cursor, int* __restrict__ csrc) {
  for (int e = blockIdx.x * blockDim.x + threadIdx.x; e < E; e += gridDim.x * blockDim.x) {
    int pos = atomicAdd(&cursor[dst[e]], 1);
    csrc[pos] = src[e];
  }
}

// ---------------- initial input prep (layer 0): x01b[0]=bf16(hf+hs), x01b[1]=bf16(hs) ----------------
__global__ void prep_kernel(const float* __restrict__ hf, const float* __restrict__ hs,
                            unsigned short* __restrict__ x01b, int total) {
  const size_t ZS = (size_t)Nn * Dm;
  for (int i = blockIdx.x * blockDim.x + threadIdx.x; i < total; i += gridDim.x * blockDim.x) {
    float a = hf[i], b = hs[i];
    x01b[i] = f2bf(a + b);
    x01b[ZS + i] = f2bf(b);
  }
}

// ---------------- proj GEMM (both streams, z) + fused attention scores, BK=64 ----------------
__global__ __launch_bounds__(256, 2) void proj_kernel(
    const unsigned short* __restrict__ xib, const unsigned short* __restrict__ Wgt_l,
    unsigned short* __restrict__ hbuf2, const float* __restrict__ asr_l,
    const float* __restrict__ ads_l, float* __restrict__ a_s2, float* __restrict__ a_d2) {
  __shared__ __align__(16) unsigned short sA[128 * 64];
  __shared__ __align__(16) unsigned short sB[64 * 64];
  const int K = 256;
  const size_t ZS = (size_t)Nn * Dm;
  int tid = threadIdx.x;
  int wave = tid >> 6, lane = tid & 63;
  int l16 = lane & 15, lhi = lane >> 4;
  int brow = blockIdx.x, bcol = blockIdx.y, z = blockIdx.z;
  int wm = wave >> 1, wn = wave & 1;  // wave tile 64x32

  const unsigned short* Ab = xib + z * ZS + (size_t)brow * 128 * K;
  const unsigned short* Bb = Wgt_l + (size_t)z * 4 * 65536 + (size_t)bcol * 64 * K;
  int lrow = lane >> 3, lk = (lane & 7) * 8;

  f32x4 acc[4][2] = {};

  for (int k0 = 0; k0 < K; k0 += 64) {
#pragma unroll
    for (int r = 0; r < 4; ++r) {
      int rb = r * 32 + wave * 8;
      async_copy16(Ab + (size_t)(rb + lrow) * K + k0 + lk, &sA[rb * 64]);
      if (r < 2)
        async_copy16(Bb + (size_t)(rb + lrow) * K + k0 + lk, &sB[rb * 64]);
    }
    __syncthreads();
#pragma unroll
    for (int kk = 0; kk < 2; ++kk) {
      bf16x8 af[4], bfr[2];
#pragma unroll
      for (int mi = 0; mi < 4; ++mi)
        af[mi] = *(const bf16x8*)&sA[(wm * 64 + mi * 16 + l16) * 64 + kk * 32 + lhi * 8];
#pragma unroll
      for (int ni = 0; ni < 2; ++ni)
        bfr[ni] = *(const bf16x8*)&sB[(wn * 32 + ni * 16 + l16) * 64 + kk * 32 + lhi * 8];
#pragma unroll
      for (int mi = 0; mi < 4; ++mi)
#pragma unroll
        for (int ni = 0; ni < 2; ++ni)
          acc[mi][ni] = __builtin_amdgcn_mfma_f32_16x16x32_bf16(af[mi], bfr[ni], acc[mi][ni], 0, 0, 0);
    }
    __syncthreads();
  }

  // ---- epilogue: C store (bf16) + per-row attention-score partials ----
  unsigned short* hb = hbuf2 + z * ZS;
  const float* asr_p = asr_l + z * 1024 + bcol * 64;
  const float* ads_p = ads_l + z * 1024 + bcol * 64;
  float as0 = asr_p[wn * 32 + l16],      ad0 = ads_p[wn * 32 + l16];
  float as1 = asr_p[wn * 32 + 16 + l16], ad1 = ads_p[wn * 32 + 16 + l16];
  float* sredS = (float*)sA;        // [wm][wn][64] = 256 floats
  float* sredD = (float*)sA + 256;  // (sA dead after K loop)

#pragma unroll
  for (int mi = 0; mi < 4; ++mi) {
#pragma unroll
    for (int j = 0; j < 4; ++j) {
      int r = brow * 128 + wm * 64 + mi * 16 + lhi * 4 + j;
      float v0 = acc[mi][0][j], v1 = acc[mi][1][j];
      hb[(size_t)r * 256 + bcol * 64 + wn * 32 + l16] = f2bf(v0);
      hb[(size_t)r * 256 + bcol * 64 + wn * 32 + 16 + l16] = f2bf(v1);
      float ps = v0 * as0 + v1 * as1;
      float pd = v0 * ad0 + v1 * ad1;
#pragma unroll
      for (int off = 1; off < 16; off <<= 1) {
        ps += __shfl_xor(ps, off);
        pd += __shfl_xor(pd, off);
      }
      if (l16 == 0) {
        int rl = mi * 16 + lhi * 4 + j;  // row within wave tile [0,64)
        sredS[wm * 128 + wn * 64 + rl] = ps;
        sredD[wm * 128 + wn * 64 + rl] = pd;
      }
    }
  }
  __syncthreads();
  if (tid < 128) {
    int w = tid >> 6, rl = tid & 63;
    float s = sredS[w * 128 + rl] + sredS[w * 128 + 64 + rl];
    float d = sredD[w * 128 + rl] + sredD[w * 128 + 64 + rl];
    int row = brow * 128 + tid;
    a_s2[(size_t)z * Nn * 4 + row * 4 + bcol] = s;
    a_d2[(size_t)z * Nn * 4 + row * 4 + bcol] = d;
  }
}

// ---------------- FFN1: f = relu(x1 @ W1 + b1), BK=64, BM=BN=128, z=stream ----------------
__global__ __launch_bounds__(256, 2) void ffn1_kernel(
    const unsigned short* __restrict__ A2, const unsigned short* __restrict__ Bt_l,
    unsigned short* __restrict__ out2, const float* __restrict__ b1_l) {
  const int K = 256, Ncol = Ff;
  const size_t ZS = (size_t)Nn * Dm;
  __shared__ __align__(16) unsigned short sA[128 * 64];
  __shared__ __align__(16) unsigned short sB[128 * 64];
  int tid = threadIdx.x, wave = tid >> 6, lane = tid & 63;
  int l16 = lane & 15, lhi = lane >> 4;
  int brow = blockIdx.x, bcol = blockIdx.y, z = blockIdx.z;
  int wm = wave >> 1, wn = wave & 1;  // wave tile 64x64

  const unsigned short* Ab = A2 + z * ZS + (size_t)brow * 128 * K;
  const unsigned short* Bb = Bt_l + (size_t)z * 4 * Ff * 256 + (size_t)bcol * 128 * K;
  int lrow = lane >> 3, lk = (lane & 7) * 8;

  f32x4 acc[4][4] = {};

  for (int k0 = 0; k0 < K; k0 += 64) {
#pragma unroll
    for (int r = 0; r < 4; ++r) {
      int rb = r * 32 + wave * 8;
      async_copy16(Ab + (size_t)(rb + lrow) * K + k0 + lk, &sA[rb * 64]);
      async_copy16(Bb + (size_t)(rb + lrow) * K + k0 + lk, &sB[rb * 64]);
    }
    __syncthreads();
#pragma unroll
    for (int kk = 0; kk < 2; ++kk) {
      bf16x8 af[4], bfr[4];
#pragma unroll
      for (int mi = 0; mi < 4; ++mi)
        af[mi] = *(const bf16x8*)&sA[(wm * 64 + mi * 16 + l16) * 64 + kk * 32 + lhi * 8];
#pragma unroll
      for (int ni = 0; ni < 4; ++ni)
        bfr[ni] = *(const bf16x8*)&sB[(wn * 64 + ni * 16 + l16) * 64 + kk * 32 + lhi * 8];
#pragma unroll
      for (int mi = 0; mi < 4; ++mi)
#pragma unroll
        for (int ni = 0; ni < 4; ++ni)
          acc[mi][ni] = __builtin_amdgcn_mfma_f32_16x16x32_bf16(af[mi], bfr[ni], acc[mi][ni], 0, 0, 0);
    }
    __syncthreads();
  }

  unsigned short* outB = out2 + (size_t)z * Nn * Ff;
  const float* bias = b1_l + z * 4096;
#pragma unroll
  for (int mi = 0; mi < 4; ++mi) {
#pragma unroll
    for (int ni = 0; ni < 4; ++ni) {
#pragma unroll
      for (int j = 0; j < 4; ++j) {
        int r = brow * 128 + wm * 64 + mi * 16 + lhi * 4 + j;
        int c = bcol * 128 + wn * 64 + ni * 16 + l16;
        float v = acc[mi][ni][j] + bias[c];
        v = v > 0.f ? v : 0.f;
        outB[(size_t)r * Ncol + c] = f2bf(v);
      }
    }
  }
}

// ---------------- FFN2: t = f @ W2 + b2 + x1 (bf16 resid), bf16 out ----------------
// BM=64, BN=256 (single col-block: f read exactly once), BK=64, z=stream.
// 4 waves, wave w = col group w*64; wave tile 64x64, acc 4x4.
__global__ __launch_bounds__(256, 2) void ffn2_kernel(
    const unsigned short* __restrict__ A2, const unsigned short* __restrict__ Bt_l,
    unsigned short* __restrict__ out2, const float* __restrict__ b2_l,
    const unsigned short* __restrict__ resid2) {
  const int K = Ff, Ncol = 256;
  const size_t ZS = (size_t)Nn * Dm;
  __shared__ __align__(16) unsigned short sA[64 * 64];    // 8 KB
  __shared__ __align__(16) unsigned short sB[256 * 64];   // 32 KB
  int tid = threadIdx.x, wave = tid >> 6, lane = tid & 63;
  int l16 = lane & 15, lhi = lane >> 4;
  int brow = blockIdx.x, z = blockIdx.z;

  const unsigned short* Ab = A2 + (size_t)z * Nn * Ff + (size_t)brow * 64 * K;
  const unsigned short* Bb = Bt_l + (size_t)z * 4 * Ff * 256;  // all 256 cols
  int lrow = lane >> 3, lk = (lane & 7) * 8;

  f32x4 acc[4][4] = {};

  for (int k0 = 0; k0 < K; k0 += 64) {
#pragma unroll
    for (int r = 0; r < 8; ++r) {
      int rb = r * 32 + wave * 8;
      if (r < 2)
        async_copy16(Ab + (size_t)(rb + lrow) * K + k0 + lk, &sA[rb * 64]);
      async_copy16(Bb + (size_t)(rb + lrow) * K + k0 + lk, &sB[rb * 64]);
    }
    __syncthreads();
#pragma unroll
    for (int kk = 0; kk < 2; ++kk) {
      bf16x8 af[4], bfr[4];
#pragma unroll
      for (int mi = 0; mi < 4; ++mi)
        af[mi] = *(const bf16x8*)&sA[(mi * 16 + l16) * 64 + kk * 32 + lhi * 8];
#pragma unroll
      for (int ni = 0; ni < 4; ++ni)
        bfr[ni] = *(const bf16x8*)&sB[(wave * 64 + ni * 16 + l16) * 64 + kk * 32 + lhi * 8];
#pragma unroll
      for (int mi = 0; mi < 4; ++mi)
#pragma unroll
        for (int ni = 0; ni < 4; ++ni)
          acc[mi][ni] = __builtin_amdgcn_mfma_f32_16x16x32_bf16(af[mi], bfr[ni], acc[mi][ni], 0, 0, 0);
    }
    __syncthreads();
  }

  unsigned short* outB = out2 + z * ZS;
  const float* bias = b2_l + z * 1024;
  const unsigned short* resid = resid2 + z * ZS;
#pragma unroll
  for (int mi = 0; mi < 4; ++mi) {
#pragma unroll
    for (int ni = 0; ni < 4; ++ni) {
#pragma unroll
      for (int j = 0; j < 4; ++j) {
        int r = brow * 64 + mi * 16 + lhi * 4 + j;
        int c = wave * 64 + ni * 16 + l16;
        float v = acc[mi][ni][j] + bias[c] + bf2f(resid[(size_t)r * Ncol + c]);
        outB[(size_t)r * Ncol + c] = f2bf(v);
      }
    }
  }
}

// ---------------- wave-per-node fused softmax + aggregation + bias + residual + LN1 ----------------
// grid (Nn/4, 2): y = stream. 4 waves/block. Barrier-free. Fast path for deg <= 64.
__global__ __launch_bounds__(256) void agg_kernel(
    const unsigned short* __restrict__ hbuf2, const float* __restrict__ a_s2,
    const float* __restrict__ a_d2,
    const int* __restrict__ rowptr, const int* __restrict__ csrc,
    const float* __restrict__ bias_l, const unsigned short* __restrict__ x01b,
    const float* __restrict__ g1_l, const float* __restrict__ bt1_l,
    unsigned short* __restrict__ x1b2) {
  __shared__ float sw[4][320];  // [wave][slot*5 + head]  (stride 5: conflict-free)
  __shared__ int ssrc[4][64];
  const size_t ZS = (size_t)Nn * Dm;
  int z = blockIdx.y;
  const unsigned short* hb = hbuf2 + z * ZS;
  const float* a_s = a_s2 + (size_t)z * Nn * 4;
  const float* a_d = a_d2 + (size_t)z * Nn * 4;
  const float* bias = bias_l + z * 1024;
  const unsigned short* xres = x01b + z * ZS;
  const float* g1 = g1_l + z * 1024;
  const float* bt1 = bt1_l + z * 1024;
  unsigned short* x1b = x1b2 + z * ZS;

  int wave = threadIdx.x >> 6, lane = threadIdx.x & 63;
  int n = blockIdx.x * 4 + wave;
  int l32 = lane & 31;
  int par = lane >> 5;         // edge parity
  int hch = l32 >> 3;          // head of my channel block
  int c0 = l32 * 8;            // my 8 channels
  int beg = rowptr[n], end = rowptr[n + 1];
  float4 adv = *(const float4*)&a_d[n * 4];
  const float NI = -__builtin_inff();
  float acc[8] = {};
  float den = 0.f;

  if (end - beg <= 64) {
    // ---- fast path: single chunk, no online rescale ----
    int cnt = end - beg;
    float4 ev = {NI, NI, NI, NI};
    if (lane < cnt) {
      int s = csrc[beg + lane];
      ssrc[wave][lane] = s;
      float4 as = *(const float4*)&a_s[s * 4];
      float e0 = as.x + adv.x; ev.x = e0 > 0.f ? e0 : 0.2f * e0;
      float e1 = as.y + adv.y; ev.y = e1 > 0.f ? e1 : 0.2f * e1;
      float e2 = as.z + adv.z; ev.z = e2 > 0.f ? e2 : 0.2f * e2;
      float e3 = as.w + adv.w; ev.w = e3 > 0.f ? e3 : 0.2f * e3;
    }
    float4 mv = ev;
#pragma unroll
    for (int off = 32; off; off >>= 1) {
      mv.x = fmaxf(mv.x, __shfl_xor(mv.x, off));
      mv.y = fmaxf(mv.y, __shfl_xor(mv.y, off));
      mv.z = fmaxf(mv.z, __shfl_xor(mv.z, off));
      mv.w = fmaxf(mv.w, __shfl_xor(mv.w, off));
    }
    if (lane < cnt) {
      float* swl = &sw[wave][lane * 5];
      swl[0] = __expf(ev.x - mv.x);
      swl[1] = __expf(ev.y - mv.y);
      swl[2] = __expf(ev.z - mv.z);
      swl[3] = __expf(ev.w - mv.w);
    }
    __builtin_amdgcn_wave_barrier();
    for (int i = par; i < cnt; i += 2) {
      float w = sw[wave][i * 5 + hch];
      int s_i = ssrc[wave][i];
      bf16x8 hv = *(const bf16x8*)(hb + (size_t)s_i * 256 + c0);
#pragma unroll
      for (int j = 0; j < 8; ++j)
        acc[j] = fmaf(bf2f((unsigned short)hv[j]), w, acc[j]);
      den += w;
    }
  } else {
    // ---- general path: online softmax over 64-edge chunks ----
    float4 m4 = {NI, NI, NI, NI};
    for (int base = beg; base < end; base += 64) {
      int cnt = min(64, end - base);
      float4 ev = {NI, NI, NI, NI};
      if (lane < cnt) {
        int s = csrc[base + lane];
        ssrc[wave][lane] = s;
        float4 as = *(const float4*)&a_s[s * 4];
        float e0 = as.x + adv.x; ev.x = e0 > 0.f ? e0 : 0.2f * e0;
        float e1 = as.y + adv.y; ev.y = e1 > 0.f ? e1 : 0.2f * e1;
        float e2 = as.z + adv.z; ev.z = e2 > 0.f ? e2 : 0.2f * e2;
        float e3 = as.w + adv.w; ev.w = e3 > 0.f ? e3 : 0.2f * e3;
      }
      float4 mv = ev;
#pragma unroll
      for (int off = 32; off; off >>= 1) {
        mv.x = fmaxf(mv.x, __shfl_xor(mv.x, off));
        mv.y = fmaxf(mv.y, __shfl_xor(mv.y, off));
        mv.z = fmaxf(mv.z, __shfl_xor(mv.z, off));
        mv.w = fmaxf(mv.w, __shfl_xor(mv.w, off));
      }
      float4 m4n;
      m4n.x = fmaxf(m4.x, mv.x); m4n.y = fmaxf(m4.y, mv.y);
      m4n.z = fmaxf(m4.z, mv.z); m4n.w = fmaxf(m4.w, mv.w);
      float rm = __expf(sel4(m4, hch) - sel4(m4n, hch));
#pragma unroll
      for (int j = 0; j < 8; ++j) acc[j] *= rm;
      den *= rm;
      if (lane < cnt) {
        float* swl = &sw[wave][lane * 5];
        swl[0] = __expf(ev.x - m4n.x);
        swl[1] = __expf(ev.y - m4n.y);
        swl[2] = __expf(ev.z - m4n.z);
        swl[3] = __expf(ev.w - m4n.w);
      }
      m4 = m4n;
      __builtin_amdgcn_wave_barrier();
      for (int i = par; i < cnt; i += 2) {
        float w = sw[wave][i * 5 + hch];
        int s_i = ssrc[wave][i];
        bf16x8 hv = *(const bf16x8*)(hb + (size_t)s_i * 256 + c0);
#pragma unroll
        for (int j = 0; j < 8; ++j)
          acc[j] = fmaf(bf2f((unsigned short)hv[j]), w, acc[j]);
        den += w;
      }
      __builtin_amdgcn_wave_barrier();
    }
  }

  // combine edge parities (lane ^ 32 holds same channels, other parity)
#pragma unroll
  for (int j = 0; j < 8; ++j) acc[j] += __shfl_xor(acc[j], 32);
  den += __shfl_xor(den, 32);

  float invden = 1.f / fmaxf(den, 1e-16f);
  bf16x8 rv = *(const bf16x8*)(xres + (size_t)n * 256 + c0);
  float outv[8];
  float s1 = 0.f, s2 = 0.f;
#pragma unroll
  for (int j = 0; j < 8; ++j) {
    float v = acc[j] * invden + bias[c0 + j] + bf2f((unsigned short)rv[j]);
    outv[j] = v;
    s1 += v;
    s2 += v * v;
  }
  // LN reduce over the 32-lane half (halves hold identical data)
#pragma unroll
  for (int off = 16; off; off >>= 1) {
    s1 += __shfl_xor(s1, off);
    s2 += __shfl_xor(s2, off);
  }
  float mean = s1 * (1.f / 256.f);
  float var = s2 * (1.f / 256.f) - mean * mean;
  float rst = rsqrtf(var + 1e-5f);
  if (par == 0) {
    unsigned short yb[8];
#pragma unroll
    for (int j = 0; j < 8; ++j)
      yb[j] = f2bf((outv[j] - mean) * rst * g1[c0 + j] + bt1[c0 + j]);
    *(bf16x8*)&x1b[(size_t)n * 256 + c0] = *(bf16x8*)yb;
  }
}

// ---------------- dual LN2 (wave per node) ----------------
// PREP=1 (layers 0-2): writes ONLY next-layer bf16 inputs (out states are dead until layer 3).
// PREP=0 (layer 3): writes ONLY the f32 output states.
template <int PREP>
__global__ __launch_bounds__(256) void ln2_kernel(const unsigned short* __restrict__ tb2,
                                                  const float* __restrict__ g2_l,
                                                  const float* __restrict__ bt2_l,
                                                  float* __restrict__ out_hf,
                                                  float* __restrict__ out_hs,
                                                  unsigned short* __restrict__ x01b) {
  const size_t ZS = (size_t)Nn * Dm;
  int wave = threadIdx.x >> 6, lane = threadIdx.x & 63;
  int n = blockIdx.x * 4 + wave;
  int c0 = lane * 4;
  size_t idx = (size_t)n * 256 + c0;
  ushort4 u0 = *(const ushort4*)&tb2[idx];
  ushort4 u1 = *(const ushort4*)&tb2[ZS + idx];
  float v0[4] = {bf2f(u0.x), bf2f(u0.y), bf2f(u0.z), bf2f(u0.w)};
  float v1[4] = {bf2f(u1.x), bf2f(u1.y), bf2f(u1.z), bf2f(u1.w)};
  float a0 = 0.f, b0 = 0.f, a1 = 0.f, b1 = 0.f;
#pragma unroll
  for (int j = 0; j < 4; ++j) {
    a0 += v0[j]; b0 += v0[j] * v0[j];
    a1 += v1[j]; b1 += v1[j] * v1[j];
  }
#pragma unroll
  for (int off = 32; off; off >>= 1) {
    a0 += __shfl_xor(a0, off);
    b0 += __shfl_xor(b0, off);
    a1 += __shfl_xor(a1, off);
    b1 += __shfl_xor(b1, off);
  }
  float m0 = a0 * (1.f / 256.f), m1 = a1 * (1.f / 256.f);
  float r0 = rsqrtf(b0 * (1.f / 256.f) - m0 * m0 + 1e-5f);
  float r1 = rsqrtf(b1 * (1.f / 256.f) - m1 * m1 + 1e-5f);
  float4 y0, y1;
  unsigned short p0[4], p1[4];
#pragma unroll
  for (int j = 0; j < 4; ++j) {
    float yf = (v0[j] - m0) * r0 * g2_l[c0 + j] + bt2_l[c0 + j];
    float ys = (v1[j] - m1) * r1 * g2_l[1024 + c0 + j] + bt2_l[1024 + c0 + j];
    ((float*)&y0)[j] = yf;
    ((float*)&y1)[j] = ys;
    if (PREP) { p0[j] = f2bf(yf + ys); p1[j] = f2bf(ys); }
  }
  if (PREP) {
    // out states are dead until the last layer — skip their 32 MB of f32 writes
    *(ushort4*)&x01b[idx] = *(ushort4*)p0;
    *(ushort4*)&x01b[ZS + idx] = *(ushort4*)p1;
  } else {
    *(float4*)&out_hf[idx] = y0;
    *(float4*)&out_hs[idx] = y1;
  }
}

extern "C" void kernel_launch(void* const* d_in, const int* in_sizes, int n_in,
                              void* d_out, int out_size, void* d_ws, size_t ws_size,
                              hipStream_t stream) {
  const float* hf_in = (const float*)d_in[0];
  const float* hs_in = (const float*)d_in[1];
  const int* ei = (const int*)d_in[2];
  const int E = in_sizes[2] / 2;
  const float* Wgat = (const float*)d_in[3];
  const float* att_src = (const float*)d_in[4];
  const float* att_dst = (const float*)d_in[5];
  const float* bias_gat = (const float*)d_in[6];
  const float* W1 = (const float*)d_in[7];
  const float* b1 = (const float*)d_in[8];
  const float* W2 = (const float*)d_in[9];
  const float* b2 = (const float*)d_in[10];
  const float* g1 = (const float*)d_in[11];
  const float* bt1 = (const float*)d_in[12];
  const float* g2 = (const float*)d_in[13];
  const float* bt2 = (const float*)d_in[14];
  const int* src = ei;
  const int* dst = ei + E;
  const size_t ZS = (size_t)Nn * Dm;

  // ---- carve workspace ----
  char* wsp = (char*)d_ws;
  size_t off = 0;
  auto carve = [&](size_t bytes) -> void* {
    void* p = wsp + off;
    off += (bytes + 255) & ~(size_t)255;
    return p;
  };
  unsigned short* Wgt  = (unsigned short*)carve((size_t)8 * 256 * 256 * 2);
  unsigned short* W1t  = (unsigned short*)carve((size_t)8 * 256 * 1024 * 2);
  unsigned short* W2t  = (unsigned short*)carve((size_t)8 * 1024 * 256 * 2);
  int* cnt      = (int*)carve((size_t)Nn * 4);
  int* rowptr   = (int*)carve((size_t)(Nn + 1) * 4);
  int* cursor   = (int*)carve((size_t)Nn * 4);
  int* part     = (int*)carve((size_t)Nn * 4);
  int* bsum     = (int*)carve((size_t)64 * 4);
  int* bbase    = (int*)carve((size_t)64 * 4);
  int* csrc     = (int*)carve((size_t)E * 4);
  unsigned short* x01b = (unsigned short*)carve(2 * ZS * 2);  // [z]: layer input bf16
  unsigned short* hbuf2 = (unsigned short*)carve(2 * ZS * 2); // [z]: proj out bf16
  float* a_s2   = (float*)carve((size_t)2 * Nn * 4 * 4);
  float* a_d2   = (float*)carve((size_t)2 * Nn * 4 * 4);
  unsigned short* x1b2 = (unsigned short*)carve(2 * ZS * 2);  // [z]: LN1 out bf16
  unsigned short* tb2  = (unsigned short*)carve(2 * ZS * 2);  // [z]: FFN2 out (pre-LN2) bf16
  unsigned short* f_b2 = (unsigned short*)carve((size_t)2 * Nn * Ff * 2);  // [z]: FFN1 out
  if (off > ws_size) return;  // workspace too small — fail visibly

  // ---- once per call: weights (tiled transpose) + CSR ----
  wconvt_kernel<<<dim3(4, 4, 8), 256, 0, stream>>>(Wgat, Wgt, 256, 256);
  wconvt_kernel<<<dim3(16, 4, 8), 256, 0, stream>>>(W1, W1t, 256, 1024);
  wconvt_kernel<<<dim3(4, 16, 8), 256, 0, stream>>>(W2, W2t, 1024, 256);
  hipMemsetAsync(cnt, 0, (size_t)Nn * 4, stream);
  count_kernel<<<1024, 256, 0, stream>>>(dst, E, cnt);
  scan1_kernel<<<64, 256, 0, stream>>>(cnt, part, bsum);
  scan2_kernel<<<1, 64, 0, stream>>>(bsum, bbase, rowptr);
  scan3_kernel<<<64, 256, 0, stream>>>(part, bbase, rowptr, cursor);
  fill_kernel<<<1024, 256, 0, stream>>>(src, dst, E, cursor, csrc);

  float* out_hf = (float*)d_out;
  float* out_hs = out_hf + ZS;

  prep_kernel<<<2048, 256, 0, stream>>>(hf_in, hs_in, x01b, Nn * Dm);

  for (int l = 0; l < 4; ++l) {
    // proj (both streams) + fused scores
    proj_kernel<<<dim3(128, 4, 2), 256, 0, stream>>>(
        x01b, Wgt + (size_t)l * 65536, hbuf2,
        att_src + l * 256, att_dst + l * 256, a_s2, a_d2);
    // segment softmax + aggregate + bias + residual + LN1 (both streams)
    agg_kernel<<<dim3(Nn / 4, 2), 256, 0, stream>>>(
        hbuf2, a_s2, a_d2, rowptr, csrc,
        bias_gat + l * 256, x01b, g1 + l * 256, bt1 + l * 256, x1b2);
    // FFN (both streams per dispatch)
    ffn1_kernel<<<dim3(128, 8, 2), 256, 0, stream>>>(
        x1b2, W1t + (size_t)l * 256 * 1024, f_b2, b1 + l * 1024);
    // FFN2: BM=64, BN=256 — f read exactly once
    ffn2_kernel<<<dim3(256, 1, 2), 256, 0, stream>>>(
        f_b2, W2t + (size_t)l * 1024 * 256, tb2, b2 + l * 256, x1b2);
    // dual LN2 (+ next-layer prep for l<3; out states written only at l=3)
    if (l < 3) {
      ln2_kernel<1><<<Nn / 4, 256, 0, stream>>>(tb2, g2 + l * 256, bt2 + l * 256,
                                                out_hf, out_hs, x01b);
    } else {
      ln2_kernel<0><<<Nn / 4, 256, 0, stream>>>(tb2, g2 + l * 256, bt2 + l * 256,
                                                out_hf, out_hs, x01b);
    }
  }
}

// Round 13
// 631.952 us; speedup vs baseline: 1.1212x; 1.0206x over previous
//
#include <hip/hip_runtime.h>

#define Nn 16384
#define Dm 256
#define Ff 1024

typedef __attribute__((ext_vector_type(8))) short bf16x8;
typedef __attribute__((ext_vector_type(4))) float f32x4;

typedef const __attribute__((address_space(1))) unsigned int glb_u32;
typedef __attribute__((address_space(3))) unsigned int lds_u32;

__device__ __forceinline__ void async_copy16(const void* g, void* l) {
  __builtin_amdgcn_global_load_lds((glb_u32*)g, (lds_u32*)l, 16, 0, 0);
}

__device__ __forceinline__ unsigned short f2bf(float f) {
  union { float f; unsigned u; } v; v.f = f;
  return (unsigned short)((v.u + 0x7FFFu + ((v.u >> 16) & 1u)) >> 16);
}

__device__ __forceinline__ float bf2f(unsigned short u) {
  union { unsigned u; float f; } v; v.u = ((unsigned)u) << 16;
  return v.f;
}

__device__ __forceinline__ float sel4(float4 v, int h) {
  float r = v.x;
  r = (h == 1) ? v.y : r;
  r = (h == 2) ? v.z : r;
  r = (h == 3) ? v.w : r;
  return r;
}

// v_dot2_f32_bf16: D = a.bf16[0]*b.bf16[0] + a.bf16[1]*b.bf16[1] + c  (VOP3P, gfx940+)
__device__ __forceinline__ float dot2bf(unsigned a, unsigned b, float c) {
  float d;
  asm("v_dot2_f32_bf16 %0, %1, %2, %3" : "=v"(d) : "v"(a), "v"(b), "v"(c));
  return d;
}

// ---------------- tiled weight convert+transpose: wt[b][j][k] = bf16(w[b][k][j]) ----------------
__global__ __launch_bounds__(256) void wconvt_kernel(const float* __restrict__ w,
                                                     unsigned short* __restrict__ wt,
                                                     int K, int J) {
  __shared__ unsigned short t[64][65];
  int b = blockIdx.z;
  int j0 = blockIdx.x * 64, k0 = blockIdx.y * 64;
  int tj = threadIdx.x & 63, q = threadIdx.x >> 6;  // 4 rows per pass
  const float* wb = w + (size_t)b * K * J;
#pragma unroll
  for (int r = 0; r < 16; ++r) {
    int k = r * 4 + q;
    t[k][tj] = f2bf(wb[(size_t)(k0 + k) * J + j0 + tj]);
  }
  __syncthreads();
  unsigned short* wtb = wt + (size_t)b * K * J;
#pragma unroll
  for (int r = 0; r < 16; ++r) {
    int j = r * 4 + q;
    wtb[(size_t)(j0 + j) * K + k0 + tj] = t[tj][j];
  }
}

// ---------------- CSR build ----------------
__global__ void count_kernel(const int* __restrict__ dst, int E, int* __restrict__ cnt) {
  for (int e = blockIdx.x * blockDim.x + threadIdx.x; e < E; e += gridDim.x * blockDim.x)
    atomicAdd(&cnt[dst[e]], 1);
}

__global__ __launch_bounds__(256) void scan1_kernel(const int* __restrict__ cnt,
                                                    int* __restrict__ part,
                                                    int* __restrict__ bsum) {
  __shared__ int sd[256];
  int b = blockIdx.x, tid = threadIdx.x;
  int v = cnt[b * 256 + tid];
  sd[tid] = v;
  __syncthreads();
  for (int offt = 1; offt < 256; offt <<= 1) {
    int t = (tid >= offt) ? sd[tid - offt] : 0;
    __syncthreads();
    sd[tid] += t;
    __syncthreads();
  }
  part[b * 256 + tid] = sd[tid] - v;  // exclusive
  if (tid == 255) bsum[b] = sd[255];
}

__global__ __launch_bounds__(64) void scan2_kernel(const int* __restrict__ bsum,
                                                   int* __restrict__ bbase,
                                                   int* __restrict__ rowptr) {
  __shared__ int sd[64];
  int tid = threadIdx.x;
  int v = bsum[tid];
  sd[tid] = v;
  __syncthreads();
  for (int offt = 1; offt < 64; offt <<= 1) {
    int t = (tid >= offt) ? sd[tid - offt] : 0;
    __syncthreads();
    sd[tid] += t;
    __syncthreads();
  }
  bbase[tid] = sd[tid] - v;
  if (tid == 63) rowptr[Nn] = sd[63];
}

__global__ __launch_bounds__(256) void scan3_kernel(const int* __restrict__ part,
                                                    const int* __restrict__ bbase,
                                                    int* __restrict__ rowptr,
                                                    int* __restrict__ cursor) {
  int b = blockIdx.x, tid = threadIdx.x;
  int v = part[b * 256 + tid] + bbase[b];
  rowptr[b * 256 + tid] = v;
  cursor[b * 256 + tid] = v;
}

__global__ void fill_kernel(const int* __restrict__ src, const int* __restrict__ dst, int E,
                            int* __restrict__ cursor, int* __restrict__ csrc) {
  for (int e = blockIdx.x * blockDim.x + threadIdx.x; e < E; e += gridDim.x * blockDim.x) {
    int pos = atomicAdd(&cursor[dst[e]], 1);
    csrc[pos] = src[e];
  }
}

// ---------------- initial input prep (layer 0): x01b[0]=bf16(hf+hs), x01b[1]=bf16(hs) ----------------
__global__ void prep_kernel(const float* __restrict__ hf, const float* __restrict__ hs,
                            unsigned short* __restrict__ x01b, int total) {
  const size_t ZS = (size_t)Nn * Dm;
  for (int i = blockIdx.x * blockDim.x + threadIdx.x; i < total; i += gridDim.x * blockDim.x) {
    float a = hf[i], b = hs[i];
    x01b[i] = f2bf(a + b);
    x01b[ZS + i] = f2bf(b);
  }
}

// ---------------- proj GEMM (both streams, z) + fused attention scores, BK=64 ----------------
__global__ __launch_bounds__(256, 2) void proj_kernel(
    const unsigned short* __restrict__ xib, const unsigned short* __restrict__ Wgt_l,
    unsigned short* __restrict__ hbuf2, const float* __restrict__ asr_l,
    const float* __restrict__ ads_l, float* __restrict__ a_s2, float* __restrict__ a_d2) {
  __shared__ __align__(16) unsigned short sA[128 * 64];
  __shared__ __align__(16) unsigned short sB[64 * 64];
  const int K = 256;
  const size_t ZS = (size_t)Nn * Dm;
  int tid = threadIdx.x;
  int wave = tid >> 6, lane = tid & 63;
  int l16 = lane & 15, lhi = lane >> 4;
  int brow = blockIdx.x, bcol = blockIdx.y, z = blockIdx.z;
  int wm = wave >> 1, wn = wave & 1;  // wave tile 64x32

  const unsigned short* Ab = xib + z * ZS + (size_t)brow * 128 * K;
  const unsigned short* Bb = Wgt_l + (size_t)z * 4 * 65536 + (size_t)bcol * 64 * K;
  int lrow = lane >> 3, lk = (lane & 7) * 8;

  f32x4 acc[4][2] = {};

  for (int k0 = 0; k0 < K; k0 += 64) {
#pragma unroll
    for (int r = 0; r < 4; ++r) {
      int rb = r * 32 + wave * 8;
      async_copy16(Ab + (size_t)(rb + lrow) * K + k0 + lk, &sA[rb * 64]);
      if (r < 2)
        async_copy16(Bb + (size_t)(rb + lrow) * K + k0 + lk, &sB[rb * 64]);
    }
    __syncthreads();
#pragma unroll
    for (int kk = 0; kk < 2; ++kk) {
      bf16x8 af[4], bfr[2];
#pragma unroll
      for (int mi = 0; mi < 4; ++mi)
        af[mi] = *(const bf16x8*)&sA[(wm * 64 + mi * 16 + l16) * 64 + kk * 32 + lhi * 8];
#pragma unroll
      for (int ni = 0; ni < 2; ++ni)
        bfr[ni] = *(const bf16x8*)&sB[(wn * 32 + ni * 16 + l16) * 64 + kk * 32 + lhi * 8];
#pragma unroll
      for (int mi = 0; mi < 4; ++mi)
#pragma unroll
        for (int ni = 0; ni < 2; ++ni)
          acc[mi][ni] = __builtin_amdgcn_mfma_f32_16x16x32_bf16(af[mi], bfr[ni], acc[mi][ni], 0, 0, 0);
    }
    __syncthreads();
  }

  // ---- epilogue: C store (bf16) + per-row attention-score partials ----
  unsigned short* hb = hbuf2 + z * ZS;
  const float* asr_p = asr_l + z * 1024 + bcol * 64;
  const float* ads_p = ads_l + z * 1024 + bcol * 64;
  float as0 = asr_p[wn * 32 + l16],      ad0 = ads_p[wn * 32 + l16];
  float as1 = asr_p[wn * 32 + 16 + l16], ad1 = ads_p[wn * 32 + 16 + l16];
  float* sredS = (float*)sA;        // [wm][wn][64] = 256 floats
  float* sredD = (float*)sA + 256;  // (sA dead after K loop)

#pragma unroll
  for (int mi = 0; mi < 4; ++mi) {
#pragma unroll
    for (int j = 0; j < 4; ++j) {
      int r = brow * 128 + wm * 64 + mi * 16 + lhi * 4 + j;
      float v0 = acc[mi][0][j], v1 = acc[mi][1][j];
      hb[(size_t)r * 256 + bcol * 64 + wn * 32 + l16] = f2bf(v0);
      hb[(size_t)r * 256 + bcol * 64 + wn * 32 + 16 + l16] = f2bf(v1);
      float ps = v0 * as0 + v1 * as1;
      float pd = v0 * ad0 + v1 * ad1;
#pragma unroll
      for (int off = 1; off < 16; off <<= 1) {
        ps += __shfl_xor(ps, off);
        pd += __shfl_xor(pd, off);
      }
      if (l16 == 0) {
        int rl = mi * 16 + lhi * 4 + j;  // row within wave tile [0,64)
        sredS[wm * 128 + wn * 64 + rl] = ps;
        sredD[wm * 128 + wn * 64 + rl] = pd;
      }
    }
  }
  __syncthreads();
  if (tid < 128) {
    int w = tid >> 6, rl = tid & 63;
    float s = sredS[w * 128 + rl] + sredS[w * 128 + 64 + rl];
    float d = sredD[w * 128 + rl] + sredD[w * 128 + 64 + rl];
    int row = brow * 128 + tid;
    a_s2[(size_t)z * Nn * 4 + row * 4 + bcol] = s;
    a_d2[(size_t)z * Nn * 4 + row * 4 + bcol] = d;
  }
}

// ---------------- FFN1: f = relu(x1 @ W1 + b1), BK=64, BM=BN=128, z=stream ----------------
__global__ __launch_bounds__(256, 2) void ffn1_kernel(
    const unsigned short* __restrict__ A2, const unsigned short* __restrict__ Bt_l,
    unsigned short* __restrict__ out2, const float* __restrict__ b1_l) {
  const int K = 256, Ncol = Ff;
  const size_t ZS = (size_t)Nn * Dm;
  __shared__ __align__(16) unsigned short sA[128 * 64];
  __shared__ __align__(16) unsigned short sB[128 * 64];
  int tid = threadIdx.x, wave = tid >> 6, lane = tid & 63;
  int l16 = lane & 15, lhi = lane >> 4;
  int brow = blockIdx.x, bcol = blockIdx.y, z = blockIdx.z;
  int wm = wave >> 1, wn = wave & 1;  // wave tile 64x64

  const unsigned short* Ab = A2 + z * ZS + (size_t)brow * 128 * K;
  const unsigned short* Bb = Bt_l + (size_t)z * 4 * Ff * 256 + (size_t)bcol * 128 * K;
  int lrow = lane >> 3, lk = (lane & 7) * 8;

  f32x4 acc[4][4] = {};

  for (int k0 = 0; k0 < K; k0 += 64) {
#pragma unroll
    for (int r = 0; r < 4; ++r) {
      int rb = r * 32 + wave * 8;
      async_copy16(Ab + (size_t)(rb + lrow) * K + k0 + lk, &sA[rb * 64]);
      async_copy16(Bb + (size_t)(rb + lrow) * K + k0 + lk, &sB[rb * 64]);
    }
    __syncthreads();
#pragma unroll
    for (int kk = 0; kk < 2; ++kk) {
      bf16x8 af[4], bfr[4];
#pragma unroll
      for (int mi = 0; mi < 4; ++mi)
        af[mi] = *(const bf16x8*)&sA[(wm * 64 + mi * 16 + l16) * 64 + kk * 32 + lhi * 8];
#pragma unroll
      for (int ni = 0; ni < 4; ++ni)
        bfr[ni] = *(const bf16x8*)&sB[(wn * 64 + ni * 16 + l16) * 64 + kk * 32 + lhi * 8];
#pragma unroll
      for (int mi = 0; mi < 4; ++mi)
#pragma unroll
        for (int ni = 0; ni < 4; ++ni)
          acc[mi][ni] = __builtin_amdgcn_mfma_f32_16x16x32_bf16(af[mi], bfr[ni], acc[mi][ni], 0, 0, 0);
    }
    __syncthreads();
  }

  unsigned short* outB = out2 + (size_t)z * Nn * Ff;
  const float* bias = b1_l + z * 4096;
#pragma unroll
  for (int mi = 0; mi < 4; ++mi) {
#pragma unroll
    for (int ni = 0; ni < 4; ++ni) {
#pragma unroll
      for (int j = 0; j < 4; ++j) {
        int r = brow * 128 + wm * 64 + mi * 16 + lhi * 4 + j;
        int c = bcol * 128 + wn * 64 + ni * 16 + l16;
        float v = acc[mi][ni][j] + bias[c];
        v = v > 0.f ? v : 0.f;
        outB[(size_t)r * Ncol + c] = f2bf(v);
      }
    }
  }
}

// ---------------- FFN2: t = f @ W2 + b2 + x1 (bf16 resid), bf16 out ----------------
// BM=64, BN=256, BK=64, z=stream.
__global__ __launch_bounds__(256, 2) void ffn2_kernel(
    const unsigned short* __restrict__ A2, const unsigned short* __restrict__ Bt_l,
    unsigned short* __restrict__ out2, const float* __restrict__ b2_l,
    const unsigned short* __restrict__ resid2) {
  const int K = Ff, Ncol = 256;
  const size_t ZS = (size_t)Nn * Dm;
  __shared__ __align__(16) unsigned short sA[64 * 64];    // 8 KB
  __shared__ __align__(16) unsigned short sB[256 * 64];   // 32 KB
  int tid = threadIdx.x, wave = tid >> 6, lane = tid & 63;
  int l16 = lane & 15, lhi = lane >> 4;
  int brow = blockIdx.x, z = blockIdx.z;

  const unsigned short* Ab = A2 + (size_t)z * Nn * Ff + (size_t)brow * 64 * K;
  const unsigned short* Bb = Bt_l + (size_t)z * 4 * Ff * 256;  // all 256 cols
  int lrow = lane >> 3, lk = (lane & 7) * 8;

  f32x4 acc[4][4] = {};

  for (int k0 = 0; k0 < K; k0 += 64) {
#pragma unroll
    for (int r = 0; r < 8; ++r) {
      int rb = r * 32 + wave * 8;
      if (r < 2)
        async_copy16(Ab + (size_t)(rb + lrow) * K + k0 + lk, &sA[rb * 64]);
      async_copy16(Bb + (size_t)(rb + lrow) * K + k0 + lk, &sB[rb * 64]);
    }
    __syncthreads();
#pragma unroll
    for (int kk = 0; kk < 2; ++kk) {
      bf16x8 af[4], bfr[4];
#pragma unroll
      for (int mi = 0; mi < 4; ++mi)
        af[mi] = *(const bf16x8*)&sA[(mi * 16 + l16) * 64 + kk * 32 + lhi * 8];
#pragma unroll
      for (int ni = 0; ni < 4; ++ni)
        bfr[ni] = *(const bf16x8*)&sB[(wave * 64 + ni * 16 + l16) * 64 + kk * 32 + lhi * 8];
#pragma unroll
      for (int mi = 0; mi < 4; ++mi)
#pragma unroll
        for (int ni = 0; ni < 4; ++ni)
          acc[mi][ni] = __builtin_amdgcn_mfma_f32_16x16x32_bf16(af[mi], bfr[ni], acc[mi][ni], 0, 0, 0);
    }
    __syncthreads();
  }

  unsigned short* outB = out2 + z * ZS;
  const float* bias = b2_l + z * 1024;
  const unsigned short* resid = resid2 + z * ZS;
#pragma unroll
  for (int mi = 0; mi < 4; ++mi) {
#pragma unroll
    for (int ni = 0; ni < 4; ++ni) {
#pragma unroll
      for (int j = 0; j < 4; ++j) {
        int r = brow * 64 + mi * 16 + lhi * 4 + j;
        int c = wave * 64 + ni * 16 + l16;
        float v = acc[mi][ni][j] + bias[c] + bf2f(resid[(size_t)r * Ncol + c]);
        outB[(size_t)r * Ncol + c] = f2bf(v);
      }
    }
  }
}

// ---------------- wave-per-node fused softmax + aggregation + bias + residual + LN1 ----------------
// grid (Nn/4, 2): y = stream. 4 waves/block. Barrier-free.
// PV via v_dot2_f32_bf16 on edge pairs: weights packed bf16 in LDS, channels paired via v_perm.
__global__ __launch_bounds__(256) void agg_kernel(
    const unsigned short* __restrict__ hbuf2, const float* __restrict__ a_s2,
    const float* __restrict__ a_d2,
    const int* __restrict__ rowptr, const int* __restrict__ csrc,
    const float* __restrict__ bias_l, const unsigned short* __restrict__ x01b,
    const float* __restrict__ g1_l, const float* __restrict__ bt1_l,
    unsigned short* __restrict__ x1b2) {
  __shared__ unsigned short sw16[4][4][64];  // [wave][head][edge] packed bf16 weights
  __shared__ int ssrc[4][64];
  const size_t ZS = (size_t)Nn * Dm;
  int z = blockIdx.y;
  const unsigned short* hb = hbuf2 + z * ZS;
  const float* a_s = a_s2 + (size_t)z * Nn * 4;
  const float* a_d = a_d2 + (size_t)z * Nn * 4;
  const float* bias = bias_l + z * 1024;
  const unsigned short* xres = x01b + z * ZS;
  const float* g1 = g1_l + z * 1024;
  const float* bt1 = bt1_l + z * 1024;
  unsigned short* x1b = x1b2 + z * ZS;

  int wave = threadIdx.x >> 6, lane = threadIdx.x & 63;
  int n = blockIdx.x * 4 + wave;
  int l32 = lane & 31;
  int par = lane >> 5;         // pair parity (pair k handled by half k&1)
  int hch = l32 >> 3;          // head of my channel block
  int c0 = l32 * 8;            // my 8 channels
  int beg = rowptr[n], end = rowptr[n + 1];
  float4 adv = *(const float4*)&a_d[n * 4];
  const float NI = -__builtin_inff();
  float acc[8] = {};
  float den = 0.f;

  // PV over one staged chunk of cnt (<=64) edges; acc/den updated.
  auto pv_chunk = [&](int cnt) {
    int i = par * 2;
    for (; i + 1 < cnt; i += 4) {
      int sa = ssrc[wave][i], sb = ssrc[wave][i + 1];
      unsigned wp = *(const unsigned*)&sw16[wave][hch][i];  // i even -> dword aligned
      uint4 A = *(const uint4*)(hb + (size_t)sa * 256 + c0);
      uint4 B = *(const uint4*)(hb + (size_t)sb * 256 + c0);
      acc[0] = dot2bf(__builtin_amdgcn_perm(A.x, B.x, 0x01000504u), wp, acc[0]);
      acc[1] = dot2bf(__builtin_amdgcn_perm(A.x, B.x, 0x03020706u), wp, acc[1]);
      acc[2] = dot2bf(__builtin_amdgcn_perm(A.y, B.y, 0x01000504u), wp, acc[2]);
      acc[3] = dot2bf(__builtin_amdgcn_perm(A.y, B.y, 0x03020706u), wp, acc[3]);
      acc[4] = dot2bf(__builtin_amdgcn_perm(A.z, B.z, 0x01000504u), wp, acc[4]);
      acc[5] = dot2bf(__builtin_amdgcn_perm(A.z, B.z, 0x03020706u), wp, acc[5]);
      acc[6] = dot2bf(__builtin_amdgcn_perm(A.w, B.w, 0x01000504u), wp, acc[6]);
      acc[7] = dot2bf(__builtin_amdgcn_perm(A.w, B.w, 0x03020706u), wp, acc[7]);
      den += bf2f((unsigned short)(wp & 0xFFFFu)) + bf2f((unsigned short)(wp >> 16));
    }
    if (cnt & 1) {
      int e = cnt - 1;
      if (((e >> 1) & 1) == par) {
        int s_i = ssrc[wave][e];
        float w = bf2f(sw16[wave][hch][e]);
        bf16x8 hv = *(const bf16x8*)(hb + (size_t)s_i * 256 + c0);
#pragma unroll
        for (int j = 0; j < 8; ++j)
          acc[j] = fmaf(bf2f((unsigned short)hv[j]), w, acc[j]);
        den += w;
      }
    }
  };

  if (end - beg <= 64) {
    // ---- fast path: single chunk, no online rescale ----
    int cnt = end - beg;
    float4 ev = {NI, NI, NI, NI};
    if (lane < cnt) {
      int s = csrc[beg + lane];
      ssrc[wave][lane] = s;
      float4 as = *(const float4*)&a_s[s * 4];
      float e0 = as.x + adv.x; ev.x = e0 > 0.f ? e0 : 0.2f * e0;
      float e1 = as.y + adv.y; ev.y = e1 > 0.f ? e1 : 0.2f * e1;
      float e2 = as.z + adv.z; ev.z = e2 > 0.f ? e2 : 0.2f * e2;
      float e3 = as.w + adv.w; ev.w = e3 > 0.f ? e3 : 0.2f * e3;
    }
    float4 mv = ev;
#pragma unroll
    for (int off = 32; off; off >>= 1) {
      mv.x = fmaxf(mv.x, __shfl_xor(mv.x, off));
      mv.y = fmaxf(mv.y, __shfl_xor(mv.y, off));
      mv.z = fmaxf(mv.z, __shfl_xor(mv.z, off));
      mv.w = fmaxf(mv.w, __shfl_xor(mv.w, off));
    }
    if (lane < cnt) {
      sw16[wave][0][lane] = f2bf(__expf(ev.x - mv.x));
      sw16[wave][1][lane] = f2bf(__expf(ev.y - mv.y));
      sw16[wave][2][lane] = f2bf(__expf(ev.z - mv.z));
      sw16[wave][3][lane] = f2bf(__expf(ev.w - mv.w));
    }
    __builtin_amdgcn_wave_barrier();
    pv_chunk(cnt);
  } else {
    // ---- general path: online softmax over 64-edge chunks ----
    float4 m4 = {NI, NI, NI, NI};
    for (int base = beg; base < end; base += 64) {
      int cnt = min(64, end - base);
      float4 ev = {NI, NI, NI, NI};
      if (lane < cnt) {
        int s = csrc[base + lane];
        ssrc[wave][lane] = s;
        float4 as = *(const float4*)&a_s[s * 4];
        float e0 = as.x + adv.x; ev.x = e0 > 0.f ? e0 : 0.2f * e0;
        float e1 = as.y + adv.y; ev.y = e1 > 0.f ? e1 : 0.2f * e1;
        float e2 = as.z + adv.z; ev.z = e2 > 0.f ? e2 : 0.2f * e2;
        float e3 = as.w + adv.w; ev.w = e3 > 0.f ? e3 : 0.2f * e3;
      }
      float4 mv = ev;
#pragma unroll
      for (int off = 32; off; off >>= 1) {
        mv.x = fmaxf(mv.x, __shfl_xor(mv.x, off));
        mv.y = fmaxf(mv.y, __shfl_xor(mv.y, off));
        mv.z = fmaxf(mv.z, __shfl_xor(mv.z, off));
        mv.w = fmaxf(mv.w, __shfl_xor(mv.w, off));
      }
      float4 m4n;
      m4n.x = fmaxf(m4.x, mv.x); m4n.y = fmaxf(m4.y, mv.y);
      m4n.z = fmaxf(m4.z, mv.z); m4n.w = fmaxf(m4.w, mv.w);
      float rm = __expf(sel4(m4, hch) - sel4(m4n, hch));
#pragma unroll
      for (int j = 0; j < 8; ++j) acc[j] *= rm;
      den *= rm;
      if (lane < cnt) {
        sw16[wave][0][lane] = f2bf(__expf(ev.x - m4n.x));
        sw16[wave][1][lane] = f2bf(__expf(ev.y - m4n.y));
        sw16[wave][2][lane] = f2bf(__expf(ev.z - m4n.z));
        sw16[wave][3][lane] = f2bf(__expf(ev.w - m4n.w));
      }
      m4 = m4n;
      __builtin_amdgcn_wave_barrier();
      pv_chunk(cnt);
      __builtin_amdgcn_wave_barrier();
    }
  }

  // combine pair parities (lane ^ 32 holds same channels, other parity)
#pragma unroll
  for (int j = 0; j < 8; ++j) acc[j] += __shfl_xor(acc[j], 32);
  den += __shfl_xor(den, 32);

  float invden = 1.f / fmaxf(den, 1e-16f);
  bf16x8 rv = *(const bf16x8*)(xres + (size_t)n * 256 + c0);
  float outv[8];
  float s1 = 0.f, s2 = 0.f;
#pragma unroll
  for (int j = 0; j < 8; ++j) {
    float v = acc[j] * invden + bias[c0 + j] + bf2f((unsigned short)rv[j]);
    outv[j] = v;
    s1 += v;
    s2 += v * v;
  }
  // LN reduce over the 32-lane half (halves hold identical data)
#pragma unroll
  for (int off = 16; off; off >>= 1) {
    s1 += __shfl_xor(s1, off);
    s2 += __shfl_xor(s2, off);
  }
  float mean = s1 * (1.f / 256.f);
  float var = s2 * (1.f / 256.f) - mean * mean;
  float rst = rsqrtf(var + 1e-5f);
  if (par == 0) {
    unsigned short yb[8];
#pragma unroll
    for (int j = 0; j < 8; ++j)
      yb[j] = f2bf((outv[j] - mean) * rst * g1[c0 + j] + bt1[c0 + j]);
    *(bf16x8*)&x1b[(size_t)n * 256 + c0] = *(bf16x8*)yb;
  }
}

// ---------------- dual LN2 (wave per node) ----------------
// PREP=1 (layers 0-2): writes ONLY next-layer bf16 inputs. PREP=0 (layer 3): writes f32 states.
template <int PREP>
__global__ __launch_bounds__(256) void ln2_kernel(const unsigned short* __restrict__ tb2,
                                                  const float* __restrict__ g2_l,
                                                  const float* __restrict__ bt2_l,
                                                  float* __restrict__ out_hf,
                                                  float* __restrict__ out_hs,
                                                  unsigned short* __restrict__ x01b) {
  const size_t ZS = (size_t)Nn * Dm;
  int wave = threadIdx.x >> 6, lane = threadIdx.x & 63;
  int n = blockIdx.x * 4 + wave;
  int c0 = lane * 4;
  size_t idx = (size_t)n * 256 + c0;
  ushort4 u0 = *(const ushort4*)&tb2[idx];
  ushort4 u1 = *(const ushort4*)&tb2[ZS + idx];
  float v0[4] = {bf2f(u0.x), bf2f(u0.y), bf2f(u0.z), bf2f(u0.w)};
  float v1[4] = {bf2f(u1.x), bf2f(u1.y), bf2f(u1.z), bf2f(u1.w)};
  float a0 = 0.f, b0 = 0.f, a1 = 0.f, b1 = 0.f;
#pragma unroll
  for (int j = 0; j < 4; ++j) {
    a0 += v0[j]; b0 += v0[j] * v0[j];
    a1 += v1[j]; b1 += v1[j] * v1[j];
  }
#pragma unroll
  for (int off = 32; off; off >>= 1) {
    a0 += __shfl_xor(a0, off);
    b0 += __shfl_xor(b0, off);
    a1 += __shfl_xor(a1, off);
    b1 += __shfl_xor(b1, off);
  }
  float m0 = a0 * (1.f / 256.f), m1 = a1 * (1.f / 256.f);
  float r0 = rsqrtf(b0 * (1.f / 256.f) - m0 * m0 + 1e-5f);
  float r1 = rsqrtf(b1 * (1.f / 256.f) - m1 * m1 + 1e-5f);
  float4 y0, y1;
  unsigned short p0[4], p1[4];
#pragma unroll
  for (int j = 0; j < 4; ++j) {
    float yf = (v0[j] - m0) * r0 * g2_l[c0 + j] + bt2_l[c0 + j];
    float ys = (v1[j] - m1) * r1 * g2_l[1024 + c0 + j] + bt2_l[1024 + c0 + j];
    ((float*)&y0)[j] = yf;
    ((float*)&y1)[j] = ys;
    if (PREP) { p0[j] = f2bf(yf + ys); p1[j] = f2bf(ys); }
  }
  if (PREP) {
    *(ushort4*)&x01b[idx] = *(ushort4*)p0;
    *(ushort4*)&x01b[ZS + idx] = *(ushort4*)p1;
  } else {
    *(float4*)&out_hf[idx] = y0;
    *(float4*)&out_hs[idx] = y1;
  }
}

extern "C" void kernel_launch(void* const* d_in, const int* in_sizes, int n_in,
                              void* d_out, int out_size, void* d_ws, size_t ws_size,
                              hipStream_t stream) {
  const float* hf_in = (const float*)d_in[0];
  const float* hs_in = (const float*)d_in[1];
  const int* ei = (const int*)d_in[2];
  const int E = in_sizes[2] / 2;
  const float* Wgat = (const float*)d_in[3];
  const float* att_src = (const float*)d_in[4];
  const float* att_dst = (const float*)d_in[5];
  const float* bias_gat = (const float*)d_in[6];
  const float* W1 = (const float*)d_in[7];
  const float* b1 = (const float*)d_in[8];
  const float* W2 = (const float*)d_in[9];
  const float* b2 = (const float*)d_in[10];
  const float* g1 = (const float*)d_in[11];
  const float* bt1 = (const float*)d_in[12];
  const float* g2 = (const float*)d_in[13];
  const float* bt2 = (const float*)d_in[14];
  const int* src = ei;
  const int* dst = ei + E;
  const size_t ZS = (size_t)Nn * Dm;

  // ---- carve workspace ----
  char* wsp = (char*)d_ws;
  size_t off = 0;
  auto carve = [&](size_t bytes) -> void* {
    void* p = wsp + off;
    off += (bytes + 255) & ~(size_t)255;
    return p;
  };
  unsigned short* Wgt  = (unsigned short*)carve((size_t)8 * 256 * 256 * 2);
  unsigned short* W1t  = (unsigned short*)carve((size_t)8 * 256 * 1024 * 2);
  unsigned short* W2t  = (unsigned short*)carve((size_t)8 * 1024 * 256 * 2);
  int* cnt      = (int*)carve((size_t)Nn * 4);
  int* rowptr   = (int*)carve((size_t)(Nn + 1) * 4);
  int* cursor   = (int*)carve((size_t)Nn * 4);
  int* part     = (int*)carve((size_t)Nn * 4);
  int* bsum     = (int*)carve((size_t)64 * 4);
  int* bbase    = (int*)carve((size_t)64 * 4);
  int* csrc     = (int*)carve((size_t)E * 4);
  unsigned short* x01b = (unsigned short*)carve(2 * ZS * 2);  // [z]: layer input bf16
  unsigned short* hbuf2 = (unsigned short*)carve(2 * ZS * 2); // [z]: proj out bf16
  float* a_s2   = (float*)carve((size_t)2 * Nn * 4 * 4);
  float* a_d2   = (float*)carve((size_t)2 * Nn * 4 * 4);
  unsigned short* x1b2 = (unsigned short*)carve(2 * ZS * 2);  // [z]: LN1 out bf16
  unsigned short* tb2  = (unsigned short*)carve(2 * ZS * 2);  // [z]: FFN2 out (pre-LN2) bf16
  unsigned short* f_b2 = (unsigned short*)carve((size_t)2 * Nn * Ff * 2);  // [z]: FFN1 out
  if (off > ws_size) return;  // workspace too small — fail visibly

  // ---- once per call: weights (tiled transpose) + CSR ----
  wconvt_kernel<<<dim3(4, 4, 8), 256, 0, stream>>>(Wgat, Wgt, 256, 256);
  wconvt_kernel<<<dim3(16, 4, 8), 256, 0, stream>>>(W1, W1t, 256, 1024);
  wconvt_kernel<<<dim3(4, 16, 8), 256, 0, stream>>>(W2, W2t, 1024, 256);
  hipMemsetAsync(cnt, 0, (size_t)Nn * 4, stream);
  count_kernel<<<1024, 256, 0, stream>>>(dst, E, cnt);
  scan1_kernel<<<64, 256, 0, stream>>>(cnt, part, bsum);
  scan2_kernel<<<1, 64, 0, stream>>>(bsum, bbase, rowptr);
  scan3_kernel<<<64, 256, 0, stream>>>(part, bbase, rowptr, cursor);
  fill_kernel<<<1024, 256, 0, stream>>>(src, dst, E, cursor, csrc);

  float* out_hf = (float*)d_out;
  float* out_hs = out_hf + ZS;

  prep_kernel<<<2048, 256, 0, stream>>>(hf_in, hs_in, x01b, Nn * Dm);

  for (int l = 0; l < 4; ++l) {
    // proj (both streams) + fused scores
    proj_kernel<<<dim3(128, 4, 2), 256, 0, stream>>>(
        x01b, Wgt + (size_t)l * 65536, hbuf2,
        att_src + l * 256, att_dst + l * 256, a_s2, a_d2);
    // segment softmax + aggregate + bias + residual + LN1 (both streams)
    agg_kernel<<<dim3(Nn / 4, 2), 256, 0, stream>>>(
        hbuf2, a_s2, a_d2, rowptr, csrc,
        bias_gat + l * 256, x01b, g1 + l * 256, bt1 + l * 256, x1b2);
    // FFN (both streams per dispatch)
    ffn1_kernel<<<dim3(128, 8, 2), 256, 0, stream>>>(
        x1b2, W1t + (size_t)l * 256 * 1024, f_b2, b1 + l * 1024);
    ffn2_kernel<<<dim3(256, 1, 2), 256, 0, stream>>>(
        f_b2, W2t + (size_t)l * 1024 * 256, tb2, b2 + l * 256, x1b2);
    // dual LN2 (+ next-layer prep for l<3; out states written only at l=3)
    if (l < 3) {
      ln2_kernel<1><<<Nn / 4, 256, 0, stream>>>(tb2, g2 + l * 256, bt2 + l * 256,
                                                out_hf, out_hs, x01b);
    } else {
      ln2_kernel<0><<<Nn / 4, 256, 0, stream>>>(tb2, g2 + l * 256, bt2 + l * 256,
                                                out_hf, out_hs, x01b);
    }
  }
}

// Round 14
// 631.913 us; speedup vs baseline: 1.1213x; 1.0001x over previous
//
#include <hip/hip_runtime.h>

#define Nn 16384
#define Dm 256
#define Ff 1024

typedef __attribute__((ext_vector_type(8))) short bf16x8;
typedef __attribute__((ext_vector_type(4))) float f32x4;

typedef const __attribute__((address_space(1))) unsigned int glb_u32;
typedef __attribute__((address_space(3))) unsigned int lds_u32;

__device__ __forceinline__ void async_copy16(const void* g, void* l) {
  __builtin_amdgcn_global_load_lds((glb_u32*)g, (lds_u32*)l, 16, 0, 0);
}

__device__ __forceinline__ unsigned short f2bf(float f) {
  union { float f; unsigned u; } v; v.f = f;
  return (unsigned short)((v.u + 0x7FFFu + ((v.u >> 16) & 1u)) >> 16);
}

__device__ __forceinline__ float bf2f(unsigned short u) {
  union { unsigned u; float f; } v; v.u = ((unsigned)u) << 16;
  return v.f;
}

__device__ __forceinline__ float sel4(float4 v, int h) {
  float r = v.x;
  r = (h == 1) ? v.y : r;
  r = (h == 2) ? v.z : r;
  r = (h == 3) ? v.w : r;
  return r;
}

// v_dot2_f32_bf16: D = a.bf16[0]*b.bf16[0] + a.bf16[1]*b.bf16[1] + c  (VOP3P, gfx940+)
__device__ __forceinline__ float dot2bf(unsigned a, unsigned b, float c) {
  float d;
  asm("v_dot2_f32_bf16 %0, %1, %2, %3" : "=v"(d) : "v"(a), "v"(b), "v"(c));
  return d;
}

// ---------------- tiled weight convert+transpose: wt[b][j][k] = bf16(w[b][k][j]) ----------------
__global__ __launch_bounds__(256) void wconvt_kernel(const float* __restrict__ w,
                                                     unsigned short* __restrict__ wt,
                                                     int K, int J) {
  __shared__ unsigned short t[64][65];
  int b = blockIdx.z;
  int j0 = blockIdx.x * 64, k0 = blockIdx.y * 64;
  int tj = threadIdx.x & 63, q = threadIdx.x >> 6;  // 4 rows per pass
  const float* wb = w + (size_t)b * K * J;
#pragma unroll
  for (int r = 0; r < 16; ++r) {
    int k = r * 4 + q;
    t[k][tj] = f2bf(wb[(size_t)(k0 + k) * J + j0 + tj]);
  }
  __syncthreads();
  unsigned short* wtb = wt + (size_t)b * K * J;
#pragma unroll
  for (int r = 0; r < 16; ++r) {
    int j = r * 4 + q;
    wtb[(size_t)(j0 + j) * K + k0 + tj] = t[tj][j];
  }
}

// ---------------- CSR build ----------------
__global__ void count_kernel(const int* __restrict__ dst, int E, int* __restrict__ cnt) {
  for (int e = blockIdx.x * blockDim.x + threadIdx.x; e < E; e += gridDim.x * blockDim.x)
    atomicAdd(&cnt[dst[e]], 1);
}

__global__ __launch_bounds__(256) void scan1_kernel(const int* __restrict__ cnt,
                                                    int* __restrict__ part,
                                                    int* __restrict__ bsum) {
  __shared__ int sd[256];
  int b = blockIdx.x, tid = threadIdx.x;
  int v = cnt[b * 256 + tid];
  sd[tid] = v;
  __syncthreads();
  for (int offt = 1; offt < 256; offt <<= 1) {
    int t = (tid >= offt) ? sd[tid - offt] : 0;
    __syncthreads();
    sd[tid] += t;
    __syncthreads();
  }
  part[b * 256 + tid] = sd[tid] - v;  // exclusive
  if (tid == 255) bsum[b] = sd[255];
}

__global__ __launch_bounds__(64) void scan2_kernel(const int* __restrict__ bsum,
                                                   int* __restrict__ bbase,
                                                   int* __restrict__ rowptr) {
  __shared__ int sd[64];
  int tid = threadIdx.x;
  int v = bsum[tid];
  sd[tid] = v;
  __syncthreads();
  for (int offt = 1; offt < 64; offt <<= 1) {
    int t = (tid >= offt) ? sd[tid - offt] : 0;
    __syncthreads();
    sd[tid] += t;
    __syncthreads();
  }
  bbase[tid] = sd[tid] - v;
  if (tid == 63) rowptr[Nn] = sd[63];
}

__global__ __launch_bounds__(256) void scan3_kernel(const int* __restrict__ part,
                                                    const int* __restrict__ bbase,
                                                    int* __restrict__ rowptr,
                                                    int* __restrict__ cursor) {
  int b = blockIdx.x, tid = threadIdx.x;
  int v = part[b * 256 + tid] + bbase[b];
  rowptr[b * 256 + tid] = v;
  cursor[b * 256 + tid] = v;
}

__global__ void fill_kernel(const int* __restrict__ src, const int* __restrict__ dst, int E,
                            int* __restrict__ cursor, int* __restrict__ csrc) {
  for (int e = blockIdx.x * blockDim.x + threadIdx.x; e < E; e += gridDim.x * blockDim.x) {
    int pos = atomicAdd(&cursor[dst[e]], 1);
    csrc[pos] = src[e];
  }
}

// ---------------- initial input prep (layer 0): x01b[0]=bf16(hf+hs), x01b[1]=bf16(hs) ----------------
__global__ void prep_kernel(const float* __restrict__ hf, const float* __restrict__ hs,
                            unsigned short* __restrict__ x01b, int total) {
  const size_t ZS = (size_t)Nn * Dm;
  for (int i = blockIdx.x * blockDim.x + threadIdx.x; i < total; i += gridDim.x * blockDim.x) {
    float a = hf[i], b = hs[i];
    x01b[i] = f2bf(a + b);
    x01b[ZS + i] = f2bf(b);
  }
}

// ---------------- proj GEMM (both streams, z) + fused attention scores, BK=64 ----------------
__global__ __launch_bounds__(256, 2) void proj_kernel(
    const unsigned short* __restrict__ xib, const unsigned short* __restrict__ Wgt_l,
    unsigned short* __restrict__ hbuf2, const float* __restrict__ asr_l,
    const float* __restrict__ ads_l, float* __restrict__ a_s2, float* __restrict__ a_d2) {
  __shared__ __align__(16) unsigned short sA[128 * 64];
  __shared__ __align__(16) unsigned short sB[64 * 64];
  const int K = 256;
  const size_t ZS = (size_t)Nn * Dm;
  int tid = threadIdx.x;
  int wave = tid >> 6, lane = tid & 63;
  int l16 = lane & 15, lhi = lane >> 4;
  int brow = blockIdx.x, bcol = blockIdx.y, z = blockIdx.z;
  int wm = wave >> 1, wn = wave & 1;  // wave tile 64x32

  const unsigned short* Ab = xib + z * ZS + (size_t)brow * 128 * K;
  const unsigned short* Bb = Wgt_l + (size_t)z * 4 * 65536 + (size_t)bcol * 64 * K;
  int lrow = lane >> 3, lk = (lane & 7) * 8;

  f32x4 acc[4][2] = {};

  for (int k0 = 0; k0 < K; k0 += 64) {
#pragma unroll
    for (int r = 0; r < 4; ++r) {
      int rb = r * 32 + wave * 8;
      async_copy16(Ab + (size_t)(rb + lrow) * K + k0 + lk, &sA[rb * 64]);
      if (r < 2)
        async_copy16(Bb + (size_t)(rb + lrow) * K + k0 + lk, &sB[rb * 64]);
    }
    __syncthreads();
#pragma unroll
    for (int kk = 0; kk < 2; ++kk) {
      bf16x8 af[4], bfr[2];
#pragma unroll
      for (int mi = 0; mi < 4; ++mi)
        af[mi] = *(const bf16x8*)&sA[(wm * 64 + mi * 16 + l16) * 64 + kk * 32 + lhi * 8];
#pragma unroll
      for (int ni = 0; ni < 2; ++ni)
        bfr[ni] = *(const bf16x8*)&sB[(wn * 32 + ni * 16 + l16) * 64 + kk * 32 + lhi * 8];
#pragma unroll
      for (int mi = 0; mi < 4; ++mi)
#pragma unroll
        for (int ni = 0; ni < 2; ++ni)
          acc[mi][ni] = __builtin_amdgcn_mfma_f32_16x16x32_bf16(af[mi], bfr[ni], acc[mi][ni], 0, 0, 0);
    }
    __syncthreads();
  }

  // ---- epilogue: C store (bf16) + per-row attention-score partials ----
  unsigned short* hb = hbuf2 + z * ZS;
  const float* asr_p = asr_l + z * 1024 + bcol * 64;
  const float* ads_p = ads_l + z * 1024 + bcol * 64;
  float as0 = asr_p[wn * 32 + l16],      ad0 = ads_p[wn * 32 + l16];
  float as1 = asr_p[wn * 32 + 16 + l16], ad1 = ads_p[wn * 32 + 16 + l16];
  float* sredS = (float*)sA;        // [wm][wn][64] = 256 floats
  float* sredD = (float*)sA + 256;  // (sA dead after K loop)

#pragma unroll
  for (int mi = 0; mi < 4; ++mi) {
#pragma unroll
    for (int j = 0; j < 4; ++j) {
      int r = brow * 128 + wm * 64 + mi * 16 + lhi * 4 + j;
      float v0 = acc[mi][0][j], v1 = acc[mi][1][j];
      hb[(size_t)r * 256 + bcol * 64 + wn * 32 + l16] = f2bf(v0);
      hb[(size_t)r * 256 + bcol * 64 + wn * 32 + 16 + l16] = f2bf(v1);
      float ps = v0 * as0 + v1 * as1;
      float pd = v0 * ad0 + v1 * ad1;
#pragma unroll
      for (int off = 1; off < 16; off <<= 1) {
        ps += __shfl_xor(ps, off);
        pd += __shfl_xor(pd, off);
      }
      if (l16 == 0) {
        int rl = mi * 16 + lhi * 4 + j;  // row within wave tile [0,64)
        sredS[wm * 128 + wn * 64 + rl] = ps;
        sredD[wm * 128 + wn * 64 + rl] = pd;
      }
    }
  }
  __syncthreads();
  if (tid < 128) {
    int w = tid >> 6, rl = tid & 63;
    float s = sredS[w * 128 + rl] + sredS[w * 128 + 64 + rl];
    float d = sredD[w * 128 + rl] + sredD[w * 128 + 64 + rl];
    int row = brow * 128 + tid;
    a_s2[(size_t)z * Nn * 4 + row * 4 + bcol] = s;
    a_d2[(size_t)z * Nn * 4 + row * 4 + bcol] = d;
  }
}

// ---------------- FFN1: f = relu(x1 @ W1 + b1), BK=64, BM=BN=128, z=stream ----------------
__global__ __launch_bounds__(256, 2) void ffn1_kernel(
    const unsigned short* __restrict__ A2, const unsigned short* __restrict__ Bt_l,
    unsigned short* __restrict__ out2, const float* __restrict__ b1_l) {
  const int K = 256, Ncol = Ff;
  const size_t ZS = (size_t)Nn * Dm;
  __shared__ __align__(16) unsigned short sA[128 * 64];
  __shared__ __align__(16) unsigned short sB[128 * 64];
  int tid = threadIdx.x, wave = tid >> 6, lane = tid & 63;
  int l16 = lane & 15, lhi = lane >> 4;
  int brow = blockIdx.x, bcol = blockIdx.y, z = blockIdx.z;
  int wm = wave >> 1, wn = wave & 1;  // wave tile 64x64

  const unsigned short* Ab = A2 + z * ZS + (size_t)brow * 128 * K;
  const unsigned short* Bb = Bt_l + (size_t)z * 4 * Ff * 256 + (size_t)bcol * 128 * K;
  int lrow = lane >> 3, lk = (lane & 7) * 8;

  f32x4 acc[4][4] = {};

  for (int k0 = 0; k0 < K; k0 += 64) {
#pragma unroll
    for (int r = 0; r < 4; ++r) {
      int rb = r * 32 + wave * 8;
      async_copy16(Ab + (size_t)(rb + lrow) * K + k0 + lk, &sA[rb * 64]);
      async_copy16(Bb + (size_t)(rb + lrow) * K + k0 + lk, &sB[rb * 64]);
    }
    __syncthreads();
#pragma unroll
    for (int kk = 0; kk < 2; ++kk) {
      bf16x8 af[4], bfr[4];
#pragma unroll
      for (int mi = 0; mi < 4; ++mi)
        af[mi] = *(const bf16x8*)&sA[(wm * 64 + mi * 16 + l16) * 64 + kk * 32 + lhi * 8];
#pragma unroll
      for (int ni = 0; ni < 4; ++ni)
        bfr[ni] = *(const bf16x8*)&sB[(wn * 64 + ni * 16 + l16) * 64 + kk * 32 + lhi * 8];
#pragma unroll
      for (int mi = 0; mi < 4; ++mi)
#pragma unroll
        for (int ni = 0; ni < 4; ++ni)
          acc[mi][ni] = __builtin_amdgcn_mfma_f32_16x16x32_bf16(af[mi], bfr[ni], acc[mi][ni], 0, 0, 0);
    }
    __syncthreads();
  }

  unsigned short* outB = out2 + (size_t)z * Nn * Ff;
  const float* bias = b1_l + z * 4096;
#pragma unroll
  for (int mi = 0; mi < 4; ++mi) {
#pragma unroll
    for (int ni = 0; ni < 4; ++ni) {
#pragma unroll
      for (int j = 0; j < 4; ++j) {
        int r = brow * 128 + wm * 64 + mi * 16 + lhi * 4 + j;
        int c = bcol * 128 + wn * 64 + ni * 16 + l16;
        float v = acc[mi][ni][j] + bias[c];
        v = v > 0.f ? v : 0.f;
        outB[(size_t)r * Ncol + c] = f2bf(v);
      }
    }
  }
}

// ---------------- FFN2: t = f @ W2 + b2 + x1 (bf16 resid), bf16 out ----------------
// BM=64, BN=256, BK=64, z=stream.
__global__ __launch_bounds__(256, 2) void ffn2_kernel(
    const unsigned short* __restrict__ A2, const unsigned short* __restrict__ Bt_l,
    unsigned short* __restrict__ out2, const float* __restrict__ b2_l,
    const unsigned short* __restrict__ resid2) {
  const int K = Ff, Ncol = 256;
  const size_t ZS = (size_t)Nn * Dm;
  __shared__ __align__(16) unsigned short sA[64 * 64];    // 8 KB
  __shared__ __align__(16) unsigned short sB[256 * 64];   // 32 KB
  int tid = threadIdx.x, wave = tid >> 6, lane = tid & 63;
  int l16 = lane & 15, lhi = lane >> 4;
  int brow = blockIdx.x, z = blockIdx.z;

  const unsigned short* Ab = A2 + (size_t)z * Nn * Ff + (size_t)brow * 64 * K;
  const unsigned short* Bb = Bt_l + (size_t)z * 4 * Ff * 256;  // all 256 cols
  int lrow = lane >> 3, lk = (lane & 7) * 8;

  f32x4 acc[4][4] = {};

  for (int k0 = 0; k0 < K; k0 += 64) {
#pragma unroll
    for (int r = 0; r < 8; ++r) {
      int rb = r * 32 + wave * 8;
      if (r < 2)
        async_copy16(Ab + (size_t)(rb + lrow) * K + k0 + lk, &sA[rb * 64]);
      async_copy16(Bb + (size_t)(rb + lrow) * K + k0 + lk, &sB[rb * 64]);
    }
    __syncthreads();
#pragma unroll
    for (int kk = 0; kk < 2; ++kk) {
      bf16x8 af[4], bfr[4];
#pragma unroll
      for (int mi = 0; mi < 4; ++mi)
        af[mi] = *(const bf16x8*)&sA[(mi * 16 + l16) * 64 + kk * 32 + lhi * 8];
#pragma unroll
      for (int ni = 0; ni < 4; ++ni)
        bfr[ni] = *(const bf16x8*)&sB[(wave * 64 + ni * 16 + l16) * 64 + kk * 32 + lhi * 8];
#pragma unroll
      for (int mi = 0; mi < 4; ++mi)
#pragma unroll
        for (int ni = 0; ni < 4; ++ni)
          acc[mi][ni] = __builtin_amdgcn_mfma_f32_16x16x32_bf16(af[mi], bfr[ni], acc[mi][ni], 0, 0, 0);
    }
    __syncthreads();
  }

  unsigned short* outB = out2 + z * ZS;
  const float* bias = b2_l + z * 1024;
  const unsigned short* resid = resid2 + z * ZS;
#pragma unroll
  for (int mi = 0; mi < 4; ++mi) {
#pragma unroll
    for (int ni = 0; ni < 4; ++ni) {
#pragma unroll
      for (int j = 0; j < 4; ++j) {
        int r = brow * 64 + mi * 16 + lhi * 4 + j;
        int c = wave * 64 + ni * 16 + l16;
        float v = acc[mi][ni][j] + bias[c] + bf2f(resid[(size_t)r * Ncol + c]);
        outB[(size_t)r * Ncol + c] = f2bf(v);
      }
    }
  }
}

// ---------------- wave-per-node fused softmax + aggregation + bias + residual + LN1 ----------------
// grid (Nn/4, 2): y = stream. 4 waves/block. Barrier-free.
// PV via v_dot2_f32_bf16 on edge pairs; weight array padded (head stride 144B) -> bank-conflict-free.
__global__ __launch_bounds__(256) void agg_kernel(
    const unsigned short* __restrict__ hbuf2, const float* __restrict__ a_s2,
    const float* __restrict__ a_d2,
    const int* __restrict__ rowptr, const int* __restrict__ csrc,
    const float* __restrict__ bias_l, const unsigned short* __restrict__ x01b,
    const float* __restrict__ g1_l, const float* __restrict__ bt1_l,
    unsigned short* __restrict__ x1b2) {
  __shared__ __align__(16) unsigned short sw16[4][4][72];  // pad 64->72: heads hit banks 0/4/8/12
  __shared__ int ssrc[4][64];
  const size_t ZS = (size_t)Nn * Dm;
  int z = blockIdx.y;
  const unsigned short* hb = hbuf2 + z * ZS;
  const float* a_s = a_s2 + (size_t)z * Nn * 4;
  const float* a_d = a_d2 + (size_t)z * Nn * 4;
  const float* bias = bias_l + z * 1024;
  const unsigned short* xres = x01b + z * ZS;
  const float* g1 = g1_l + z * 1024;
  const float* bt1 = bt1_l + z * 1024;
  unsigned short* x1b = x1b2 + z * ZS;

  int wave = threadIdx.x >> 6, lane = threadIdx.x & 63;
  int n = blockIdx.x * 4 + wave;
  int l32 = lane & 31;
  int par = lane >> 5;         // pair parity (pair k handled by half k&1)
  int hch = l32 >> 3;          // head of my channel block
  int c0 = l32 * 8;            // my 8 channels
  int beg = rowptr[n], end = rowptr[n + 1];
  float4 adv = *(const float4*)&a_d[n * 4];
  const float NI = -__builtin_inff();
  float acc[8] = {};
  float den = 0.f;

  // PV over one staged chunk of cnt (<=64) edges; acc/den updated.
  auto pv_chunk = [&](int cnt) {
    int i = par * 2;
    for (; i + 1 < cnt; i += 4) {
      int sa = ssrc[wave][i], sb = ssrc[wave][i + 1];
      unsigned wp = *(const unsigned*)&sw16[wave][hch][i];  // i even -> dword aligned
      uint4 A = *(const uint4*)(hb + (size_t)sa * 256 + c0);
      uint4 B = *(const uint4*)(hb + (size_t)sb * 256 + c0);
      acc[0] = dot2bf(__builtin_amdgcn_perm(A.x, B.x, 0x01000504u), wp, acc[0]);
      acc[1] = dot2bf(__builtin_amdgcn_perm(A.x, B.x, 0x03020706u), wp, acc[1]);
      acc[2] = dot2bf(__builtin_amdgcn_perm(A.y, B.y, 0x01000504u), wp, acc[2]);
      acc[3] = dot2bf(__builtin_amdgcn_perm(A.y, B.y, 0x03020706u), wp, acc[3]);
      acc[4] = dot2bf(__builtin_amdgcn_perm(A.z, B.z, 0x01000504u), wp, acc[4]);
      acc[5] = dot2bf(__builtin_amdgcn_perm(A.z, B.z, 0x03020706u), wp, acc[5]);
      acc[6] = dot2bf(__builtin_amdgcn_perm(A.w, B.w, 0x01000504u), wp, acc[6]);
      acc[7] = dot2bf(__builtin_amdgcn_perm(A.w, B.w, 0x03020706u), wp, acc[7]);
      den += bf2f((unsigned short)(wp & 0xFFFFu)) + bf2f((unsigned short)(wp >> 16));
    }
    if (cnt & 1) {
      int e = cnt - 1;
      if (((e >> 1) & 1) == par) {
        int s_i = ssrc[wave][e];
        float w = bf2f(sw16[wave][hch][e]);
        bf16x8 hv = *(const bf16x8*)(hb + (size_t)s_i * 256 + c0);
#pragma unroll
        for (int j = 0; j < 8; ++j)
          acc[j] = fmaf(bf2f((unsigned short)hv[j]), w, acc[j]);
        den += w;
      }
    }
  };

  if (end - beg <= 64) {
    // ---- fast path: single chunk, no online rescale ----
    int cnt = end - beg;
    float4 ev = {NI, NI, NI, NI};
    if (lane < cnt) {
      int s = csrc[beg + lane];
      ssrc[wave][lane] = s;
      float4 as = *(const float4*)&a_s[s * 4];
      float e0 = as.x + adv.x; ev.x = e0 > 0.f ? e0 : 0.2f * e0;
      float e1 = as.y + adv.y; ev.y = e1 > 0.f ? e1 : 0.2f * e1;
      float e2 = as.z + adv.z; ev.z = e2 > 0.f ? e2 : 0.2f * e2;
      float e3 = as.w + adv.w; ev.w = e3 > 0.f ? e3 : 0.2f * e3;
    }
    float4 mv = ev;
#pragma unroll
    for (int off = 32; off; off >>= 1) {
      mv.x = fmaxf(mv.x, __shfl_xor(mv.x, off));
      mv.y = fmaxf(mv.y, __shfl_xor(mv.y, off));
      mv.z = fmaxf(mv.z, __shfl_xor(mv.z, off));
      mv.w = fmaxf(mv.w, __shfl_xor(mv.w, off));
    }
    if (lane < cnt) {
      sw16[wave][0][lane] = f2bf(__expf(ev.x - mv.x));
      sw16[wave][1][lane] = f2bf(__expf(ev.y - mv.y));
      sw16[wave][2][lane] = f2bf(__expf(ev.z - mv.z));
      sw16[wave][3][lane] = f2bf(__expf(ev.w - mv.w));
    }
    __builtin_amdgcn_wave_barrier();
    pv_chunk(cnt);
  } else {
    // ---- general path: online softmax over 64-edge chunks ----
    float4 m4 = {NI, NI, NI, NI};
    for (int base = beg; base < end; base += 64) {
      int cnt = min(64, end - base);
      float4 ev = {NI, NI, NI, NI};
      if (lane < cnt) {
        int s = csrc[base + lane];
        ssrc[wave][lane] = s;
        float4 as = *(const float4*)&a_s[s * 4];
        float e0 = as.x + adv.x; ev.x = e0 > 0.f ? e0 : 0.2f * e0;
        float e1 = as.y + adv.y; ev.y = e1 > 0.f ? e1 : 0.2f * e1;
        float e2 = as.z + adv.z; ev.z = e2 > 0.f ? e2 : 0.2f * e2;
        float e3 = as.w + adv.w; ev.w = e3 > 0.f ? e3 : 0.2f * e3;
      }
      float4 mv = ev;
#pragma unroll
      for (int off = 32; off; off >>= 1) {
        mv.x = fmaxf(mv.x, __shfl_xor(mv.x, off));
        mv.y = fmaxf(mv.y, __shfl_xor(mv.y, off));
        mv.z = fmaxf(mv.z, __shfl_xor(mv.z, off));
        mv.w = fmaxf(mv.w, __shfl_xor(mv.w, off));
      }
      float4 m4n;
      m4n.x = fmaxf(m4.x, mv.x); m4n.y = fmaxf(m4.y, mv.y);
      m4n.z = fmaxf(m4.z, mv.z); m4n.w = fmaxf(m4.w, mv.w);
      float rm = __expf(sel4(m4, hch) - sel4(m4n, hch));
#pragma unroll
      for (int j = 0; j < 8; ++j) acc[j] *= rm;
      den *= rm;
      if (lane < cnt) {
        sw16[wave][0][lane] = f2bf(__expf(ev.x - m4n.x));
        sw16[wave][1][lane] = f2bf(__expf(ev.y - m4n.y));
        sw16[wave][2][lane] = f2bf(__expf(ev.z - m4n.z));
        sw16[wave][3][lane] = f2bf(__expf(ev.w - m4n.w));
      }
      m4 = m4n;
      __builtin_amdgcn_wave_barrier();
      pv_chunk(cnt);
      __builtin_amdgcn_wave_barrier();
    }
  }

  // combine pair parities (lane ^ 32 holds same channels, other parity)
#pragma unroll
  for (int j = 0; j < 8; ++j) acc[j] += __shfl_xor(acc[j], 32);
  den += __shfl_xor(den, 32);

  float invden = 1.f / fmaxf(den, 1e-16f);
  bf16x8 rv = *(const bf16x8*)(xres + (size_t)n * 256 + c0);
  float outv[8];
  float s1 = 0.f, s2 = 0.f;
#pragma unroll
  for (int j = 0; j < 8; ++j) {
    float v = acc[j] * invden + bias[c0 + j] + bf2f((unsigned short)rv[j]);
    outv[j] = v;
    s1 += v;
    s2 += v * v;
  }
  // LN reduce over the 32-lane half (halves hold identical data)
#pragma unroll
  for (int off = 16; off; off >>= 1) {
    s1 += __shfl_xor(s1, off);
    s2 += __shfl_xor(s2, off);
  }
  float mean = s1 * (1.f / 256.f);
  float var = s2 * (1.f / 256.f) - mean * mean;
  float rst = rsqrtf(var + 1e-5f);
  if (par == 0) {
    unsigned short yb[8];
#pragma unroll
    for (int j = 0; j < 8; ++j)
      yb[j] = f2bf((outv[j] - mean) * rst * g1[c0 + j] + bt1[c0 + j]);
    *(bf16x8*)&x1b[(size_t)n * 256 + c0] = *(bf16x8*)yb;
  }
}

// ---------------- dual LN2 (wave per node) ----------------
// PREP=1 (layers 0-2): writes ONLY next-layer bf16 inputs. PREP=0 (layer 3): writes f32 states.
template <int PREP>
__global__ __launch_bounds__(256) void ln2_kernel(const unsigned short* __restrict__ tb2,
                                                  const float* __restrict__ g2_l,
                                                  const float* __restrict__ bt2_l,
                                                  float* __restrict__ out_hf,
                                                  float* __restrict__ out_hs,
                                                  unsigned short* __restrict__ x01b) {
  const size_t ZS = (size_t)Nn * Dm;
  int wave = threadIdx.x >> 6, lane = threadIdx.x & 63;
  int n = blockIdx.x * 4 + wave;
  int c0 = lane * 4;
  size_t idx = (size_t)n * 256 + c0;
  ushort4 u0 = *(const ushort4*)&tb2[idx];
  ushort4 u1 = *(const ushort4*)&tb2[ZS + idx];
  float v0[4] = {bf2f(u0.x), bf2f(u0.y), bf2f(u0.z), bf2f(u0.w)};
  float v1[4] = {bf2f(u1.x), bf2f(u1.y), bf2f(u1.z), bf2f(u1.w)};
  float a0 = 0.f, b0 = 0.f, a1 = 0.f, b1 = 0.f;
#pragma unroll
  for (int j = 0; j < 4; ++j) {
    a0 += v0[j]; b0 += v0[j] * v0[j];
    a1 += v1[j]; b1 += v1[j] * v1[j];
  }
#pragma unroll
  for (int off = 32; off; off >>= 1) {
    a0 += __shfl_xor(a0, off);
    b0 += __shfl_xor(b0, off);
    a1 += __shfl_xor(a1, off);
    b1 += __shfl_xor(b1, off);
  }
  float m0 = a0 * (1.f / 256.f), m1 = a1 * (1.f / 256.f);
  float r0 = rsqrtf(b0 * (1.f / 256.f) - m0 * m0 + 1e-5f);
  float r1 = rsqrtf(b1 * (1.f / 256.f) - m1 * m1 + 1e-5f);
  float4 y0, y1;
  unsigned short p0[4], p1[4];
#pragma unroll
  for (int j = 0; j < 4; ++j) {
    float yf = (v0[j] - m0) * r0 * g2_l[c0 + j] + bt2_l[c0 + j];
    float ys = (v1[j] - m1) * r1 * g2_l[1024 + c0 + j] + bt2_l[1024 + c0 + j];
    ((float*)&y0)[j] = yf;
    ((float*)&y1)[j] = ys;
    if (PREP) { p0[j] = f2bf(yf + ys); p1[j] = f2bf(ys); }
  }
  if (PREP) {
    *(ushort4*)&x01b[idx] = *(ushort4*)p0;
    *(ushort4*)&x01b[ZS + idx] = *(ushort4*)p1;
  } else {
    *(float4*)&out_hf[idx] = y0;
    *(float4*)&out_hs[idx] = y1;
  }
}

extern "C" void kernel_launch(void* const* d_in, const int* in_sizes, int n_in,
                              void* d_out, int out_size, void* d_ws, size_t ws_size,
                              hipStream_t stream) {
  const float* hf_in = (const float*)d_in[0];
  const float* hs_in = (const float*)d_in[1];
  const int* ei = (const int*)d_in[2];
  const int E = in_sizes[2] / 2;
  const float* Wgat = (const float*)d_in[3];
  const float* att_src = (const float*)d_in[4];
  const float* att_dst = (const float*)d_in[5];
  const float* bias_gat = (const float*)d_in[6];
  const float* W1 = (const float*)d_in[7];
  const float* b1 = (const float*)d_in[8];
  const float* W2 = (const float*)d_in[9];
  const float* b2 = (const float*)d_in[10];
  const float* g1 = (const float*)d_in[11];
  const float* bt1 = (const float*)d_in[12];
  const float* g2 = (const float*)d_in[13];
  const float* bt2 = (const float*)d_in[14];
  const int* src = ei;
  const int* dst = ei + E;
  const size_t ZS = (size_t)Nn * Dm;

  // ---- carve workspace ----
  char* wsp = (char*)d_ws;
  size_t off = 0;
  auto carve = [&](size_t bytes) -> void* {
    void* p = wsp + off;
    off += (bytes + 255) & ~(size_t)255;
    return p;
  };
  unsigned short* Wgt  = (unsigned short*)carve((size_t)8 * 256 * 256 * 2);
  unsigned short* W1t  = (unsigned short*)carve((size_t)8 * 256 * 1024 * 2);
  unsigned short* W2t  = (unsigned short*)carve((size_t)8 * 1024 * 256 * 2);
  int* cnt      = (int*)carve((size_t)Nn * 4);
  int* rowptr   = (int*)carve((size_t)(Nn + 1) * 4);
  int* cursor   = (int*)carve((size_t)Nn * 4);
  int* part     = (int*)carve((size_t)Nn * 4);
  int* bsum     = (int*)carve((size_t)64 * 4);
  int* bbase    = (int*)carve((size_t)64 * 4);
  int* csrc     = (int*)carve((size_t)E * 4);
  unsigned short* x01b = (unsigned short*)carve(2 * ZS * 2);  // [z]: layer input bf16
  unsigned short* hbuf2 = (unsigned short*)carve(2 * ZS * 2); // [z]: proj out bf16
  float* a_s2   = (float*)carve((size_t)2 * Nn * 4 * 4);
  float* a_d2   = (float*)carve((size_t)2 * Nn * 4 * 4);
  unsigned short* x1b2 = (unsigned short*)carve(2 * ZS * 2);  // [z]: LN1 out bf16
  unsigned short* tb2  = (unsigned short*)carve(2 * ZS * 2);  // [z]: FFN2 out (pre-LN2) bf16
  unsigned short* f_b2 = (unsigned short*)carve((size_t)2 * Nn * Ff * 2);  // [z]: FFN1 out
  if (off > ws_size) return;  // workspace too small — fail visibly

  // ---- once per call: weights (tiled transpose) + CSR ----
  wconvt_kernel<<<dim3(4, 4, 8), 256, 0, stream>>>(Wgat, Wgt, 256, 256);
  wconvt_kernel<<<dim3(16, 4, 8), 256, 0, stream>>>(W1, W1t, 256, 1024);
  wconvt_kernel<<<dim3(4, 16, 8), 256, 0, stream>>>(W2, W2t, 1024, 256);
  hipMemsetAsync(cnt, 0, (size_t)Nn * 4, stream);
  count_kernel<<<1024, 256, 0, stream>>>(dst, E, cnt);
  scan1_kernel<<<64, 256, 0, stream>>>(cnt, part, bsum);
  scan2_kernel<<<1, 64, 0, stream>>>(bsum, bbase, rowptr);
  scan3_kernel<<<64, 256, 0, stream>>>(part, bbase, rowptr, cursor);
  fill_kernel<<<1024, 256, 0, stream>>>(src, dst, E, cursor, csrc);

  float* out_hf = (float*)d_out;
  float* out_hs = out_hf + ZS;

  prep_kernel<<<2048, 256, 0, stream>>>(hf_in, hs_in, x01b, Nn * Dm);

  for (int l = 0; l < 4; ++l) {
    // proj (both streams) + fused scores
    proj_kernel<<<dim3(128, 4, 2), 256, 0, stream>>>(
        x01b, Wgt + (size_t)l * 65536, hbuf2,
        att_src + l * 256, att_dst + l * 256, a_s2, a_d2);
    // segment softmax + aggregate + bias + residual + LN1 (both streams)
    agg_kernel<<<dim3(Nn / 4, 2), 256, 0, stream>>>(
        hbuf2, a_s2, a_d2, rowptr, csrc,
        bias_gat + l * 256, x01b, g1 + l * 256, bt1 + l * 256, x1b2);
    // FFN (both streams per dispatch)
    ffn1_kernel<<<dim3(128, 8, 2), 256, 0, stream>>>(
        x1b2, W1t + (size_t)l * 256 * 1024, f_b2, b1 + l * 1024);
    ffn2_kernel<<<dim3(256, 1, 2), 256, 0, stream>>>(
        f_b2, W2t + (size_t)l * 1024 * 256, tb2, b2 + l * 256, x1b2);
    // dual LN2 (+ next-layer prep for l<3; out states written only at l=3)
    if (l < 3) {
      ln2_kernel<1><<<Nn / 4, 256, 0, stream>>>(tb2, g2 + l * 256, bt2 + l * 256,
                                                out_hf, out_hs, x01b);
    } else {
      ln2_kernel<0><<<Nn / 4, 256, 0, stream>>>(tb2, g2 + l * 256, bt2 + l * 256,
                                                out_hf, out_hs, x01b);
    }
  }
}